// Round 10
// baseline (2193.474 us; speedup 1.0000x reference)
//
#include <hip/hip_runtime.h>

// LSTMConditioned: conv-encoder + attention-LSTM (T=64) + MDN head.
// N=128, T=64, HID=512, COMB=1024, ATT=128, K=20, D=2, FMAP=64, L=196, ODIM=121.
// Recurrence: 2 launches/step (launch-boundary sync is the cheapest sync on MI355X).
// stepA (160 blocks x 512 thr) = attention (blocks 0-127) || gates Whh-part GEMM
// (blocks 128-159, LDS-free direct-global A-frags). stepB (32 blocks x 512 thr) =
// z-part GEMM (direct-global u-frags) + fused cell update.

#define TN 128
#define TT 64

typedef __attribute__((ext_vector_type(4))) float f32x4;
typedef __attribute__((ext_vector_type(8))) short bf16x8;

__device__ __forceinline__ float fsigm(float x){ return __builtin_amdgcn_rcpf(1.0f + __expf(-x)); }
__device__ __forceinline__ float ftanh(float x){ return 1.0f - 2.0f*__builtin_amdgcn_rcpf(1.0f + __expf(2.0f*x)); }
__device__ __forceinline__ unsigned short f2bf(float f){
  unsigned int u = __float_as_uint(f);
  u += 0x7fffu + ((u >> 16) & 1u);
  return (unsigned short)(u >> 16);
}
__device__ __forceinline__ float b2f(unsigned short u){ return __uint_as_float(((unsigned)u)<<16); }

// ---------------- conv1 (direct, small), bf16 out ----------------
__global__ __launch_bounds__(256) void k_conv1(const float* __restrict__ xc, const float* __restrict__ w,
                                               const float* __restrict__ b, unsigned short* __restrict__ c1bf){
  int idx = blockIdx.x*256 + threadIdx.x;
  if (idx >= TN*16*784) return;
  int p = idx % 784, oc = (idx/784) & 15, n = idx/(784*16);
  int py = p/28, px = p%28;
  const float* src = xc + n*784;
  float acc = b[oc];
  #pragma unroll
  for (int ky=0;ky<3;ky++){
    int iy = py+ky-1; if (iy<0||iy>=28) continue;
    #pragma unroll
    for (int kx=0;kx<3;kx++){
      int ix = px+kx-1; if (ix<0||ix>=28) continue;
      acc += (src[iy*28+ix]-0.0243f)*(1.0f/0.1383f) * w[oc*9+ky*3+kx];
    }
  }
  c1bf[idx] = f2bf(fmaxf(acc, 0.0f));
}

// ---------------- im2col for conv2 (bf16 gather) ----------------
__global__ __launch_bounds__(256) void k_im2col2(const unsigned short* __restrict__ c1bf, unsigned short* __restrict__ a2){
  int idx = blockIdx.x*256 + threadIdx.x;   // 62720*256 = 100352*160
  int k = idx % 160, r = idx / 160;
  unsigned short v = 0;
  if (k < 144){
    int ic = k/9, rem = k - ic*9, ky = rem/3, kx = rem - ky*3;
    int p = r % 784, n = r / 784;
    int py = p/28, px = p%28;
    int iy = py+ky-1, ix = px+kx-1;
    if (iy>=0 && iy<28 && ix>=0 && ix<28) v = c1bf[(n*16+ic)*784 + iy*28+ix];
  }
  a2[idx] = v;
}

// ---------------- conv2 GEMM ----------------
__global__ __launch_bounds__(256) void k_gconv2(const unsigned short* __restrict__ a2,
    const unsigned short* __restrict__ w2b, const float* __restrict__ b2,
    unsigned short* __restrict__ c2bf){
  int mbase = blockIdx.x*128;           // 784 blocks
  int tid = threadIdx.x, w = tid>>6, l = tid&63;
  int lr = l&15, lk = (l>>4)*8;
  __shared__ unsigned short at[128*168];
  {
    int row = tid>>1, off = (tid&1)*80;
    const unsigned short* sp = a2 + (size_t)(mbase+row)*160 + off;
    #pragma unroll
    for (int j=0;j<10;j++) *(float4*)&at[row*168 + off + j*8] = *(const float4*)(sp + j*8);
  }
  __syncthreads();
  f32x4 acc[2][2];
  #pragma unroll
  for (int mi=0;mi<2;mi++){ acc[mi][0]=(f32x4){0,0,0,0}; acc[mi][1]=(f32x4){0,0,0,0}; }
  for (int kt=0; kt<5; ++kt){
    bf16x8 b0 = *(const bf16x8*)(w2b + (0*16+lr)*160 + kt*32 + lk);
    bf16x8 b1 = *(const bf16x8*)(w2b + (1*16+lr)*160 + kt*32 + lk);
    #pragma unroll
    for (int mi=0;mi<2;mi++){
      bf16x8 afrag = *(const bf16x8*)&at[((2*w+mi)*16+lr)*168 + kt*32 + lk];
      acc[mi][0] = __builtin_amdgcn_mfma_f32_16x16x32_bf16(afrag, b0, acc[mi][0], 0,0,0);
      acc[mi][1] = __builtin_amdgcn_mfma_f32_16x16x32_bf16(afrag, b1, acc[mi][1], 0,0,0);
    }
  }
  #pragma unroll
  for (int mi=0;mi<2;mi++){
    #pragma unroll
    for (int j=0;j<2;j++){
      int oc = j*16 + lr;
      float bb = b2[oc];
      #pragma unroll
      for (int i=0;i<4;i++){
        int r = mbase + (2*w+mi)*16 + (l>>4)*4 + i;
        c2bf[(size_t)r*32 + oc] = f2bf(fmaxf(acc[mi][j][i] + bb, 0.0f));
      }
    }
  }
}

// ---------------- im2col for conv3 (stride 2) ----------------
__global__ __launch_bounds__(256) void k_im2col3(const unsigned short* __restrict__ c2bf, unsigned short* __restrict__ a3){
  int idx = blockIdx.x*256 + threadIdx.x;   // 31360*256 = 25088*320
  int k = idx % 320, r = idx / 320;
  unsigned short v = 0;
  if (k < 288){
    int ic = k/9, rem = k - ic*9, ky = rem/3, kx = rem - ky*3;
    int p = r % 196, n = r / 196;
    int py = p/14, px = p%14;
    int iy = 2*py+ky-1, ix = 2*px+kx-1;
    if (iy>=0 && iy<28 && ix>=0 && ix<28) v = c2bf[(size_t)(n*784 + iy*28+ix)*32 + ic];
  }
  a3[idx] = v;
}

// ---------------- conv3 GEMM: afbf[n][f][l] (bf16) + abf[r][f] (bf16) ----------------
__global__ __launch_bounds__(256) void k_gconv3(const unsigned short* __restrict__ a3,
    const unsigned short* __restrict__ w3b, const float* __restrict__ b3,
    unsigned short* __restrict__ afbf, unsigned short* __restrict__ abf){
  int mbase = blockIdx.x*128;           // 196 blocks
  int tid = threadIdx.x, w = tid>>6, l = tid&63;
  int lr = l&15, lk = (l>>4)*8;
  __shared__ unsigned short at[128*168];
  f32x4 acc[2][4];
  #pragma unroll
  for (int mi=0;mi<2;mi++)
    #pragma unroll
    for (int j=0;j<4;j++) acc[mi][j]=(f32x4){0,0,0,0};
  for (int kt2=0; kt2<2; ++kt2){
    {
      int row = tid>>1, off = (tid&1)*80;
      const unsigned short* sp = a3 + (size_t)(mbase+row)*320 + kt2*160 + off;
      #pragma unroll
      for (int j=0;j<10;j++) *(float4*)&at[row*168 + off + j*8] = *(const float4*)(sp + j*8);
    }
    __syncthreads();
    for (int kt=0; kt<5; ++kt){
      #pragma unroll
      for (int mi=0;mi<2;mi++){
        bf16x8 afrag = *(const bf16x8*)&at[((2*w+mi)*16+lr)*168 + kt*32 + lk];
        #pragma unroll
        for (int j=0;j<4;j++){
          bf16x8 bf = *(const bf16x8*)(w3b + (size_t)(j*16+lr)*320 + kt2*160 + kt*32 + lk);
          acc[mi][j] = __builtin_amdgcn_mfma_f32_16x16x32_bf16(afrag, bf, acc[mi][j], 0,0,0);
        }
      }
    }
    __syncthreads();
  }
  #pragma unroll
  for (int mi=0;mi<2;mi++){
    #pragma unroll
    for (int j=0;j<4;j++){
      int oc = j*16 + lr;
      float bb = b3[oc];
      #pragma unroll
      for (int i=0;i<4;i++){
        int r = mbase + (2*w+mi)*16 + (l>>4)*4 + i;
        int n = r/196, p = r - n*196;
        float v = ftanh(acc[mi][j][i] + bb);
        unsigned short vb16 = f2bf(v);
        afbf[(size_t)(n*64+oc)*196 + p] = vb16;
        abf[(size_t)r*64 + oc] = vb16;
      }
    }
  }
}

__global__ __launch_bounds__(64) void k_amean(const unsigned short* __restrict__ afbf, float* __restrict__ amean){
  int n = blockIdx.x, f = threadIdx.x;
  const unsigned short* row = afbf + (size_t)(n*64+f)*196;
  float s = 0;
  for (int l=0;l<196;l++) s += b2f(row[l]);
  amean[n*64+f] = s * (1.0f/196.0f);
}

// ---------------- embeddings / init ----------------
__global__ __launch_bounds__(256) void k_embed(const float* __restrict__ x, const float* __restrict__ start,
    const float* __restrict__ xw, const float* __restrict__ xb,
    const float* __restrict__ sw, const float* __restrict__ sb,
    float* __restrict__ xe, float* __restrict__ se){
  int idx = blockIdx.x*256 + threadIdx.x;
  if (idx < TN*TT*16){
    int j = idx & 15, t = (idx>>4) & 63, n = idx>>10;
    float acc = xb[j];
    if (t > 0){
      const float* xp = x + (n*TT + t-1)*2;
      acc += xp[0]*xw[j*2] + xp[1]*xw[j*2+1];
    }
    xe[idx] = ftanh(acc);
  } else if (idx < TN*TT*16 + TN*16){
    int k2 = idx - TN*TT*16;
    int j = k2 & 15, n = k2 >> 4;
    float acc = sb[j] + start[n*2]*sw[j*2] + start[n*2+1]*sw[j*2+1];
    se[k2] = ftanh(acc);
  }
}

__global__ __launch_bounds__(256) void k_init(const float* __restrict__ amean, const float* __restrict__ se,
    const float* __restrict__ w, const float* __restrict__ b,
    unsigned short* __restrict__ hbfA, float* __restrict__ cbuf){
  int idx = blockIdx.x*256 + threadIdx.x;
  if (idx >= TN*1024) return;
  int o = idx & 1023, n = idx >> 10;
  const float* wr = w + o*80;
  float acc = b[o];
  for (int k2=0;k2<64;k2++) acc += amean[n*64+k2]*wr[k2];
  for (int k2=0;k2<16;k2++) acc += se[n*16+k2]*wr[64+k2];
  float v = ftanh(acc);
  if (o & 1) cbuf[n*512 + (o>>1)] = v;
  else       hbfA[n*512 + (o>>1)] = f2bf(v);
}

// ---------------- weight prep ----------------
// wgf: gates weights in MFMA fragment order: frag (g,b,kt) at ((g*32+b)*19+kt)*512,
// lane l elem j = W[g*512+b*16+(l&15)][kt*32+(l>>4)*8+j], W = [Whh | Wih(pad 96)].
__global__ __launch_bounds__(256) void k_prep(
    const float* __restrict__ Whh, const float* __restrict__ Wih,
    const float* __restrict__ bih, const float* __restrict__ bhh,
    const float* __restrict__ comb_w, const float* __restrict__ out_w, const float* __restrict__ out_b,
    const float* __restrict__ Uw, const float* __restrict__ beta_w, const float* __restrict__ Ww,
    const float* __restrict__ conv2_w, const float* __restrict__ conv3_w,
    unsigned short* __restrict__ wgf, float* __restrict__ gbias,
    unsigned short* __restrict__ cwbf, unsigned short* __restrict__ owbf, float* __restrict__ obias,
    unsigned short* __restrict__ uwbf, unsigned short* __restrict__ betabf, unsigned short* __restrict__ wwbf,
    unsigned short* __restrict__ w2b, unsigned short* __restrict__ w3b){
  int idx = blockIdx.x*256 + threadIdx.x;
  if (idx < 1245184){
    int fragi = idx >> 9;
    int lane8 = idx & 511;
    int lane = lane8 >> 3, j = lane8 & 7;
    int g = fragi / 608;
    int rem = fragi - g*608;
    int b = rem / 19, kt = rem - b*19;
    int row = g*512 + b*16 + (lane & 15);
    int col = kt*32 + (lane >> 4)*8 + j;
    float v = 0.f;
    if (col < 512) v = Whh[(size_t)row*512 + col];
    else { int c2 = col - 512; if (c2 < 80) v = Wih[(size_t)row*80 + c2]; }
    wgf[idx] = f2bf(v);
    return;
  }
  idx -= 1245184;
  if (idx < 2048){ gbias[idx] = bih[idx]+bhh[idx]; return; }
  idx -= 2048;
  if (idx < 622592){ cwbf[idx] = f2bf(comb_w[idx]); return; }
  idx -= 622592;
  if (idx < 131072){ int o = idx>>10, k2 = idx & 1023; owbf[idx] = (o<121)? f2bf(out_w[o*1024+k2]) : (unsigned short)0; return; }
  idx -= 131072;
  if (idx < 128){ obias[idx] = (idx<121)? out_b[idx] : 0.0f; return; }
  idx -= 128;
  if (idx < 65536){ uwbf[idx] = f2bf(Uw[idx]); return; }
  idx -= 65536;
  if (idx < 32768){ betabf[idx] = f2bf(beta_w[idx]); return; }
  idx -= 32768;
  if (idx < 8192){ wwbf[idx] = f2bf(Ww[idx]); return; }
  idx -= 8192;
  if (idx < 5120){ int o = idx/160, k2 = idx - o*160; w2b[idx] = (k2<144)? f2bf(conv2_w[o*144+k2]) : (unsigned short)0; return; }
  idx -= 5120;
  if (idx < 20480){ int o = idx/320, k2 = idx - o*320; w3b[idx] = (k2<288)? f2bf(conv3_w[o*288+k2]) : (unsigned short)0; return; }
}

// ---------------- W_a = a @ Ww.T + Wb (MFMA), stored bf16 [n][l][att] ----------------
__global__ __launch_bounds__(256) void k_wa(const unsigned short* __restrict__ abf,
    const unsigned short* __restrict__ wwbf, const float* __restrict__ Wb,
    unsigned short* __restrict__ wabf){
  int mbase = blockIdx.x*128;
  int tid = threadIdx.x, w = tid>>6, l = tid&63;
  int lr = l & 15, lk = (l>>4)*8;
  __shared__ unsigned short at[128*40];
  f32x4 acc[8][2];
  #pragma unroll
  for (int m=0;m<8;m++){ acc[m][0] = (f32x4){0,0,0,0}; acc[m][1] = (f32x4){0,0,0,0}; }
  for (int kt=0; kt<2; ++kt){
    int row = tid>>1, half = (tid&1)*16;
    const unsigned short* sp = abf + (mbase+row)*64 + kt*32 + half;
    *(float4*)&at[row*40 + half]     = *(const float4*)sp;
    *(float4*)&at[row*40 + half + 8] = *(const float4*)(sp + 8);
    __syncthreads();
    bf16x8 b0 = *(const bf16x8*)(wwbf + ((2*w+0)*16 + lr)*64 + kt*32 + lk);
    bf16x8 b1 = *(const bf16x8*)(wwbf + ((2*w+1)*16 + lr)*64 + kt*32 + lk);
    #pragma unroll
    for (int m=0;m<8;m++){
      bf16x8 afrag = *(const bf16x8*)&at[(m*16+lr)*40 + lk];
      acc[m][0] = __builtin_amdgcn_mfma_f32_16x16x32_bf16(afrag, b0, acc[m][0], 0,0,0);
      acc[m][1] = __builtin_amdgcn_mfma_f32_16x16x32_bf16(afrag, b1, acc[m][1], 0,0,0);
    }
    __syncthreads();
  }
  #pragma unroll
  for (int m=0;m<8;m++){
    #pragma unroll
    for (int j=0;j<2;j++){
      int att = (2*w+j)*16 + lr;
      float wb = Wb[att];
      #pragma unroll
      for (int i=0;i<4;i++){
        int arow = mbase + m*16 + (l>>4)*4 + i;
        int n = arow/196, l2 = arow - n*196;
        wabf[((size_t)n*196 + l2)*128 + att] = f2bf(acc[m][j][i] + wb);
      }
    }
  }
}

// ---------------- step A: attention (blocks 0-127) || gates-h GEMM (blocks 128-159, LDS-free) ----------------
__global__ __launch_bounds__(512) void k_stepA(int t,
    const unsigned short* __restrict__ hbf_in,
    const unsigned short* __restrict__ uwbf, const float* __restrict__ Ub,
    const unsigned short* __restrict__ betabf, const float* __restrict__ beta_b,
    const float* __restrict__ vw, const float* __restrict__ vb,
    const unsigned short* __restrict__ wabf, const unsigned short* __restrict__ afbf,
    unsigned short* __restrict__ ubf_all, unsigned short* __restrict__ cbf,
    const unsigned short* __restrict__ wgf, float* __restrict__ gpart)
{
  const int bid = blockIdx.x, tid = threadIdx.x;
  __shared__ __align__(16) float hs[512];
  __shared__ __align__(16) float Uh[128];
  __shared__ __align__(16) float vws[128];
  __shared__ float bsig[64];
  __shared__ float ew[196];
  __shared__ float red[16];
  __shared__ float up[4][128];
  __shared__ float qp8[8][64];
  __shared__ float ep2[256][2];

  if (bid < TN){
    // =================== attention role: sample n = bid ===================
    const int n = bid;
    hs[tid] = b2f(hbf_in[n*512 + tid]);
    if (tid < 128) vws[tid] = vw[tid];
    const float vb0 = vb[0];
    __syncthreads();
    // Uh partials: (att, k-quarter)
    {
      int att = tid & 127, q = tid >> 7;
      const unsigned short* uw = uwbf + (size_t)att*512 + q*128;
      const float* hh = hs + q*128;
      float acc = 0.f;
      #pragma unroll 4
      for (int k=0;k<128;k+=8){
        bf16x8 v = *(const bf16x8*)(uw + k);
        acc += hh[k+0]*b2f(v[0]) + hh[k+1]*b2f(v[1]) + hh[k+2]*b2f(v[2]) + hh[k+3]*b2f(v[3])
             + hh[k+4]*b2f(v[4]) + hh[k+5]*b2f(v[5]) + hh[k+6]*b2f(v[6]) + hh[k+7]*b2f(v[7]);
      }
      up[q][att] = acc;
    }
    // beta partials: (f, k-eighth)
    {
      int f = tid & 63, q = tid >> 6;
      const unsigned short* bw = betabf + (size_t)f*512 + q*64;
      const float* hh = hs + q*64;
      float acc = 0.f;
      #pragma unroll 4
      for (int k=0;k<64;k+=8){
        bf16x8 v = *(const bf16x8*)(bw + k);
        acc += hh[k+0]*b2f(v[0]) + hh[k+1]*b2f(v[1]) + hh[k+2]*b2f(v[2]) + hh[k+3]*b2f(v[3])
             + hh[k+4]*b2f(v[4]) + hh[k+5]*b2f(v[5]) + hh[k+6]*b2f(v[6]) + hh[k+7]*b2f(v[7]);
      }
      qp8[q][f] = acc;
    }
    __syncthreads();
    if (tid < 128) Uh[tid] = Ub[tid] + up[0][tid]+up[1][tid]+up[2][tid]+up[3][tid];
    else if (tid < 192){
      int f = tid-128;
      bsig[f] = fsigm(beta_b[f] + qp8[0][f]+qp8[1][f]+qp8[2][f]+qp8[3][f]
                                + qp8[4][f]+qp8[5][f]+qp8[6][f]+qp8[7][f]);
    }
    __syncthreads();
    // e partials: (l, att-half)
    {
      int l = tid >> 1, half = tid & 1;
      float acc = 0.f;
      if (l < 196){
        const unsigned short* wr = wabf + ((size_t)n*196 + l)*128 + half*64;
        const float* uh = Uh + half*64;
        const float* vv = vws + half*64;
        #pragma unroll 2
        for (int k=0;k<64;k+=8){
          bf16x8 wv = *(const bf16x8*)(wr + k);
          acc += vv[k+0]*ftanh(b2f(wv[0]) + uh[k+0]) + vv[k+1]*ftanh(b2f(wv[1]) + uh[k+1])
               + vv[k+2]*ftanh(b2f(wv[2]) + uh[k+2]) + vv[k+3]*ftanh(b2f(wv[3]) + uh[k+3])
               + vv[k+4]*ftanh(b2f(wv[4]) + uh[k+4]) + vv[k+5]*ftanh(b2f(wv[5]) + uh[k+5])
               + vv[k+6]*ftanh(b2f(wv[6]) + uh[k+6]) + vv[k+7]*ftanh(b2f(wv[7]) + uh[k+7]);
        }
      }
      ep2[l][half] = acc;
    }
    __syncthreads();
    float ev = -1e30f;
    if (tid < 196) ev = vb0 + ep2[tid][0] + ep2[tid][1];
    float m = ev;
    #pragma unroll
    for (int off=32; off>0; off>>=1) m = fmaxf(m, __shfl_xor(m, off));
    if ((tid&63)==0) red[tid>>6] = m;
    __syncthreads();
    float mx = red[0];
    #pragma unroll
    for (int i=1;i<8;i++) mx = fmaxf(mx, red[i]);
    float ex = (tid<196) ? __expf(ev - mx) : 0.0f;
    float ss = ex;
    #pragma unroll
    for (int off=32; off>0; off>>=1) ss += __shfl_xor(ss, off);
    if ((tid&63)==0) red[8+(tid>>6)] = ss;
    if (tid<196) ew[tid] = ex;
    __syncthreads();
    float inv = __builtin_amdgcn_rcpf(red[8]+red[9]+red[10]+red[11]+red[12]+red[13]+red[14]+red[15]);
    // z partials: (f, l-chunk of 25)
    {
      int f = tid & 63, q = tid >> 6;
      int l0 = q*25, l1 = (l0+25 < 196) ? l0+25 : 196;
      const unsigned short* an = afbf + (size_t)n*12544 + (size_t)f*196;
      float acc = 0.f;
      for (int l2=l0; l2<l1; l2++) acc += ew[l2]*b2f(an[l2]);
      qp8[q][f] = acc;
    }
    __syncthreads();
    if (tid < 64){
      float z = bsig[tid]*(qp8[0][tid]+qp8[1][tid]+qp8[2][tid]+qp8[3][tid]
                          +qp8[4][tid]+qp8[5][tid]+qp8[6][tid]+qp8[7][tid])*inv;
      unsigned short zb = f2bf(z);
      ubf_all[((size_t)t*TN + n)*96 + 16 + tid] = zb;
      cbf[((size_t)n*TT + t)*608 + 512 + tid] = zb;
    }
  } else {
    // =================== gates Whh-part role: col-slice b (LDS-free, no syncs) ===================
    const int b = bid - TN;                       // 0..31
    const int w = tid>>6, l = tid&63, lr = l&15, li = l>>4, lk = li*8;
    const int g = w & 3, mh = w >> 2;             // wave -> (gate, M-half)
    bf16x8 wreg[16];
    {
      const unsigned short* wp = wgf + ((size_t)(g*32 + b)*19)*512 + (size_t)l*8;
      #pragma unroll
      for (int i=0;i<16;i++) wreg[i] = *(const bf16x8*)(wp + (size_t)i*512);
    }
    f32x4 acc[4];
    #pragma unroll
    for (int m2=0;m2<4;m2++) acc[m2] = (f32x4){0,0,0,0};
    #pragma unroll 4
    for (int kt=0; kt<16; ++kt){
      #pragma unroll
      for (int m2=0;m2<4;m2++){
        bf16x8 a = *(const bf16x8*)(hbf_in + (size_t)((mh*4+m2)*16 + lr)*512 + kt*32 + lk);
        acc[m2] = __builtin_amdgcn_mfma_f32_16x16x32_bf16(a, wreg[kt], acc[m2], 0,0,0);
      }
    }
    #pragma unroll
    for (int m2=0;m2<4;m2++){
      #pragma unroll
      for (int i=0;i<4;i++){
        int n2 = (mh*4+m2)*16 + li*4 + i;
        gpart[(((size_t)g*128 + n2)<<9) + b*16 + lr] = acc[m2][i];
      }
    }
  }
}

// ---------------- step B: z-part GEMM (direct u-frags) + cell update (32 blocks x 512 thr) ----------------
__global__ __launch_bounds__(512) void k_stepB(int t,
    unsigned short* __restrict__ hout,
    const unsigned short* __restrict__ ubf_all,
    const unsigned short* __restrict__ wgf, const float* __restrict__ gbias,
    const float* __restrict__ gpart,
    float* __restrict__ cbuf, unsigned short* __restrict__ cbf)
{
  const int b = blockIdx.x, tid = threadIdx.x;
  const int w = tid>>6, l = tid&63, lr = l&15, li = l>>4, lk = li*8;
  const int g = w & 3, mh = w >> 2;
  __shared__ float gsh[4][128][16];              // 32 KB: gate accumulators
  const unsigned short* ub = ubf_all + (size_t)t*TN*96;
  bf16x8 wz[3];
  {
    const unsigned short* wp = wgf + (((size_t)(g*32 + b)*19) + 16)*512 + (size_t)l*8;
    #pragma unroll
    for (int i=0;i<3;i++) wz[i] = *(const bf16x8*)(wp + (size_t)i*512);
  }
  // load gpart -> gsh (2048 float4 over 512 threads)
  for (int i = tid; i < 2048; i += 512){
    int gg = i>>9, r = i&511, n2 = r>>2, j4 = r&3;
    *(float4*)&gsh[gg][n2][j4*4] = *(const float4*)&gpart[(((size_t)gg*128 + n2)<<9) + b*16 + j4*4];
  }
  // z-part MFMA: wave (g,mh) covers m-tiles mh*4..mh*4+4, direct global u-frags
  f32x4 acc[4];
  #pragma unroll
  for (int m2=0;m2<4;m2++) acc[m2] = (f32x4){0,0,0,0};
  #pragma unroll
  for (int kt=0; kt<3; ++kt){
    #pragma unroll
    for (int m2=0;m2<4;m2++){
      bf16x8 a = *(const bf16x8*)(ub + (size_t)((mh*4+m2)*16 + lr)*96 + kt*32 + lk);
      acc[m2] = __builtin_amdgcn_mfma_f32_16x16x32_bf16(a, wz[kt], acc[m2], 0,0,0);
    }
  }
  __syncthreads();   // gsh fully loaded
  #pragma unroll
  for (int m2=0;m2<4;m2++)
    #pragma unroll
    for (int i=0;i<4;i++)
      gsh[g][(mh*4+m2)*16 + li*4 + i][lr] += acc[m2][i];
  __syncthreads();
  // cell update: 2048 cells, 4 per thread
  #pragma unroll
  for (int e=0;e<4;++e){
    int c = tid*4 + e;
    int nn = c>>4, j = c&15;
    int hidx = b*16 + j;
    float gi = gsh[0][nn][j] + gbias[         hidx];
    float gf = gsh[1][nn][j] + gbias[1*512 + hidx];
    float gg = gsh[2][nn][j] + gbias[2*512 + hidx];
    float go = gsh[3][nn][j] + gbias[3*512 + hidx];
    float cc = cbuf[nn*512 + hidx];
    float cs = fsigm(gf)*cc + fsigm(gi)*ftanh(gg);
    float h  = fsigm(go)*ftanh(cs);
    cbuf[nn*512 + hidx] = cs;
    unsigned short hb = f2bf(h);
    hout[nn*512 + hidx] = hb;
    cbf[((size_t)nn*TT + t)*608 + hidx] = hb;
  }
}

// ---------------- comb-input xe/se slices + ubf xe/pad prefill ----------------
__global__ __launch_bounds__(256) void k_cbf_xs(const float* __restrict__ xe, const float* __restrict__ se,
                                                unsigned short* __restrict__ cbf,
                                                unsigned short* __restrict__ ubf_all){
  int idx = blockIdx.x*256 + threadIdx.x;   // 2048 blocks: TN*TT*64
  if (idx >= TN*TT*64) return;
  int j = idx & 63, r = idx >> 6;
  int n = r >> 6, t = r & 63;
  if (j < 16)      cbf[(size_t)r*608 + 576 + j] = f2bf(xe[r*16 + j]);
  else if (j < 32) cbf[(size_t)r*608 + 592 + (j-16)] = f2bf(se[n*16 + (j-16)]);
  else if (j < 48) ubf_all[((size_t)t*TN + n)*96 + (j-32)] = f2bf(xe[r*16 + (j-32)]);
  else             ubf_all[((size_t)t*TN + n)*96 + 80 + (j-48)] = 0;
}

// ---------------- comb GEMM ----------------
__global__ __launch_bounds__(256) void k_comb(const unsigned short* __restrict__ cbf,
    const unsigned short* __restrict__ cwbf, const float* __restrict__ comb_b,
    unsigned short* __restrict__ ybf){
  int mbase = blockIdx.x*128, obase = blockIdx.y*128;
  int tid = threadIdx.x, w = tid>>6, l = tid&63;
  int lr = l&15, lk = (l>>4)*8;
  __shared__ unsigned short at[128*40];
  f32x4 acc[8][2];
  #pragma unroll
  for (int m=0;m<8;m++){ acc[m][0] = (f32x4){0,0,0,0}; acc[m][1] = (f32x4){0,0,0,0}; }
  for (int kt=0; kt<19; ++kt){
    int row = tid>>1, half = (tid&1)*16;
    const unsigned short* sp = cbf + (size_t)(mbase+row)*608 + kt*32 + half;
    *(float4*)&at[row*40 + half]     = *(const float4*)sp;
    *(float4*)&at[row*40 + half + 8] = *(const float4*)(sp + 8);
    __syncthreads();
    bf16x8 b0 = *(const bf16x8*)(cwbf + (size_t)(obase + (2*w+0)*16 + lr)*608 + kt*32 + lk);
    bf16x8 b1 = *(const bf16x8*)(cwbf + (size_t)(obase + (2*w+1)*16 + lr)*608 + kt*32 + lk);
    #pragma unroll
    for (int m=0;m<8;m++){
      bf16x8 afrag = *(const bf16x8*)&at[(m*16+lr)*40 + lk];
      acc[m][0] = __builtin_amdgcn_mfma_f32_16x16x32_bf16(afrag, b0, acc[m][0], 0,0,0);
      acc[m][1] = __builtin_amdgcn_mfma_f32_16x16x32_bf16(afrag, b1, acc[m][1], 0,0,0);
    }
    __syncthreads();
  }
  #pragma unroll
  for (int m=0;m<8;m++){
    #pragma unroll
    for (int j=0;j<2;j++){
      int o = obase + (2*w+j)*16 + lr;
      float cb = comb_b[o];
      #pragma unroll
      for (int i=0;i<4;i++){
        int r = mbase + m*16 + (l>>4)*4 + i;
        ybf[(size_t)r*1024 + o] = f2bf(ftanh(acc[m][j][i] + cb));
      }
    }
  }
}

// ---------------- out GEMM ----------------
__global__ __launch_bounds__(256) void k_out(const unsigned short* __restrict__ ybf,
    const unsigned short* __restrict__ owbf, const float* __restrict__ obias,
    float* __restrict__ obuf){
  int mbase = blockIdx.x*128;
  int tid = threadIdx.x, w = tid>>6, l = tid&63;
  int lr = l&15, lk = (l>>4)*8;
  __shared__ unsigned short at[128*40];
  f32x4 acc[8][2];
  #pragma unroll
  for (int m=0;m<8;m++){ acc[m][0] = (f32x4){0,0,0,0}; acc[m][1] = (f32x4){0,0,0,0}; }
  for (int kt=0; kt<32; ++kt){
    int row = tid>>1, half = (tid&1)*16;
    const unsigned short* sp = ybf + (size_t)(mbase+row)*1024 + kt*32 + half;
    *(float4*)&at[row*40 + half]     = *(const float4*)sp;
    *(float4*)&at[row*40 + half + 8] = *(const float4*)(sp + 8);
    __syncthreads();
    bf16x8 b0 = *(const bf16x8*)(owbf + ((2*w+0)*16 + lr)*1024 + kt*32 + lk);
    bf16x8 b1 = *(const bf16x8*)(owbf + ((2*w+1)*16 + lr)*1024 + kt*32 + lk);
    #pragma unroll
    for (int m=0;m<8;m++){
      bf16x8 afrag = *(const bf16x8*)&at[(m*16+lr)*40 + lk];
      acc[m][0] = __builtin_amdgcn_mfma_f32_16x16x32_bf16(afrag, b0, acc[m][0], 0,0,0);
      acc[m][1] = __builtin_amdgcn_mfma_f32_16x16x32_bf16(afrag, b1, acc[m][1], 0,0,0);
    }
    __syncthreads();
  }
  #pragma unroll
  for (int m=0;m<8;m++){
    #pragma unroll
    for (int j=0;j<2;j++){
      int o = (2*w+j)*16 + lr;
      float ob = obias[o];
      #pragma unroll
      for (int i=0;i<4;i++){
        int r = mbase + m*16 + (l>>4)*4 + i;
        obuf[(size_t)r*128 + o] = acc[m][j][i] + ob;
      }
    }
  }
}

// ---------------- postprocess ----------------
__global__ __launch_bounds__(256) void k_post(const float* __restrict__ obuf, float* __restrict__ out){
  int r = blockIdx.x*256 + threadIdx.x;
  if (r >= TN*TT) return;
  const float* row = obuf + (size_t)r*128;
  float mx = -1e30f;
  #pragma unroll
  for (int k2=0;k2<20;k2++) mx = fmaxf(mx, row[k2]);
  float e[20]; float s = 0;
  #pragma unroll
  for (int k2=0;k2<20;k2++){ e[k2] = __expf(row[k2]-mx); s += e[k2]; }
  float inv = __builtin_amdgcn_rcpf(s);
  float* mixo  = out;
  float* meano = out + 163840;
  float* scaleo= out + 491520;
  float* corro = out + 819200;
  float* vlogo = out + 983040;
  #pragma unroll
  for (int k2=0;k2<20;k2++) mixo[r*20+k2] = e[k2]*inv;
  #pragma unroll
  for (int j=0;j<40;j++) meano[r*40+j] = row[20+j];
  #pragma unroll
  for (int j=0;j<40;j++) scaleo[r*40+j] = __expf(row[60+j]);
  #pragma unroll
  for (int k2=0;k2<20;k2++) corro[r*20+k2] = ftanh(row[100+k2]);
  vlogo[r] = row[120];
}

extern "C" void kernel_launch(void* const* d_in, const int* in_sizes, int n_in,
                              void* d_out, int out_size, void* d_ws, size_t ws_size,
                              hipStream_t stream){
  const float* x       = (const float*)d_in[0];
  const float* x_canv  = (const float*)d_in[1];
  const float* start_  = (const float*)d_in[2];
  const float* conv1_w = (const float*)d_in[3];
  const float* conv1_b = (const float*)d_in[4];
  const float* conv2_w = (const float*)d_in[5];
  const float* conv2_b = (const float*)d_in[6];
  const float* conv3_w = (const float*)d_in[7];
  const float* conv3_b = (const float*)d_in[8];
  const float* init_w  = (const float*)d_in[9];
  const float* init_b  = (const float*)d_in[10];
  const float* Uw      = (const float*)d_in[11];
  const float* Ub      = (const float*)d_in[12];
  const float* Ww      = (const float*)d_in[13];
  const float* Wb      = (const float*)d_in[14];
  const float* vw      = (const float*)d_in[15];
  const float* vb      = (const float*)d_in[16];
  const float* beta_w  = (const float*)d_in[17];
  const float* beta_b  = (const float*)d_in[18];
  const float* xemb_w  = (const float*)d_in[19];
  const float* xemb_b  = (const float*)d_in[20];
  const float* semb_w  = (const float*)d_in[21];
  const float* semb_b  = (const float*)d_in[22];
  const float* Wih     = (const float*)d_in[23];
  const float* Whh     = (const float*)d_in[24];
  const float* bih     = (const float*)d_in[25];
  const float* bhh     = (const float*)d_in[26];
  const float* comb_w  = (const float*)d_in[27];
  const float* comb_b  = (const float*)d_in[28];
  const float* out_w   = (const float*)d_in[29];
  const float* out_b   = (const float*)d_in[30];
  (void)in_sizes; (void)n_in; (void)out_size; (void)ws_size;

  char* wsb = (char*)d_ws;
  size_t off = 0;
  auto alloc = [&](size_t bytes)->char*{
    char* p = wsb + off;
    off = (off + bytes + 255) & ~(size_t)255;
    return p;
  };
  unsigned short* c1bf   = (unsigned short*)alloc((size_t)TN*16*784*2);
  unsigned short* a2     = (unsigned short*)alloc((size_t)100352*160*2);  // a3 aliases a2
  unsigned short* a3     = a2;
  unsigned short* c2bf   = (unsigned short*)alloc((size_t)100352*32*2);
  unsigned short* afbf   = (unsigned short*)alloc((size_t)TN*64*196*2);
  unsigned short* abf    = (unsigned short*)alloc((size_t)TN*196*64*2);
  float*          amean  = (float*)alloc((size_t)TN*64*4);
  float*          xe     = (float*)alloc((size_t)TN*TT*16*4);
  float*          se     = (float*)alloc((size_t)TN*16*4);
  unsigned short* wabf   = (unsigned short*)alloc((size_t)TN*196*128*2);
  float*          cbuf   = (float*)alloc((size_t)TN*512*4);
  unsigned short* hbfA   = (unsigned short*)alloc((size_t)TN*512*2);
  unsigned short* hbfB   = (unsigned short*)alloc((size_t)TN*512*2);
  unsigned short* ubf_all= (unsigned short*)alloc((size_t)TT*TN*96*2);
  unsigned short* cbf    = (unsigned short*)alloc((size_t)TN*TT*608*2);
  unsigned short* ybf    = (unsigned short*)alloc((size_t)TN*TT*1024*2);
  float*          obuf   = (float*)alloc((size_t)TN*TT*128*4);
  unsigned short* wgf    = (unsigned short*)alloc((size_t)1245184*2);
  float*          gbias  = (float*)alloc((size_t)2048*4);
  float*          gpart  = (float*)alloc((size_t)4*128*512*4);
  unsigned short* cwbf   = (unsigned short*)alloc((size_t)1024*608*2);
  unsigned short* owbf   = (unsigned short*)alloc((size_t)128*1024*2);
  float*          obias  = (float*)alloc((size_t)128*4);
  unsigned short* uwbf   = (unsigned short*)alloc((size_t)128*512*2);
  unsigned short* betabf = (unsigned short*)alloc((size_t)64*512*2);
  unsigned short* wwbf   = (unsigned short*)alloc((size_t)128*64*2);
  unsigned short* w2b    = (unsigned short*)alloc((size_t)32*160*2);
  unsigned short* w3b    = (unsigned short*)alloc((size_t)64*320*2);

  hipLaunchKernelGGL(k_conv1, dim3(6272), dim3(256), 0, stream, x_canv, conv1_w, conv1_b, c1bf);
  hipLaunchKernelGGL(k_prep, dim3(8334), dim3(256), 0, stream,
                     Whh, Wih, bih, bhh, comb_w, out_w, out_b, Uw, beta_w, Ww, conv2_w, conv3_w,
                     wgf, gbias, cwbf, owbf, obias, uwbf, betabf, wwbf, w2b, w3b);
  hipLaunchKernelGGL(k_im2col2, dim3(62720), dim3(256), 0, stream, c1bf, a2);
  hipLaunchKernelGGL(k_gconv2, dim3(784), dim3(256), 0, stream, a2, w2b, conv2_b, c2bf);
  hipLaunchKernelGGL(k_im2col3, dim3(31360), dim3(256), 0, stream, c2bf, a3);
  hipLaunchKernelGGL(k_gconv3, dim3(196), dim3(256), 0, stream, a3, w3b, conv3_b, afbf, abf);
  hipLaunchKernelGGL(k_amean, dim3(128), dim3(64), 0, stream, afbf, amean);
  hipLaunchKernelGGL(k_embed, dim3(520), dim3(256), 0, stream, x, start_, xemb_w, xemb_b, semb_w, semb_b, xe, se);
  hipLaunchKernelGGL(k_init, dim3(512), dim3(256), 0, stream, amean, se, init_w, init_b, hbfA, cbuf);
  hipLaunchKernelGGL(k_wa, dim3(196), dim3(256), 0, stream, abf, wwbf, Wb, wabf);
  hipLaunchKernelGGL(k_cbf_xs, dim3(2048), dim3(256), 0, stream, xe, se, cbf, ubf_all);

  for (int t = 0; t < TT; ++t){
    unsigned short* hin  = (t & 1) ? hbfB : hbfA;
    unsigned short* hout = (t & 1) ? hbfA : hbfB;
    hipLaunchKernelGGL(k_stepA, dim3(160), dim3(512), 0, stream, t,
                       hin, uwbf, Ub, betabf, beta_b, vw, vb, wabf, afbf, ubf_all, cbf, wgf, gpart);
    hipLaunchKernelGGL(k_stepB, dim3(32), dim3(512), 0, stream, t,
                       hout, ubf_all, wgf, gbias, gpart, cbuf, cbf);
  }

  hipLaunchKernelGGL(k_comb, dim3(64, 8), dim3(256), 0, stream, cbf, cwbf, comb_b, ybf);
  hipLaunchKernelGGL(k_out, dim3(64), dim3(256), 0, stream, ybf, owbf, obias, obuf);
  hipLaunchKernelGGL(k_post, dim3(32), dim3(256), 0, stream, obuf, (float*)d_out);
}

// Round 11
// 1750.305 us; speedup vs baseline: 1.2532x; 1.2532x over previous
//
#include <hip/hip_runtime.h>

// LSTMConditioned: conv-encoder + attention-LSTM (T=64) + MDN head.
// N=128, T=64, HID=512, COMB=1024, ATT=128, K=20, D=2, FMAP=64, L=196, ODIM=121.
// Recurrence: 2 launches/step (launch-boundary sync; in-kernel cross-block sync measured
// 44-183 us/step on MI355X — never again). stepA (160 blocks x 512 thr) = attention
// (blocks 0-127) || gates Whh-part GEMM (blocks 128-159, LDS double-buffered staging).
// stepB (32 blocks x 256 thr) = z-part GEMM + fused cell update.
// Convs: im2col fused into the GEMM staging (no materialized patch matrices).

#define TN 128
#define TT 64

typedef __attribute__((ext_vector_type(4))) float f32x4;
typedef __attribute__((ext_vector_type(8))) short bf16x8;

__device__ __forceinline__ float fsigm(float x){ return __builtin_amdgcn_rcpf(1.0f + __expf(-x)); }
__device__ __forceinline__ float ftanh(float x){ return 1.0f - 2.0f*__builtin_amdgcn_rcpf(1.0f + __expf(2.0f*x)); }
__device__ __forceinline__ unsigned short f2bf(float f){
  unsigned int u = __float_as_uint(f);
  u += 0x7fffu + ((u >> 16) & 1u);
  return (unsigned short)(u >> 16);
}
__device__ __forceinline__ float b2f(unsigned short u){ return __uint_as_float(((unsigned)u)<<16); }

// ---------------- conv1 (direct, small), bf16 out ----------------
__global__ __launch_bounds__(256) void k_conv1(const float* __restrict__ xc, const float* __restrict__ w,
                                               const float* __restrict__ b, unsigned short* __restrict__ c1bf){
  int idx = blockIdx.x*256 + threadIdx.x;
  if (idx >= TN*16*784) return;
  int p = idx % 784, oc = (idx/784) & 15, n = idx/(784*16);
  int py = p/28, px = p%28;
  const float* src = xc + n*784;
  float acc = b[oc];
  #pragma unroll
  for (int ky=0;ky<3;ky++){
    int iy = py+ky-1; if (iy<0||iy>=28) continue;
    #pragma unroll
    for (int kx=0;kx<3;kx++){
      int ix = px+kx-1; if (ix<0||ix>=28) continue;
      acc += (src[iy*28+ix]-0.0243f)*(1.0f/0.1383f) * w[oc*9+ky*3+kx];
    }
  }
  c1bf[idx] = f2bf(fmaxf(acc, 0.0f));
}

// ---------------- conv2 GEMM with fused im2col staging ----------------
__global__ __launch_bounds__(256) void k_gconv2(const unsigned short* __restrict__ c1bf,
    const unsigned short* __restrict__ w2b, const float* __restrict__ b2,
    unsigned short* __restrict__ c2bf){
  int mbase = blockIdx.x*128;           // 784 blocks
  int tid = threadIdx.x, w = tid>>6, l = tid&63;
  int lr = l&15, lk = (l>>4)*8;
  __shared__ unsigned short at[128*168];
  {
    int row = tid>>1, off = (tid&1)*80;
    int r = mbase + row;
    int p = r % 784, n = r / 784;
    int py = p/28, px = p%28;
    for (int kk=0; kk<80; ++kk){
      int k = off + kk;
      unsigned short v = 0;
      if (k < 144){
        int ic = k/9, rem = k - ic*9, ky = rem/3, kx = rem - ky*3;
        int iy = py+ky-1, ix = px+kx-1;
        if (iy>=0 && iy<28 && ix>=0 && ix<28) v = c1bf[(n*16+ic)*784 + iy*28+ix];
      }
      at[row*168 + k] = v;
    }
  }
  __syncthreads();
  f32x4 acc[2][2];
  #pragma unroll
  for (int mi=0;mi<2;mi++){ acc[mi][0]=(f32x4){0,0,0,0}; acc[mi][1]=(f32x4){0,0,0,0}; }
  for (int kt=0; kt<5; ++kt){
    bf16x8 b0 = *(const bf16x8*)(w2b + (0*16+lr)*160 + kt*32 + lk);
    bf16x8 b1 = *(const bf16x8*)(w2b + (1*16+lr)*160 + kt*32 + lk);
    #pragma unroll
    for (int mi=0;mi<2;mi++){
      bf16x8 afrag = *(const bf16x8*)&at[((2*w+mi)*16+lr)*168 + kt*32 + lk];
      acc[mi][0] = __builtin_amdgcn_mfma_f32_16x16x32_bf16(afrag, b0, acc[mi][0], 0,0,0);
      acc[mi][1] = __builtin_amdgcn_mfma_f32_16x16x32_bf16(afrag, b1, acc[mi][1], 0,0,0);
    }
  }
  #pragma unroll
  for (int mi=0;mi<2;mi++){
    #pragma unroll
    for (int j=0;j<2;j++){
      int oc = j*16 + lr;
      float bb = b2[oc];
      #pragma unroll
      for (int i=0;i<4;i++){
        int r = mbase + (2*w+mi)*16 + (l>>4)*4 + i;
        c2bf[(size_t)r*32 + oc] = f2bf(fmaxf(acc[mi][j][i] + bb, 0.0f));
      }
    }
  }
}

// ---------------- conv3 GEMM with fused im2col (stride-2): afbf[n][f][l] + abf[r][f] ----------------
__global__ __launch_bounds__(256) void k_gconv3(const unsigned short* __restrict__ c2bf,
    const unsigned short* __restrict__ w3b, const float* __restrict__ b3,
    unsigned short* __restrict__ afbf, unsigned short* __restrict__ abf){
  int mbase = blockIdx.x*128;           // 196 blocks
  int tid = threadIdx.x, w = tid>>6, l = tid&63;
  int lr = l&15, lk = (l>>4)*8;
  __shared__ unsigned short at[128*168];
  f32x4 acc[2][4];
  #pragma unroll
  for (int mi=0;mi<2;mi++)
    #pragma unroll
    for (int j=0;j<4;j++) acc[mi][j]=(f32x4){0,0,0,0};
  int srow = tid>>1, soff = (tid&1)*80;
  int sr = mbase + srow;
  int sp2 = sr % 196, sn = sr / 196;
  int spy = sp2/14, spx = sp2%14;
  for (int kt2=0; kt2<2; ++kt2){
    for (int kk=0; kk<80; ++kk){
      int k = kt2*160 + soff + kk;
      unsigned short v = 0;
      if (k < 288){
        int ic = k/9, rem = k - ic*9, ky = rem/3, kx = rem - ky*3;
        int iy = 2*spy+ky-1, ix = 2*spx+kx-1;
        if (iy>=0 && iy<28 && ix>=0 && ix<28) v = c2bf[(size_t)(sn*784 + iy*28+ix)*32 + ic];
      }
      at[srow*168 + soff + kk] = v;
    }
    __syncthreads();
    for (int kt=0; kt<5; ++kt){
      #pragma unroll
      for (int mi=0;mi<2;mi++){
        bf16x8 afrag = *(const bf16x8*)&at[((2*w+mi)*16+lr)*168 + kt*32 + lk];
        #pragma unroll
        for (int j=0;j<4;j++){
          bf16x8 bf = *(const bf16x8*)(w3b + (size_t)(j*16+lr)*320 + kt2*160 + kt*32 + lk);
          acc[mi][j] = __builtin_amdgcn_mfma_f32_16x16x32_bf16(afrag, bf, acc[mi][j], 0,0,0);
        }
      }
    }
    __syncthreads();
  }
  #pragma unroll
  for (int mi=0;mi<2;mi++){
    #pragma unroll
    for (int j=0;j<4;j++){
      int oc = j*16 + lr;
      float bb = b3[oc];
      #pragma unroll
      for (int i=0;i<4;i++){
        int r = mbase + (2*w+mi)*16 + (l>>4)*4 + i;
        int n = r/196, p = r - n*196;
        float v = ftanh(acc[mi][j][i] + bb);
        unsigned short vb16 = f2bf(v);
        afbf[(size_t)(n*64+oc)*196 + p] = vb16;
        abf[(size_t)r*64 + oc] = vb16;
      }
    }
  }
}

__global__ __launch_bounds__(64) void k_amean(const unsigned short* __restrict__ afbf, float* __restrict__ amean){
  int n = blockIdx.x, f = threadIdx.x;
  const unsigned short* row = afbf + (size_t)(n*64+f)*196;
  float s = 0;
  for (int l=0;l<196;l++) s += b2f(row[l]);
  amean[n*64+f] = s * (1.0f/196.0f);
}

// ---------------- embeddings / init ----------------
__global__ __launch_bounds__(256) void k_embed(const float* __restrict__ x, const float* __restrict__ start,
    const float* __restrict__ xw, const float* __restrict__ xb,
    const float* __restrict__ sw, const float* __restrict__ sb,
    float* __restrict__ xe, float* __restrict__ se){
  int idx = blockIdx.x*256 + threadIdx.x;
  if (idx < TN*TT*16){
    int j = idx & 15, t = (idx>>4) & 63, n = idx>>10;
    float acc = xb[j];
    if (t > 0){
      const float* xp = x + (n*TT + t-1)*2;
      acc += xp[0]*xw[j*2] + xp[1]*xw[j*2+1];
    }
    xe[idx] = ftanh(acc);
  } else if (idx < TN*TT*16 + TN*16){
    int k2 = idx - TN*TT*16;
    int j = k2 & 15, n = k2 >> 4;
    float acc = sb[j] + start[n*2]*sw[j*2] + start[n*2+1]*sw[j*2+1];
    se[k2] = ftanh(acc);
  }
}

__global__ __launch_bounds__(256) void k_init(const float* __restrict__ amean, const float* __restrict__ se,
    const float* __restrict__ w, const float* __restrict__ b,
    unsigned short* __restrict__ hbfA, float* __restrict__ cbuf){
  int idx = blockIdx.x*256 + threadIdx.x;
  if (idx >= TN*1024) return;
  int o = idx & 1023, n = idx >> 10;
  const float* wr = w + o*80;
  float acc = b[o];
  for (int k2=0;k2<64;k2++) acc += amean[n*64+k2]*wr[k2];
  for (int k2=0;k2<16;k2++) acc += se[n*16+k2]*wr[64+k2];
  float v = ftanh(acc);
  if (o & 1) cbuf[n*512 + (o>>1)] = v;
  else       hbfA[n*512 + (o>>1)] = f2bf(v);
}

// ---------------- weight prep ----------------
// wgf: gates weights in MFMA fragment order: frag (g,b,kt) at ((g*32+b)*19+kt)*512,
// lane l elem j = W[g*512+b*16+(l&15)][kt*32+(l>>4)*8+j], W = [Whh | Wih(pad 96)].
__global__ __launch_bounds__(256) void k_prep(
    const float* __restrict__ Whh, const float* __restrict__ Wih,
    const float* __restrict__ bih, const float* __restrict__ bhh,
    const float* __restrict__ comb_w, const float* __restrict__ out_w, const float* __restrict__ out_b,
    const float* __restrict__ Uw, const float* __restrict__ beta_w, const float* __restrict__ Ww,
    const float* __restrict__ conv2_w, const float* __restrict__ conv3_w,
    unsigned short* __restrict__ wgf, float* __restrict__ gbias,
    unsigned short* __restrict__ cwbf, unsigned short* __restrict__ owbf, float* __restrict__ obias,
    unsigned short* __restrict__ uwbf, unsigned short* __restrict__ betabf, unsigned short* __restrict__ wwbf,
    unsigned short* __restrict__ w2b, unsigned short* __restrict__ w3b){
  int idx = blockIdx.x*256 + threadIdx.x;
  if (idx < 1245184){
    int fragi = idx >> 9;
    int lane8 = idx & 511;
    int lane = lane8 >> 3, j = lane8 & 7;
    int g = fragi / 608;
    int rem = fragi - g*608;
    int b = rem / 19, kt = rem - b*19;
    int row = g*512 + b*16 + (lane & 15);
    int col = kt*32 + (lane >> 4)*8 + j;
    float v = 0.f;
    if (col < 512) v = Whh[(size_t)row*512 + col];
    else { int c2 = col - 512; if (c2 < 80) v = Wih[(size_t)row*80 + c2]; }
    wgf[idx] = f2bf(v);
    return;
  }
  idx -= 1245184;
  if (idx < 2048){ gbias[idx] = bih[idx]+bhh[idx]; return; }
  idx -= 2048;
  if (idx < 622592){ cwbf[idx] = f2bf(comb_w[idx]); return; }
  idx -= 622592;
  if (idx < 131072){ int o = idx>>10, k2 = idx & 1023; owbf[idx] = (o<121)? f2bf(out_w[o*1024+k2]) : (unsigned short)0; return; }
  idx -= 131072;
  if (idx < 128){ obias[idx] = (idx<121)? out_b[idx] : 0.0f; return; }
  idx -= 128;
  if (idx < 65536){ uwbf[idx] = f2bf(Uw[idx]); return; }
  idx -= 65536;
  if (idx < 32768){ betabf[idx] = f2bf(beta_w[idx]); return; }
  idx -= 32768;
  if (idx < 8192){ wwbf[idx] = f2bf(Ww[idx]); return; }
  idx -= 8192;
  if (idx < 5120){ int o = idx/160, k2 = idx - o*160; w2b[idx] = (k2<144)? f2bf(conv2_w[o*144+k2]) : (unsigned short)0; return; }
  idx -= 5120;
  if (idx < 20480){ int o = idx/320, k2 = idx - o*320; w3b[idx] = (k2<288)? f2bf(conv3_w[o*288+k2]) : (unsigned short)0; return; }
}

// ---------------- W_a = a @ Ww.T + Wb (MFMA), stored bf16 [n][l][att] ----------------
__global__ __launch_bounds__(256) void k_wa(const unsigned short* __restrict__ abf,
    const unsigned short* __restrict__ wwbf, const float* __restrict__ Wb,
    unsigned short* __restrict__ wabf){
  int mbase = blockIdx.x*128;
  int tid = threadIdx.x, w = tid>>6, l = tid&63;
  int lr = l & 15, lk = (l>>4)*8;
  __shared__ unsigned short at[128*40];
  f32x4 acc[8][2];
  #pragma unroll
  for (int m=0;m<8;m++){ acc[m][0] = (f32x4){0,0,0,0}; acc[m][1] = (f32x4){0,0,0,0}; }
  for (int kt=0; kt<2; ++kt){
    int row = tid>>1, half = (tid&1)*16;
    const unsigned short* sp = abf + (mbase+row)*64 + kt*32 + half;
    *(float4*)&at[row*40 + half]     = *(const float4*)sp;
    *(float4*)&at[row*40 + half + 8] = *(const float4*)(sp + 8);
    __syncthreads();
    bf16x8 b0 = *(const bf16x8*)(wwbf + ((2*w+0)*16 + lr)*64 + kt*32 + lk);
    bf16x8 b1 = *(const bf16x8*)(wwbf + ((2*w+1)*16 + lr)*64 + kt*32 + lk);
    #pragma unroll
    for (int m=0;m<8;m++){
      bf16x8 afrag = *(const bf16x8*)&at[(m*16+lr)*40 + lk];
      acc[m][0] = __builtin_amdgcn_mfma_f32_16x16x32_bf16(afrag, b0, acc[m][0], 0,0,0);
      acc[m][1] = __builtin_amdgcn_mfma_f32_16x16x32_bf16(afrag, b1, acc[m][1], 0,0,0);
    }
    __syncthreads();
  }
  #pragma unroll
  for (int m=0;m<8;m++){
    #pragma unroll
    for (int j=0;j<2;j++){
      int att = (2*w+j)*16 + lr;
      float wb = Wb[att];
      #pragma unroll
      for (int i=0;i<4;i++){
        int arow = mbase + m*16 + (l>>4)*4 + i;
        int n = arow/196, l2 = arow - n*196;
        wabf[((size_t)n*196 + l2)*128 + att] = f2bf(acc[m][j][i] + wb);
      }
    }
  }
}

// ---------------- step A: attention (blocks 0-127) || gates-h GEMM (blocks 128-159) ----------------
__global__ __launch_bounds__(512) void k_stepA(int t,
    const unsigned short* __restrict__ hbf_in,
    const unsigned short* __restrict__ uwbf, const float* __restrict__ Ub,
    const unsigned short* __restrict__ betabf, const float* __restrict__ beta_b,
    const float* __restrict__ vw, const float* __restrict__ vb,
    const unsigned short* __restrict__ wabf, const unsigned short* __restrict__ afbf,
    unsigned short* __restrict__ ubf_all, unsigned short* __restrict__ cbf,
    const unsigned short* __restrict__ wgf, float* __restrict__ gpart)
{
  const int bid = blockIdx.x, tid = threadIdx.x;
  __shared__ __align__(16) float Uh[128];
  __shared__ __align__(16) float vws[128];
  __shared__ float bsig[64];
  __shared__ float ew[196];
  __shared__ float red[16];
  __shared__ float up[4][128];
  __shared__ float qp8[8][64];
  __shared__ float ep2[256][2];
  __shared__ __align__(16) unsigned short at2[2][128*36];

  if (bid < TN){
    // =================== attention role: sample n = bid ===================
    const int n = bid;
    if (tid < 128) vws[tid] = vw[tid];
    const float vb0 = vb[0];
    // Uh partials: (att, k-quarter), h read directly from global (L2-hot, broadcast per wave)
    {
      int att = tid & 127, q = tid >> 7;
      const unsigned short* uw = uwbf + (size_t)att*512 + q*128;
      const unsigned short* hh = hbf_in + (size_t)n*512 + q*128;
      float acc = 0.f;
      #pragma unroll 4
      for (int k=0;k<128;k+=8){
        bf16x8 v = *(const bf16x8*)(uw + k);
        bf16x8 hv = *(const bf16x8*)(hh + k);
        acc += b2f(hv[0])*b2f(v[0]) + b2f(hv[1])*b2f(v[1]) + b2f(hv[2])*b2f(v[2]) + b2f(hv[3])*b2f(v[3])
             + b2f(hv[4])*b2f(v[4]) + b2f(hv[5])*b2f(v[5]) + b2f(hv[6])*b2f(v[6]) + b2f(hv[7])*b2f(v[7]);
      }
      up[q][att] = acc;
    }
    // beta partials: (f, k-eighth)
    {
      int f = tid & 63, q = tid >> 6;
      const unsigned short* bw = betabf + (size_t)f*512 + q*64;
      const unsigned short* hh = hbf_in + (size_t)n*512 + q*64;
      float acc = 0.f;
      #pragma unroll 4
      for (int k=0;k<64;k+=8){
        bf16x8 v = *(const bf16x8*)(bw + k);
        bf16x8 hv = *(const bf16x8*)(hh + k);
        acc += b2f(hv[0])*b2f(v[0]) + b2f(hv[1])*b2f(v[1]) + b2f(hv[2])*b2f(v[2]) + b2f(hv[3])*b2f(v[3])
             + b2f(hv[4])*b2f(v[4]) + b2f(hv[5])*b2f(v[5]) + b2f(hv[6])*b2f(v[6]) + b2f(hv[7])*b2f(v[7]);
      }
      qp8[q][f] = acc;
    }
    __syncthreads();
    if (tid < 128) Uh[tid] = Ub[tid] + up[0][tid]+up[1][tid]+up[2][tid]+up[3][tid];
    else if (tid < 192){
      int f = tid-128;
      bsig[f] = fsigm(beta_b[f] + qp8[0][f]+qp8[1][f]+qp8[2][f]+qp8[3][f]
                                + qp8[4][f]+qp8[5][f]+qp8[6][f]+qp8[7][f]);
    }
    __syncthreads();
    // e partials: (l, att-half)
    {
      int l = tid >> 1, half = tid & 1;
      float acc = 0.f;
      if (l < 196){
        const unsigned short* wr = wabf + ((size_t)n*196 + l)*128 + half*64;
        const float* uh = Uh + half*64;
        const float* vv = vws + half*64;
        #pragma unroll 2
        for (int k=0;k<64;k+=8){
          bf16x8 wv = *(const bf16x8*)(wr + k);
          acc += vv[k+0]*ftanh(b2f(wv[0]) + uh[k+0]) + vv[k+1]*ftanh(b2f(wv[1]) + uh[k+1])
               + vv[k+2]*ftanh(b2f(wv[2]) + uh[k+2]) + vv[k+3]*ftanh(b2f(wv[3]) + uh[k+3])
               + vv[k+4]*ftanh(b2f(wv[4]) + uh[k+4]) + vv[k+5]*ftanh(b2f(wv[5]) + uh[k+5])
               + vv[k+6]*ftanh(b2f(wv[6]) + uh[k+6]) + vv[k+7]*ftanh(b2f(wv[7]) + uh[k+7]);
        }
      }
      ep2[l][half] = acc;
    }
    __syncthreads();
    float ev = -1e30f;
    if (tid < 196) ev = vb0 + ep2[tid][0] + ep2[tid][1];
    float m = ev;
    #pragma unroll
    for (int off=32; off>0; off>>=1) m = fmaxf(m, __shfl_xor(m, off));
    if ((tid&63)==0) red[tid>>6] = m;
    __syncthreads();
    float mx = red[0];
    #pragma unroll
    for (int i=1;i<8;i++) mx = fmaxf(mx, red[i]);
    float ex = (tid<196) ? __expf(ev - mx) : 0.0f;
    float ss = ex;
    #pragma unroll
    for (int off=32; off>0; off>>=1) ss += __shfl_xor(ss, off);
    if ((tid&63)==0) red[8+(tid>>6)] = ss;
    if (tid<196) ew[tid] = ex;
    __syncthreads();
    float inv = __builtin_amdgcn_rcpf(red[8]+red[9]+red[10]+red[11]+red[12]+red[13]+red[14]+red[15]);
    // z partials: (f, l-chunk of 25)
    {
      int f = tid & 63, q = tid >> 6;
      int l0 = q*25, l1 = (l0+25 < 196) ? l0+25 : 196;
      const unsigned short* an = afbf + (size_t)n*12544 + (size_t)f*196;
      float acc = 0.f;
      for (int l2=l0; l2<l1; l2++) acc += ew[l2]*b2f(an[l2]);
      qp8[q][f] = acc;
    }
    __syncthreads();
    if (tid < 64){
      float z = bsig[tid]*(qp8[0][tid]+qp8[1][tid]+qp8[2][tid]+qp8[3][tid]
                          +qp8[4][tid]+qp8[5][tid]+qp8[6][tid]+qp8[7][tid])*inv;
      unsigned short zb = f2bf(z);
      ubf_all[((size_t)t*TN + n)*96 + 16 + tid] = zb;
      cbf[((size_t)n*TT + t)*608 + 512 + tid] = zb;
    }
  } else {
    // =================== gates Whh-part role: col-slice b (LDS double-buffered) ===================
    const int b = bid - TN;                       // 0..31
    const int w = tid>>6, l = tid&63, lr = l&15, li = l>>4, lk = li*8;
    const int g = w & 3, mh = w >> 2;             // wave -> (gate, M-half)
    bf16x8 wreg[16];
    {
      const unsigned short* wp = wgf + ((size_t)(g*32 + b)*19)*512 + (size_t)l*8;
      #pragma unroll
      for (int i=0;i<16;i++) wreg[i] = *(const bf16x8*)(wp + (size_t)i*512);
    }
    f32x4 acc[4];
    #pragma unroll
    for (int m2=0;m2<4;m2++) acc[m2] = (f32x4){0,0,0,0};
    {
      int row = tid>>2, seg = (tid&3)*8;
      *(float4*)&at2[0][row*36+seg] = *(const float4*)(hbf_in + (size_t)row*512 + seg);
    }
    __syncthreads();
    for (int kt=0; kt<16; ++kt){
      if (kt+1 < 16){
        int row = tid>>2, seg = (tid&3)*8;
        *(float4*)&at2[(kt+1)&1][row*36+seg] = *(const float4*)(hbf_in + (size_t)row*512 + (kt+1)*32 + seg);
      }
      #pragma unroll
      for (int m2=0;m2<4;m2++){
        bf16x8 a = *(const bf16x8*)&at2[kt&1][((mh*4+m2)*16 + lr)*36 + lk];
        acc[m2] = __builtin_amdgcn_mfma_f32_16x16x32_bf16(a, wreg[kt], acc[m2], 0,0,0);
      }
      __syncthreads();
    }
    #pragma unroll
    for (int m2=0;m2<4;m2++){
      #pragma unroll
      for (int i=0;i<4;i++){
        int n2 = (mh*4+m2)*16 + li*4 + i;
        gpart[(((size_t)g*128 + n2)<<9) + b*16 + lr] = acc[m2][i];
      }
    }
  }
}

// ---------------- step B: z-part GEMM (3 K-tiles) + cell update (32 blocks x 256 thr) ----------------
__global__ __launch_bounds__(256) void k_stepB(int t,
    unsigned short* __restrict__ hout,
    const unsigned short* __restrict__ ubf_all,
    const unsigned short* __restrict__ wgf, const float* __restrict__ gbias,
    const float* __restrict__ gpart,
    float* __restrict__ cbuf, unsigned short* __restrict__ cbf)
{
  const int b = blockIdx.x, tid = threadIdx.x;
  const int w = tid>>6, l = tid&63, lr = l&15, li = l>>4, lk = li*8;
  __shared__ float gsh[4][128][16];              // 32 KB: gate accumulators
  __shared__ __align__(16) unsigned short at[128*100];  // u-tile (96 cols + pad)
  const unsigned short* ub = ubf_all + (size_t)t*TN*96;
  // load gpart -> gsh (2048 float4)
  for (int i = tid; i < 2048; i += 256){
    int g = i>>9, r = i&511, n2 = r>>2, j4 = r&3;
    *(float4*)&gsh[g][n2][j4*4] = *(const float4*)&gpart[(((size_t)g*128 + n2)<<9) + b*16 + j4*4];
  }
  // stage u (128 rows x 96 cols)
  for (int i = tid; i < 1536; i += 256){
    int row = i/12, c8 = i - row*12;
    *(float4*)&at[row*100 + c8*8] = *(const float4*)(ub + (size_t)row*96 + c8*8);
  }
  bf16x8 wz[3];
  {
    const unsigned short* wp = wgf + (((size_t)(w*32 + b)*19) + 16)*512 + (size_t)l*8;
    #pragma unroll
    for (int i=0;i<3;i++) wz[i] = *(const bf16x8*)(wp + (size_t)i*512);
  }
  f32x4 acc[8];
  #pragma unroll
  for (int m=0;m<8;m++) acc[m] = (f32x4){0,0,0,0};
  __syncthreads();
  #pragma unroll
  for (int kt=0; kt<3; ++kt){
    #pragma unroll
    for (int m=0;m<8;m++){
      bf16x8 a = *(const bf16x8*)&at[(m*16+lr)*100 + kt*32 + lk];
      acc[m] = __builtin_amdgcn_mfma_f32_16x16x32_bf16(a, wz[kt], acc[m], 0,0,0);
    }
  }
  // accumulate z-part into gsh
  #pragma unroll
  for (int m=0;m<8;m++)
    #pragma unroll
    for (int i=0;i<4;i++)
      gsh[w][m*16 + li*4 + i][lr] += acc[m][i];
  __syncthreads();
  // cell update: 2048 cells, 8 per thread
  #pragma unroll
  for (int e=0;e<8;++e){
    int c = tid*8 + e;
    int nn = c>>4, j = c&15;
    int hidx = b*16 + j;
    float gi = gsh[0][nn][j] + gbias[         hidx];
    float gf = gsh[1][nn][j] + gbias[1*512 + hidx];
    float gg = gsh[2][nn][j] + gbias[2*512 + hidx];
    float go = gsh[3][nn][j] + gbias[3*512 + hidx];
    float cc = cbuf[nn*512 + hidx];
    float cs = fsigm(gf)*cc + fsigm(gi)*ftanh(gg);
    float h  = fsigm(go)*ftanh(cs);
    cbuf[nn*512 + hidx] = cs;
    unsigned short hb = f2bf(h);
    hout[nn*512 + hidx] = hb;
    cbf[((size_t)nn*TT + t)*608 + hidx] = hb;
  }
}

// ---------------- comb-input xe/se slices + ubf xe/pad prefill ----------------
__global__ __launch_bounds__(256) void k_cbf_xs(const float* __restrict__ xe, const float* __restrict__ se,
                                                unsigned short* __restrict__ cbf,
                                                unsigned short* __restrict__ ubf_all){
  int idx = blockIdx.x*256 + threadIdx.x;   // 2048 blocks: TN*TT*64
  if (idx >= TN*TT*64) return;
  int j = idx & 63, r = idx >> 6;
  int n = r >> 6, t = r & 63;
  if (j < 16)      cbf[(size_t)r*608 + 576 + j] = f2bf(xe[r*16 + j]);
  else if (j < 32) cbf[(size_t)r*608 + 592 + (j-16)] = f2bf(se[n*16 + (j-16)]);
  else if (j < 48) ubf_all[((size_t)t*TN + n)*96 + (j-32)] = f2bf(xe[r*16 + (j-32)]);
  else             ubf_all[((size_t)t*TN + n)*96 + 80 + (j-48)] = 0;
}

// ---------------- comb GEMM ----------------
__global__ __launch_bounds__(256) void k_comb(const unsigned short* __restrict__ cbf,
    const unsigned short* __restrict__ cwbf, const float* __restrict__ comb_b,
    unsigned short* __restrict__ ybf){
  int mbase = blockIdx.x*128, obase = blockIdx.y*128;
  int tid = threadIdx.x, w = tid>>6, l = tid&63;
  int lr = l&15, lk = (l>>4)*8;
  __shared__ unsigned short at[128*40];
  f32x4 acc[8][2];
  #pragma unroll
  for (int m=0;m<8;m++){ acc[m][0] = (f32x4){0,0,0,0}; acc[m][1] = (f32x4){0,0,0,0}; }
  for (int kt=0; kt<19; ++kt){
    int row = tid>>1, half = (tid&1)*16;
    const unsigned short* sp = cbf + (size_t)(mbase+row)*608 + kt*32 + half;
    *(float4*)&at[row*40 + half]     = *(const float4*)sp;
    *(float4*)&at[row*40 + half + 8] = *(const float4*)(sp + 8);
    __syncthreads();
    bf16x8 b0 = *(const bf16x8*)(cwbf + (size_t)(obase + (2*w+0)*16 + lr)*608 + kt*32 + lk);
    bf16x8 b1 = *(const bf16x8*)(cwbf + (size_t)(obase + (2*w+1)*16 + lr)*608 + kt*32 + lk);
    #pragma unroll
    for (int m=0;m<8;m++){
      bf16x8 afrag = *(const bf16x8*)&at[(m*16+lr)*40 + lk];
      acc[m][0] = __builtin_amdgcn_mfma_f32_16x16x32_bf16(afrag, b0, acc[m][0], 0,0,0);
      acc[m][1] = __builtin_amdgcn_mfma_f32_16x16x32_bf16(afrag, b1, acc[m][1], 0,0,0);
    }
    __syncthreads();
  }
  #pragma unroll
  for (int m=0;m<8;m++){
    #pragma unroll
    for (int j=0;j<2;j++){
      int o = obase + (2*w+j)*16 + lr;
      float cb = comb_b[o];
      #pragma unroll
      for (int i=0;i<4;i++){
        int r = mbase + m*16 + (l>>4)*4 + i;
        ybf[(size_t)r*1024 + o] = f2bf(ftanh(acc[m][j][i] + cb));
      }
    }
  }
}

// ---------------- out GEMM ----------------
__global__ __launch_bounds__(256) void k_out(const unsigned short* __restrict__ ybf,
    const unsigned short* __restrict__ owbf, const float* __restrict__ obias,
    float* __restrict__ obuf){
  int mbase = blockIdx.x*128;
  int tid = threadIdx.x, w = tid>>6, l = tid&63;
  int lr = l&15, lk = (l>>4)*8;
  __shared__ unsigned short at[128*40];
  f32x4 acc[8][2];
  #pragma unroll
  for (int m=0;m<8;m++){ acc[m][0] = (f32x4){0,0,0,0}; acc[m][1] = (f32x4){0,0,0,0}; }
  for (int kt=0; kt<32; ++kt){
    int row = tid>>1, half = (tid&1)*16;
    const unsigned short* sp = ybf + (size_t)(mbase+row)*1024 + kt*32 + half;
    *(float4*)&at[row*40 + half]     = *(const float4*)sp;
    *(float4*)&at[row*40 + half + 8] = *(const float4*)(sp + 8);
    __syncthreads();
    bf16x8 b0 = *(const bf16x8*)(owbf + ((2*w+0)*16 + lr)*1024 + kt*32 + lk);
    bf16x8 b1 = *(const bf16x8*)(owbf + ((2*w+1)*16 + lr)*1024 + kt*32 + lk);
    #pragma unroll
    for (int m=0;m<8;m++){
      bf16x8 afrag = *(const bf16x8*)&at[(m*16+lr)*40 + lk];
      acc[m][0] = __builtin_amdgcn_mfma_f32_16x16x32_bf16(afrag, b0, acc[m][0], 0,0,0);
      acc[m][1] = __builtin_amdgcn_mfma_f32_16x16x32_bf16(afrag, b1, acc[m][1], 0,0,0);
    }
    __syncthreads();
  }
  #pragma unroll
  for (int m=0;m<8;m++){
    #pragma unroll
    for (int j=0;j<2;j++){
      int o = (2*w+j)*16 + lr;
      float ob = obias[o];
      #pragma unroll
      for (int i=0;i<4;i++){
        int r = mbase + m*16 + (l>>4)*4 + i;
        obuf[(size_t)r*128 + o] = acc[m][j][i] + ob;
      }
    }
  }
}

// ---------------- postprocess ----------------
__global__ __launch_bounds__(256) void k_post(const float* __restrict__ obuf, float* __restrict__ out){
  int r = blockIdx.x*256 + threadIdx.x;
  if (r >= TN*TT) return;
  const float* row = obuf + (size_t)r*128;
  float mx = -1e30f;
  #pragma unroll
  for (int k2=0;k2<20;k2++) mx = fmaxf(mx, row[k2]);
  float e[20]; float s = 0;
  #pragma unroll
  for (int k2=0;k2<20;k2++){ e[k2] = __expf(row[k2]-mx); s += e[k2]; }
  float inv = __builtin_amdgcn_rcpf(s);
  float* mixo  = out;
  float* meano = out + 163840;
  float* scaleo= out + 491520;
  float* corro = out + 819200;
  float* vlogo = out + 983040;
  #pragma unroll
  for (int k2=0;k2<20;k2++) mixo[r*20+k2] = e[k2]*inv;
  #pragma unroll
  for (int j=0;j<40;j++) meano[r*40+j] = row[20+j];
  #pragma unroll
  for (int j=0;j<40;j++) scaleo[r*40+j] = __expf(row[60+j]);
  #pragma unroll
  for (int k2=0;k2<20;k2++) corro[r*20+k2] = ftanh(row[100+k2]);
  vlogo[r] = row[120];
}

extern "C" void kernel_launch(void* const* d_in, const int* in_sizes, int n_in,
                              void* d_out, int out_size, void* d_ws, size_t ws_size,
                              hipStream_t stream){
  const float* x       = (const float*)d_in[0];
  const float* x_canv  = (const float*)d_in[1];
  const float* start_  = (const float*)d_in[2];
  const float* conv1_w = (const float*)d_in[3];
  const float* conv1_b = (const float*)d_in[4];
  const float* conv2_w = (const float*)d_in[5];
  const float* conv2_b = (const float*)d_in[6];
  const float* conv3_w = (const float*)d_in[7];
  const float* conv3_b = (const float*)d_in[8];
  const float* init_w  = (const float*)d_in[9];
  const float* init_b  = (const float*)d_in[10];
  const float* Uw      = (const float*)d_in[11];
  const float* Ub      = (const float*)d_in[12];
  const float* Ww      = (const float*)d_in[13];
  const float* Wb      = (const float*)d_in[14];
  const float* vw      = (const float*)d_in[15];
  const float* vb      = (const float*)d_in[16];
  const float* beta_w  = (const float*)d_in[17];
  const float* beta_b  = (const float*)d_in[18];
  const float* xemb_w  = (const float*)d_in[19];
  const float* xemb_b  = (const float*)d_in[20];
  const float* semb_w  = (const float*)d_in[21];
  const float* semb_b  = (const float*)d_in[22];
  const float* Wih     = (const float*)d_in[23];
  const float* Whh     = (const float*)d_in[24];
  const float* bih     = (const float*)d_in[25];
  const float* bhh     = (const float*)d_in[26];
  const float* comb_w  = (const float*)d_in[27];
  const float* comb_b  = (const float*)d_in[28];
  const float* out_w   = (const float*)d_in[29];
  const float* out_b   = (const float*)d_in[30];
  (void)in_sizes; (void)n_in; (void)out_size; (void)ws_size;

  char* wsb = (char*)d_ws;
  size_t off = 0;
  auto alloc = [&](size_t bytes)->char*{
    char* p = wsb + off;
    off = (off + bytes + 255) & ~(size_t)255;
    return p;
  };
  unsigned short* c1bf   = (unsigned short*)alloc((size_t)TN*16*784*2);
  unsigned short* c2bf   = (unsigned short*)alloc((size_t)100352*32*2);
  unsigned short* afbf   = (unsigned short*)alloc((size_t)TN*64*196*2);
  unsigned short* abf    = (unsigned short*)alloc((size_t)TN*196*64*2);
  float*          amean  = (float*)alloc((size_t)TN*64*4);
  float*          xe     = (float*)alloc((size_t)TN*TT*16*4);
  float*          se     = (float*)alloc((size_t)TN*16*4);
  unsigned short* wabf   = (unsigned short*)alloc((size_t)TN*196*128*2);
  float*          cbuf   = (float*)alloc((size_t)TN*512*4);
  unsigned short* hbfA   = (unsigned short*)alloc((size_t)TN*512*2);
  unsigned short* hbfB   = (unsigned short*)alloc((size_t)TN*512*2);
  unsigned short* ubf_all= (unsigned short*)alloc((size_t)TT*TN*96*2);
  unsigned short* cbf    = (unsigned short*)alloc((size_t)TN*TT*608*2);
  unsigned short* ybf    = (unsigned short*)alloc((size_t)TN*TT*1024*2);
  float*          obuf   = (float*)alloc((size_t)TN*TT*128*4);
  unsigned short* wgf    = (unsigned short*)alloc((size_t)1245184*2);
  float*          gbias  = (float*)alloc((size_t)2048*4);
  float*          gpart  = (float*)alloc((size_t)4*128*512*4);
  unsigned short* cwbf   = (unsigned short*)alloc((size_t)1024*608*2);
  unsigned short* owbf   = (unsigned short*)alloc((size_t)128*1024*2);
  float*          obias  = (float*)alloc((size_t)128*4);
  unsigned short* uwbf   = (unsigned short*)alloc((size_t)128*512*2);
  unsigned short* betabf = (unsigned short*)alloc((size_t)64*512*2);
  unsigned short* wwbf   = (unsigned short*)alloc((size_t)128*64*2);
  unsigned short* w2b    = (unsigned short*)alloc((size_t)32*160*2);
  unsigned short* w3b    = (unsigned short*)alloc((size_t)64*320*2);

  hipLaunchKernelGGL(k_conv1, dim3(6272), dim3(256), 0, stream, x_canv, conv1_w, conv1_b, c1bf);
  hipLaunchKernelGGL(k_prep, dim3(8334), dim3(256), 0, stream,
                     Whh, Wih, bih, bhh, comb_w, out_w, out_b, Uw, beta_w, Ww, conv2_w, conv3_w,
                     wgf, gbias, cwbf, owbf, obias, uwbf, betabf, wwbf, w2b, w3b);
  hipLaunchKernelGGL(k_gconv2, dim3(784), dim3(256), 0, stream, c1bf, w2b, conv2_b, c2bf);
  hipLaunchKernelGGL(k_gconv3, dim3(196), dim3(256), 0, stream, c2bf, w3b, conv3_b, afbf, abf);
  hipLaunchKernelGGL(k_amean, dim3(128), dim3(64), 0, stream, afbf, amean);
  hipLaunchKernelGGL(k_embed, dim3(520), dim3(256), 0, stream, x, start_, xemb_w, xemb_b, semb_w, semb_b, xe, se);
  hipLaunchKernelGGL(k_init, dim3(512), dim3(256), 0, stream, amean, se, init_w, init_b, hbfA, cbuf);
  hipLaunchKernelGGL(k_wa, dim3(196), dim3(256), 0, stream, abf, wwbf, Wb, wabf);
  hipLaunchKernelGGL(k_cbf_xs, dim3(2048), dim3(256), 0, stream, xe, se, cbf, ubf_all);

  for (int t = 0; t < TT; ++t){
    unsigned short* hin  = (t & 1) ? hbfB : hbfA;
    unsigned short* hout = (t & 1) ? hbfA : hbfB;
    hipLaunchKernelGGL(k_stepA, dim3(160), dim3(512), 0, stream, t,
                       hin, uwbf, Ub, betabf, beta_b, vw, vb, wabf, afbf, ubf_all, cbf, wgf, gpart);
    hipLaunchKernelGGL(k_stepB, dim3(32), dim3(256), 0, stream, t,
                       hout, ubf_all, wgf, gbias, gpart, cbuf, cbf);
  }

  hipLaunchKernelGGL(k_comb, dim3(64, 8), dim3(256), 0, stream, cbf, cwbf, comb_b, ybf);
  hipLaunchKernelGGL(k_out, dim3(64), dim3(256), 0, stream, ybf, owbf, obias, obuf);
  hipLaunchKernelGGL(k_post, dim3(32), dim3(256), 0, stream, obuf, (float*)d_out);
}

// Round 12
// 1531.347 us; speedup vs baseline: 1.4324x; 1.1430x over previous
//
#include <hip/hip_runtime.h>

// LSTMConditioned: conv-encoder + attention-LSTM (T=64) + MDN head.
// N=128, T=64, HID=512, COMB=1024, ATT=128, K=20, D=2, FMAP=64, L=196, ODIM=121.
// Recurrence: 2 launches/step (launch-boundary sync; in-kernel cross-block sync measured
// 44-183 us/step on MI355X). stepA (160 blocks x 512 thr) = attention (blocks 0-127)
// || gates Whh-part GEMM (blocks 128-159, full h-tile staged once in 132KB LDS, 1 barrier).
// stepB (32 blocks x 512 thr) = z-part GEMM (direct u-frags) + fused cell update.
// im2col kernels are separate and 8-wide vectorized (fusion measured slower: serial gather).

#define TN 128
#define TT 64

typedef __attribute__((ext_vector_type(4))) float f32x4;
typedef __attribute__((ext_vector_type(8))) short bf16x8;

__device__ __forceinline__ float fsigm(float x){ return __builtin_amdgcn_rcpf(1.0f + __expf(-x)); }
__device__ __forceinline__ float ftanh(float x){ return 1.0f - 2.0f*__builtin_amdgcn_rcpf(1.0f + __expf(2.0f*x)); }
__device__ __forceinline__ unsigned short f2bf(float f){
  unsigned int u = __float_as_uint(f);
  u += 0x7fffu + ((u >> 16) & 1u);
  return (unsigned short)(u >> 16);
}
__device__ __forceinline__ float b2f(unsigned short u){ return __uint_as_float(((unsigned)u)<<16); }
__device__ __forceinline__ void cvt8(unsigned short* d, const float* s){
  __align__(16) unsigned short vals[8];
  #pragma unroll
  for (int j=0;j<8;j++) vals[j] = f2bf(s[j]);
  *(float4*)d = *(float4*)vals;
}

// ---------------- conv1 (direct, small), bf16 out ----------------
__global__ __launch_bounds__(256) void k_conv1(const float* __restrict__ xc, const float* __restrict__ w,
                                               const float* __restrict__ b, unsigned short* __restrict__ c1bf){
  int idx = blockIdx.x*256 + threadIdx.x;
  if (idx >= TN*16*784) return;
  int p = idx % 784, oc = (idx/784) & 15, n = idx/(784*16);
  int py = p/28, px = p%28;
  const float* src = xc + n*784;
  float acc = b[oc];
  #pragma unroll
  for (int ky=0;ky<3;ky++){
    int iy = py+ky-1; if (iy<0||iy>=28) continue;
    #pragma unroll
    for (int kx=0;kx<3;kx++){
      int ix = px+kx-1; if (ix<0||ix>=28) continue;
      acc += (src[iy*28+ix]-0.0243f)*(1.0f/0.1383f) * w[oc*9+ky*3+kx];
    }
  }
  c1bf[idx] = f2bf(fmaxf(acc, 0.0f));
}

// ---------------- im2col for conv2: 8 gathers + one 16B store per thread ----------------
__global__ __launch_bounds__(256) void k_im2col2(const unsigned short* __restrict__ c1bf, unsigned short* __restrict__ a2){
  int u = blockIdx.x*256 + threadIdx.x;   // 100352*20 units, grid 7840
  if (u >= 100352*20) return;
  int r = u / 20, k8 = (u - r*20)*8;
  int p = r % 784, n = r / 784;
  int py = p/28, px = p%28;
  __align__(16) unsigned short vals[8];
  #pragma unroll
  for (int j=0;j<8;j++){
    int k = k8 + j;
    unsigned short v = 0;
    if (k < 144){
      int ic = k/9, rem = k - ic*9, ky = rem/3, kx = rem - ky*3;
      int iy = py+ky-1, ix = px+kx-1;
      if (iy>=0 && iy<28 && ix>=0 && ix<28) v = c1bf[(n*16+ic)*784 + iy*28+ix];
    }
    vals[j] = v;
  }
  *(float4*)(a2 + (size_t)r*160 + k8) = *(float4*)vals;
}

// ---------------- conv2 GEMM ----------------
__global__ __launch_bounds__(256) void k_gconv2(const unsigned short* __restrict__ a2,
    const unsigned short* __restrict__ w2b, const float* __restrict__ b2,
    unsigned short* __restrict__ c2bf){
  int mbase = blockIdx.x*128;           // 784 blocks
  int tid = threadIdx.x, w = tid>>6, l = tid&63;
  int lr = l&15, lk = (l>>4)*8;
  __shared__ unsigned short at[128*168];
  {
    int row = tid>>1, off = (tid&1)*80;
    const unsigned short* sp = a2 + (size_t)(mbase+row)*160 + off;
    #pragma unroll
    for (int j=0;j<10;j++) *(float4*)&at[row*168 + off + j*8] = *(const float4*)(sp + j*8);
  }
  __syncthreads();
  f32x4 acc[2][2];
  #pragma unroll
  for (int mi=0;mi<2;mi++){ acc[mi][0]=(f32x4){0,0,0,0}; acc[mi][1]=(f32x4){0,0,0,0}; }
  for (int kt=0; kt<5; ++kt){
    bf16x8 b0 = *(const bf16x8*)(w2b + (0*16+lr)*160 + kt*32 + lk);
    bf16x8 b1 = *(const bf16x8*)(w2b + (1*16+lr)*160 + kt*32 + lk);
    #pragma unroll
    for (int mi=0;mi<2;mi++){
      bf16x8 afrag = *(const bf16x8*)&at[((2*w+mi)*16+lr)*168 + kt*32 + lk];
      acc[mi][0] = __builtin_amdgcn_mfma_f32_16x16x32_bf16(afrag, b0, acc[mi][0], 0,0,0);
      acc[mi][1] = __builtin_amdgcn_mfma_f32_16x16x32_bf16(afrag, b1, acc[mi][1], 0,0,0);
    }
  }
  #pragma unroll
  for (int mi=0;mi<2;mi++){
    #pragma unroll
    for (int j=0;j<2;j++){
      int oc = j*16 + lr;
      float bb = b2[oc];
      #pragma unroll
      for (int i=0;i<4;i++){
        int r = mbase + (2*w+mi)*16 + (l>>4)*4 + i;
        c2bf[(size_t)r*32 + oc] = f2bf(fmaxf(acc[mi][j][i] + bb, 0.0f));
      }
    }
  }
}

// ---------------- im2col for conv3 (stride 2): 8 gathers + one 16B store ----------------
__global__ __launch_bounds__(256) void k_im2col3(const unsigned short* __restrict__ c2bf, unsigned short* __restrict__ a3){
  int u = blockIdx.x*256 + threadIdx.x;   // 25088*40 units, grid 3920
  if (u >= 25088*40) return;
  int r = u / 40, k8 = (u - r*40)*8;
  int p = r % 196, n = r / 196;
  int py = p/14, px = p%14;
  __align__(16) unsigned short vals[8];
  #pragma unroll
  for (int j=0;j<8;j++){
    int k = k8 + j;
    unsigned short v = 0;
    if (k < 288){
      int ic = k/9, rem = k - ic*9, ky = rem/3, kx = rem - ky*3;
      int iy = 2*py+ky-1, ix = 2*px+kx-1;
      if (iy>=0 && iy<28 && ix>=0 && ix<28) v = c2bf[(size_t)(n*784 + iy*28+ix)*32 + ic];
    }
    vals[j] = v;
  }
  *(float4*)(a3 + (size_t)r*320 + k8) = *(float4*)vals;
}

// ---------------- conv3 GEMM: afbf[n][f][l] (bf16) + abf[r][f] (bf16) ----------------
__global__ __launch_bounds__(256) void k_gconv3(const unsigned short* __restrict__ a3,
    const unsigned short* __restrict__ w3b, const float* __restrict__ b3,
    unsigned short* __restrict__ afbf, unsigned short* __restrict__ abf){
  int mbase = blockIdx.x*128;           // 196 blocks
  int tid = threadIdx.x, w = tid>>6, l = tid&63;
  int lr = l&15, lk = (l>>4)*8;
  __shared__ unsigned short at[128*168];
  f32x4 acc[2][4];
  #pragma unroll
  for (int mi=0;mi<2;mi++)
    #pragma unroll
    for (int j=0;j<4;j++) acc[mi][j]=(f32x4){0,0,0,0};
  for (int kt2=0; kt2<2; ++kt2){
    {
      int row = tid>>1, off = (tid&1)*80;
      const unsigned short* sp = a3 + (size_t)(mbase+row)*320 + kt2*160 + off;
      #pragma unroll
      for (int j=0;j<10;j++) *(float4*)&at[row*168 + off + j*8] = *(const float4*)(sp + j*8);
    }
    __syncthreads();
    for (int kt=0; kt<5; ++kt){
      #pragma unroll
      for (int mi=0;mi<2;mi++){
        bf16x8 afrag = *(const bf16x8*)&at[((2*w+mi)*16+lr)*168 + kt*32 + lk];
        #pragma unroll
        for (int j=0;j<4;j++){
          bf16x8 bf = *(const bf16x8*)(w3b + (size_t)(j*16+lr)*320 + kt2*160 + kt*32 + lk);
          acc[mi][j] = __builtin_amdgcn_mfma_f32_16x16x32_bf16(afrag, bf, acc[mi][j], 0,0,0);
        }
      }
    }
    __syncthreads();
  }
  #pragma unroll
  for (int mi=0;mi<2;mi++){
    #pragma unroll
    for (int j=0;j<4;j++){
      int oc = j*16 + lr;
      float bb = b3[oc];
      #pragma unroll
      for (int i=0;i<4;i++){
        int r = mbase + (2*w+mi)*16 + (l>>4)*4 + i;
        int n = r/196, p = r - n*196;
        float v = ftanh(acc[mi][j][i] + bb);
        unsigned short vb16 = f2bf(v);
        afbf[(size_t)(n*64+oc)*196 + p] = vb16;
        abf[(size_t)r*64 + oc] = vb16;
      }
    }
  }
}

__global__ __launch_bounds__(64) void k_amean(const unsigned short* __restrict__ afbf, float* __restrict__ amean){
  int n = blockIdx.x, f = threadIdx.x;
  const unsigned short* row = afbf + (size_t)(n*64+f)*196;
  float s = 0;
  for (int l=0;l<196;l++) s += b2f(row[l]);
  amean[n*64+f] = s * (1.0f/196.0f);
}

// ---------------- embeddings / init ----------------
__global__ __launch_bounds__(256) void k_embed(const float* __restrict__ x, const float* __restrict__ start,
    const float* __restrict__ xw, const float* __restrict__ xb,
    const float* __restrict__ sw, const float* __restrict__ sb,
    float* __restrict__ xe, float* __restrict__ se){
  int idx = blockIdx.x*256 + threadIdx.x;
  if (idx < TN*TT*16){
    int j = idx & 15, t = (idx>>4) & 63, n = idx>>10;
    float acc = xb[j];
    if (t > 0){
      const float* xp = x + (n*TT + t-1)*2;
      acc += xp[0]*xw[j*2] + xp[1]*xw[j*2+1];
    }
    xe[idx] = ftanh(acc);
  } else if (idx < TN*TT*16 + TN*16){
    int k2 = idx - TN*TT*16;
    int j = k2 & 15, n = k2 >> 4;
    float acc = sb[j] + start[n*2]*sw[j*2] + start[n*2+1]*sw[j*2+1];
    se[k2] = ftanh(acc);
  }
}

__global__ __launch_bounds__(256) void k_init(const float* __restrict__ amean, const float* __restrict__ se,
    const float* __restrict__ w, const float* __restrict__ b,
    unsigned short* __restrict__ hbfA, float* __restrict__ cbuf){
  int idx = blockIdx.x*256 + threadIdx.x;
  if (idx >= TN*1024) return;
  int o = idx & 1023, n = idx >> 10;
  const float* wr = w + o*80;
  float acc = b[o];
  for (int k2=0;k2<64;k2++) acc += amean[n*64+k2]*wr[k2];
  for (int k2=0;k2<16;k2++) acc += se[n*16+k2]*wr[64+k2];
  float v = ftanh(acc);
  if (o & 1) cbuf[n*512 + (o>>1)] = v;
  else       hbfA[n*512 + (o>>1)] = f2bf(v);
}

// ---------------- weight prep (8-wide vectorized) ----------------
// wgf: gates weights in MFMA fragment order: frag (g,b,kt) at ((g*32+b)*19+kt)*512,
// lane l elem j = W[g*512+b*16+(l&15)][kt*32+(l>>4)*8+j], W = [Whh | Wih(pad 96)].
__global__ __launch_bounds__(256) void k_prep(
    const float* __restrict__ Whh, const float* __restrict__ Wih,
    const float* __restrict__ bih, const float* __restrict__ bhh,
    const float* __restrict__ comb_w, const float* __restrict__ out_w, const float* __restrict__ out_b,
    const float* __restrict__ Uw, const float* __restrict__ beta_w, const float* __restrict__ Ww,
    const float* __restrict__ conv2_w, const float* __restrict__ conv3_w,
    unsigned short* __restrict__ wgf, float* __restrict__ gbias,
    unsigned short* __restrict__ cwbf, unsigned short* __restrict__ owbf, float* __restrict__ obias,
    unsigned short* __restrict__ uwbf, unsigned short* __restrict__ betabf, unsigned short* __restrict__ wwbf,
    unsigned short* __restrict__ w2b, unsigned short* __restrict__ w3b){
  int u = blockIdx.x*256 + threadIdx.x;   // grid 1042 blocks = 266752 >= 266640 units
  if (u < 155648){   // wgf (units of 8)
    int fragi = u >> 6, lane = u & 63;
    int g = fragi / 608, rem = fragi - g*608;
    int b = rem / 19, kt = rem - b*19;
    int row = g*512 + b*16 + (lane & 15);
    int col = kt*32 + (lane >> 4)*8;
    __align__(16) unsigned short vals[8];
    if (col < 512){
      const float* s = Whh + (size_t)row*512 + col;
      #pragma unroll
      for (int j=0;j<8;j++) vals[j] = f2bf(s[j]);
    } else if (col - 512 < 80){
      const float* s = Wih + (size_t)row*80 + (col-512);
      #pragma unroll
      for (int j=0;j<8;j++) vals[j] = f2bf(s[j]);
    } else {
      #pragma unroll
      for (int j=0;j<8;j++) vals[j] = 0;
    }
    *(float4*)(wgf + (size_t)u*8) = *(float4*)vals;
    return;
  }
  u -= 155648;
  if (u < 256){   // gbias (2048)
    #pragma unroll
    for (int j=0;j<8;j++) gbias[u*8+j] = bih[u*8+j] + bhh[u*8+j];
    return;
  }
  u -= 256;
  if (u < 77824){ cvt8(cwbf + (size_t)u*8, comb_w + (size_t)u*8); return; }   // 622592
  u -= 77824;
  if (u < 16384){   // owbf 131072, pad rows >=121
    int o = u >> 7, k2 = (u & 127)*8;
    __align__(16) unsigned short vals[8];
    if (o < 121){
      const float* s = out_w + (size_t)o*1024 + k2;
      #pragma unroll
      for (int j=0;j<8;j++) vals[j] = f2bf(s[j]);
    } else {
      #pragma unroll
      for (int j=0;j<8;j++) vals[j] = 0;
    }
    *(float4*)(owbf + (size_t)u*8) = *(float4*)vals;
    return;
  }
  u -= 16384;
  if (u < 16){
    #pragma unroll
    for (int j=0;j<8;j++){ int i = u*8+j; obias[i] = (i<121)? out_b[i] : 0.0f; }
    return;
  }
  u -= 16;
  if (u < 8192){ cvt8(uwbf + (size_t)u*8, Uw + (size_t)u*8); return; }     // 65536
  u -= 8192;
  if (u < 4096){ cvt8(betabf + (size_t)u*8, beta_w + (size_t)u*8); return; } // 32768
  u -= 4096;
  if (u < 1024){ cvt8(wwbf + (size_t)u*8, Ww + (size_t)u*8); return; }     // 8192
  u -= 1024;
  if (u < 640){    // w2b: rows of 160, valid k2<144 (144 = 18*8, unit-aligned)
    int o = u/20, k2 = (u - o*20)*8;
    if (k2 < 144) cvt8(w2b + (size_t)u*8, conv2_w + (size_t)o*144 + k2);
    else { __align__(16) unsigned short z[8] = {0,0,0,0,0,0,0,0}; *(float4*)(w2b + (size_t)u*8) = *(float4*)z; }
    return;
  }
  u -= 640;
  if (u < 2560){   // w3b: rows of 320, valid k2<288 (288 = 36*8, unit-aligned)
    int o = u/40, k2 = (u - o*40)*8;
    if (k2 < 288) cvt8(w3b + (size_t)u*8, conv3_w + (size_t)o*288 + k2);
    else { __align__(16) unsigned short z[8] = {0,0,0,0,0,0,0,0}; *(float4*)(w3b + (size_t)u*8) = *(float4*)z; }
    return;
  }
}

// ---------------- W_a = a @ Ww.T + Wb (MFMA), stored bf16 [n][l][att] ----------------
__global__ __launch_bounds__(256) void k_wa(const unsigned short* __restrict__ abf,
    const unsigned short* __restrict__ wwbf, const float* __restrict__ Wb,
    unsigned short* __restrict__ wabf){
  int mbase = blockIdx.x*128;
  int tid = threadIdx.x, w = tid>>6, l = tid&63;
  int lr = l & 15, lk = (l>>4)*8;
  __shared__ unsigned short at[128*40];
  f32x4 acc[8][2];
  #pragma unroll
  for (int m=0;m<8;m++){ acc[m][0] = (f32x4){0,0,0,0}; acc[m][1] = (f32x4){0,0,0,0}; }
  for (int kt=0; kt<2; ++kt){
    int row = tid>>1, half = (tid&1)*16;
    const unsigned short* sp = abf + (mbase+row)*64 + kt*32 + half;
    *(float4*)&at[row*40 + half]     = *(const float4*)sp;
    *(float4*)&at[row*40 + half + 8] = *(const float4*)(sp + 8);
    __syncthreads();
    bf16x8 b0 = *(const bf16x8*)(wwbf + ((2*w+0)*16 + lr)*64 + kt*32 + lk);
    bf16x8 b1 = *(const bf16x8*)(wwbf + ((2*w+1)*16 + lr)*64 + kt*32 + lk);
    #pragma unroll
    for (int m=0;m<8;m++){
      bf16x8 afrag = *(const bf16x8*)&at[(m*16+lr)*40 + lk];
      acc[m][0] = __builtin_amdgcn_mfma_f32_16x16x32_bf16(afrag, b0, acc[m][0], 0,0,0);
      acc[m][1] = __builtin_amdgcn_mfma_f32_16x16x32_bf16(afrag, b1, acc[m][1], 0,0,0);
    }
    __syncthreads();
  }
  #pragma unroll
  for (int m=0;m<8;m++){
    #pragma unroll
    for (int j=0;j<2;j++){
      int att = (2*w+j)*16 + lr;
      float wb = Wb[att];
      #pragma unroll
      for (int i=0;i<4;i++){
        int arow = mbase + m*16 + (l>>4)*4 + i;
        int n = arow/196, l2 = arow - n*196;
        wabf[((size_t)n*196 + l2)*128 + att] = f2bf(acc[m][j][i] + wb);
      }
    }
  }
}

// ---------------- step A: attention (blocks 0-127) || gates-h GEMM (blocks 128-159) ----------------
__global__ __launch_bounds__(512) void k_stepA(int t,
    const unsigned short* __restrict__ hbf_in,
    const unsigned short* __restrict__ uwbf, const float* __restrict__ Ub,
    const unsigned short* __restrict__ betabf, const float* __restrict__ beta_b,
    const float* __restrict__ vw, const float* __restrict__ vb,
    const unsigned short* __restrict__ wabf, const unsigned short* __restrict__ afbf,
    unsigned short* __restrict__ ubf_all, unsigned short* __restrict__ cbf,
    const unsigned short* __restrict__ wgf, float* __restrict__ gpart)
{
  const int bid = blockIdx.x, tid = threadIdx.x;
  __shared__ __align__(16) float hs[512];
  __shared__ __align__(16) float Uh[128];
  __shared__ __align__(16) float vws[128];
  __shared__ float bsig[64];
  __shared__ float ew[196];
  __shared__ float red[16];
  __shared__ float up[4][128];
  __shared__ float qp8[8][64];
  __shared__ float ep2[256][2];
  __shared__ __align__(16) unsigned short at2[128*516];   // 132 KB: full h-tile (gates role)

  if (bid < TN){
    // =================== attention role: sample n = bid ===================
    const int n = bid;
    hs[tid] = b2f(hbf_in[n*512 + tid]);
    if (tid < 128) vws[tid] = vw[tid];
    const float vb0 = vb[0];
    __syncthreads();
    // Uh partials: (att, k-quarter)
    {
      int att = tid & 127, q = tid >> 7;
      const unsigned short* uw = uwbf + (size_t)att*512 + q*128;
      const float* hh = hs + q*128;
      float acc = 0.f;
      #pragma unroll 4
      for (int k=0;k<128;k+=8){
        bf16x8 v = *(const bf16x8*)(uw + k);
        acc += hh[k+0]*b2f(v[0]) + hh[k+1]*b2f(v[1]) + hh[k+2]*b2f(v[2]) + hh[k+3]*b2f(v[3])
             + hh[k+4]*b2f(v[4]) + hh[k+5]*b2f(v[5]) + hh[k+6]*b2f(v[6]) + hh[k+7]*b2f(v[7]);
      }
      up[q][att] = acc;
    }
    // beta partials: (f, k-eighth)
    {
      int f = tid & 63, q = tid >> 6;
      const unsigned short* bw = betabf + (size_t)f*512 + q*64;
      const float* hh = hs + q*64;
      float acc = 0.f;
      #pragma unroll 4
      for (int k=0;k<64;k+=8){
        bf16x8 v = *(const bf16x8*)(bw + k);
        acc += hh[k+0]*b2f(v[0]) + hh[k+1]*b2f(v[1]) + hh[k+2]*b2f(v[2]) + hh[k+3]*b2f(v[3])
             + hh[k+4]*b2f(v[4]) + hh[k+5]*b2f(v[5]) + hh[k+6]*b2f(v[6]) + hh[k+7]*b2f(v[7]);
      }
      qp8[q][f] = acc;
    }
    __syncthreads();
    if (tid < 128) Uh[tid] = Ub[tid] + up[0][tid]+up[1][tid]+up[2][tid]+up[3][tid];
    else if (tid < 192){
      int f = tid-128;
      bsig[f] = fsigm(beta_b[f] + qp8[0][f]+qp8[1][f]+qp8[2][f]+qp8[3][f]
                                + qp8[4][f]+qp8[5][f]+qp8[6][f]+qp8[7][f]);
    }
    __syncthreads();
    // e partials: (l, att-half)
    {
      int l = tid >> 1, half = tid & 1;
      float acc = 0.f;
      if (l < 196){
        const unsigned short* wr = wabf + ((size_t)n*196 + l)*128 + half*64;
        const float* uh = Uh + half*64;
        const float* vv = vws + half*64;
        #pragma unroll 2
        for (int k=0;k<64;k+=8){
          bf16x8 wv = *(const bf16x8*)(wr + k);
          acc += vv[k+0]*ftanh(b2f(wv[0]) + uh[k+0]) + vv[k+1]*ftanh(b2f(wv[1]) + uh[k+1])
               + vv[k+2]*ftanh(b2f(wv[2]) + uh[k+2]) + vv[k+3]*ftanh(b2f(wv[3]) + uh[k+3])
               + vv[k+4]*ftanh(b2f(wv[4]) + uh[k+4]) + vv[k+5]*ftanh(b2f(wv[5]) + uh[k+5])
               + vv[k+6]*ftanh(b2f(wv[6]) + uh[k+6]) + vv[k+7]*ftanh(b2f(wv[7]) + uh[k+7]);
        }
      }
      ep2[l][half] = acc;
    }
    __syncthreads();
    float ev = -1e30f;
    if (tid < 196) ev = vb0 + ep2[tid][0] + ep2[tid][1];
    float m = ev;
    #pragma unroll
    for (int off=32; off>0; off>>=1) m = fmaxf(m, __shfl_xor(m, off));
    if ((tid&63)==0) red[tid>>6] = m;
    __syncthreads();
    float mx = red[0];
    #pragma unroll
    for (int i=1;i<8;i++) mx = fmaxf(mx, red[i]);
    float ex = (tid<196) ? __expf(ev - mx) : 0.0f;
    float ss = ex;
    #pragma unroll
    for (int off=32; off>0; off>>=1) ss += __shfl_xor(ss, off);
    if ((tid&63)==0) red[8+(tid>>6)] = ss;
    if (tid<196) ew[tid] = ex;
    __syncthreads();
    float inv = __builtin_amdgcn_rcpf(red[8]+red[9]+red[10]+red[11]+red[12]+red[13]+red[14]+red[15]);
    // z partials: (f, l-chunk of 25)
    {
      int f = tid & 63, q = tid >> 6;
      int l0 = q*25, l1 = (l0+25 < 196) ? l0+25 : 196;
      const unsigned short* an = afbf + (size_t)n*12544 + (size_t)f*196;
      float acc = 0.f;
      for (int l2=l0; l2<l1; l2++) acc += ew[l2]*b2f(an[l2]);
      qp8[q][f] = acc;
    }
    __syncthreads();
    if (tid < 64){
      float z = bsig[tid]*(qp8[0][tid]+qp8[1][tid]+qp8[2][tid]+qp8[3][tid]
                          +qp8[4][tid]+qp8[5][tid]+qp8[6][tid]+qp8[7][tid])*inv;
      unsigned short zb = f2bf(z);
      ubf_all[((size_t)t*TN + n)*96 + 16 + tid] = zb;
      cbf[((size_t)n*TT + t)*608 + 512 + tid] = zb;
    }
  } else {
    // =================== gates Whh-part role: col-slice b (full h-tile staged once) ===================
    const int b = bid - TN;                       // 0..31
    const int w = tid>>6, l = tid&63, lr = l&15, li = l>>4, lk = li*8;
    const int g = w & 3, mh = w >> 2;             // wave -> (gate, M-half)
    bf16x8 wreg[16];
    {
      const unsigned short* wp = wgf + ((size_t)(g*32 + b)*19)*512 + (size_t)l*8;
      #pragma unroll
      for (int i=0;i<16;i++) wreg[i] = *(const bf16x8*)(wp + (size_t)i*512);
    }
    // stage all 128x512 h (8192 float4 over 512 threads = 16 coalesced loads each)
    for (int i = tid; i < 8192; i += 512){
      int row = i >> 6, seg = (i & 63)*8;
      *(float4*)&at2[row*516 + seg] = *(const float4*)(hbf_in + (size_t)row*512 + seg);
    }
    __syncthreads();
    f32x4 acc[4];
    #pragma unroll
    for (int m2=0;m2<4;m2++) acc[m2] = (f32x4){0,0,0,0};
    #pragma unroll 4
    for (int kt=0; kt<16; ++kt){
      #pragma unroll
      for (int m2=0;m2<4;m2++){
        bf16x8 a = *(const bf16x8*)&at2[((mh*4+m2)*16 + lr)*516 + kt*32 + lk];
        acc[m2] = __builtin_amdgcn_mfma_f32_16x16x32_bf16(a, wreg[kt], acc[m2], 0,0,0);
      }
    }
    #pragma unroll
    for (int m2=0;m2<4;m2++){
      #pragma unroll
      for (int i=0;i<4;i++){
        int n2 = (mh*4+m2)*16 + li*4 + i;
        gpart[(((size_t)g*128 + n2)<<9) + b*16 + lr] = acc[m2][i];
      }
    }
  }
}

// ---------------- step B: z-part GEMM (direct u-frags) + cell update (32 blocks x 512 thr) ----------------
__global__ __launch_bounds__(512) void k_stepB(int t,
    unsigned short* __restrict__ hout,
    const unsigned short* __restrict__ ubf_all,
    const unsigned short* __restrict__ wgf, const float* __restrict__ gbias,
    const float* __restrict__ gpart,
    float* __restrict__ cbuf, unsigned short* __restrict__ cbf)
{
  const int b = blockIdx.x, tid = threadIdx.x;
  const int w = tid>>6, l = tid&63, lr = l&15, li = l>>4, lk = li*8;
  const int g = w & 3, mh = w >> 2;
  __shared__ float gsh[4][128][16];              // 32 KB: gate accumulators
  const unsigned short* ub = ubf_all + (size_t)t*TN*96;
  bf16x8 wz[3];
  {
    const unsigned short* wp = wgf + (((size_t)(g*32 + b)*19) + 16)*512 + (size_t)l*8;
    #pragma unroll
    for (int i=0;i<3;i++) wz[i] = *(const bf16x8*)(wp + (size_t)i*512);
  }
  // load gpart -> gsh (2048 float4 over 512 threads)
  for (int i = tid; i < 2048; i += 512){
    int gg = i>>9, r = i&511, n2 = r>>2, j4 = r&3;
    *(float4*)&gsh[gg][n2][j4*4] = *(const float4*)&gpart[(((size_t)gg*128 + n2)<<9) + b*16 + j4*4];
  }
  // z-part MFMA: wave (g,mh) covers m-tiles mh*4..mh*4+4, direct global u-frags
  f32x4 acc[4];
  #pragma unroll
  for (int m2=0;m2<4;m2++) acc[m2] = (f32x4){0,0,0,0};
  #pragma unroll
  for (int kt=0; kt<3; ++kt){
    #pragma unroll
    for (int m2=0;m2<4;m2++){
      bf16x8 a = *(const bf16x8*)(ub + (size_t)((mh*4+m2)*16 + lr)*96 + kt*32 + lk);
      acc[m2] = __builtin_amdgcn_mfma_f32_16x16x32_bf16(a, wz[kt], acc[m2], 0,0,0);
    }
  }
  __syncthreads();   // gsh fully loaded
  #pragma unroll
  for (int m2=0;m2<4;m2++)
    #pragma unroll
    for (int i=0;i<4;i++)
      gsh[g][(mh*4+m2)*16 + li*4 + i][lr] += acc[m2][i];
  __syncthreads();
  // cell update: 2048 cells, 4 per thread
  #pragma unroll
  for (int e=0;e<4;++e){
    int c = tid*4 + e;
    int nn = c>>4, j = c&15;
    int hidx = b*16 + j;
    float gi = gsh[0][nn][j] + gbias[         hidx];
    float gf = gsh[1][nn][j] + gbias[1*512 + hidx];
    float gg = gsh[2][nn][j] + gbias[2*512 + hidx];
    float go = gsh[3][nn][j] + gbias[3*512 + hidx];
    float cc = cbuf[nn*512 + hidx];
    float cs = fsigm(gf)*cc + fsigm(gi)*ftanh(gg);
    float h  = fsigm(go)*ftanh(cs);
    cbuf[nn*512 + hidx] = cs;
    unsigned short hb = f2bf(h);
    hout[nn*512 + hidx] = hb;
    cbf[((size_t)nn*TT + t)*608 + hidx] = hb;
  }
}

// ---------------- comb-input xe/se slices + ubf xe/pad prefill ----------------
__global__ __launch_bounds__(256) void k_cbf_xs(const float* __restrict__ xe, const float* __restrict__ se,
                                                unsigned short* __restrict__ cbf,
                                                unsigned short* __restrict__ ubf_all){
  int idx = blockIdx.x*256 + threadIdx.x;   // 2048 blocks: TN*TT*64
  if (idx >= TN*TT*64) return;
  int j = idx & 63, r = idx >> 6;
  int n = r >> 6, t = r & 63;
  if (j < 16)      cbf[(size_t)r*608 + 576 + j] = f2bf(xe[r*16 + j]);
  else if (j < 32) cbf[(size_t)r*608 + 592 + (j-16)] = f2bf(se[n*16 + (j-16)]);
  else if (j < 48) ubf_all[((size_t)t*TN + n)*96 + (j-32)] = f2bf(xe[r*16 + (j-32)]);
  else             ubf_all[((size_t)t*TN + n)*96 + 80 + (j-48)] = 0;
}

// ---------------- comb GEMM ----------------
__global__ __launch_bounds__(256) void k_comb(const unsigned short* __restrict__ cbf,
    const unsigned short* __restrict__ cwbf, const float* __restrict__ comb_b,
    unsigned short* __restrict__ ybf){
  int mbase = blockIdx.x*128, obase = blockIdx.y*128;
  int tid = threadIdx.x, w = tid>>6, l = tid&63;
  int lr = l&15, lk = (l>>4)*8;
  __shared__ unsigned short at[128*40];
  f32x4 acc[8][2];
  #pragma unroll
  for (int m=0;m<8;m++){ acc[m][0] = (f32x4){0,0,0,0}; acc[m][1] = (f32x4){0,0,0,0}; }
  for (int kt=0; kt<19; ++kt){
    int row = tid>>1, half = (tid&1)*16;
    const unsigned short* sp = cbf + (size_t)(mbase+row)*608 + kt*32 + half;
    *(float4*)&at[row*40 + half]     = *(const float4*)sp;
    *(float4*)&at[row*40 + half + 8] = *(const float4*)(sp + 8);
    __syncthreads();
    bf16x8 b0 = *(const bf16x8*)(cwbf + (size_t)(obase + (2*w+0)*16 + lr)*608 + kt*32 + lk);
    bf16x8 b1 = *(const bf16x8*)(cwbf + (size_t)(obase + (2*w+1)*16 + lr)*608 + kt*32 + lk);
    #pragma unroll
    for (int m=0;m<8;m++){
      bf16x8 afrag = *(const bf16x8*)&at[(m*16+lr)*40 + lk];
      acc[m][0] = __builtin_amdgcn_mfma_f32_16x16x32_bf16(afrag, b0, acc[m][0], 0,0,0);
      acc[m][1] = __builtin_amdgcn_mfma_f32_16x16x32_bf16(afrag, b1, acc[m][1], 0,0,0);
    }
    __syncthreads();
  }
  #pragma unroll
  for (int m=0;m<8;m++){
    #pragma unroll
    for (int j=0;j<2;j++){
      int o = obase + (2*w+j)*16 + lr;
      float cb = comb_b[o];
      #pragma unroll
      for (int i=0;i<4;i++){
        int r = mbase + m*16 + (l>>4)*4 + i;
        ybf[(size_t)r*1024 + o] = f2bf(ftanh(acc[m][j][i] + cb));
      }
    }
  }
}

// ---------------- out GEMM ----------------
__global__ __launch_bounds__(256) void k_out(const unsigned short* __restrict__ ybf,
    const unsigned short* __restrict__ owbf, const float* __restrict__ obias,
    float* __restrict__ obuf){
  int mbase = blockIdx.x*128;
  int tid = threadIdx.x, w = tid>>6, l = tid&63;
  int lr = l&15, lk = (l>>4)*8;
  __shared__ unsigned short at[128*40];
  f32x4 acc[8][2];
  #pragma unroll
  for (int m=0;m<8;m++){ acc[m][0] = (f32x4){0,0,0,0}; acc[m][1] = (f32x4){0,0,0,0}; }
  for (int kt=0; kt<32; ++kt){
    int row = tid>>1, half = (tid&1)*16;
    const unsigned short* sp = ybf + (size_t)(mbase+row)*1024 + kt*32 + half;
    *(float4*)&at[row*40 + half]     = *(const float4*)sp;
    *(float4*)&at[row*40 + half + 8] = *(const float4*)(sp + 8);
    __syncthreads();
    bf16x8 b0 = *(const bf16x8*)(owbf + ((2*w+0)*16 + lr)*1024 + kt*32 + lk);
    bf16x8 b1 = *(const bf16x8*)(owbf + ((2*w+1)*16 + lr)*1024 + kt*32 + lk);
    #pragma unroll
    for (int m=0;m<8;m++){
      bf16x8 afrag = *(const bf16x8*)&at[(m*16+lr)*40 + lk];
      acc[m][0] = __builtin_amdgcn_mfma_f32_16x16x32_bf16(afrag, b0, acc[m][0], 0,0,0);
      acc[m][1] = __builtin_amdgcn_mfma_f32_16x16x32_bf16(afrag, b1, acc[m][1], 0,0,0);
    }
    __syncthreads();
  }
  #pragma unroll
  for (int m=0;m<8;m++){
    #pragma unroll
    for (int j=0;j<2;j++){
      int o = (2*w+j)*16 + lr;
      float ob = obias[o];
      #pragma unroll
      for (int i=0;i<4;i++){
        int r = mbase + m*16 + (l>>4)*4 + i;
        obuf[(size_t)r*128 + o] = acc[m][j][i] + ob;
      }
    }
  }
}

// ---------------- postprocess ----------------
__global__ __launch_bounds__(256) void k_post(const float* __restrict__ obuf, float* __restrict__ out){
  int r = blockIdx.x*256 + threadIdx.x;
  if (r >= TN*TT) return;
  const float* row = obuf + (size_t)r*128;
  float mx = -1e30f;
  #pragma unroll
  for (int k2=0;k2<20;k2++) mx = fmaxf(mx, row[k2]);
  float e[20]; float s = 0;
  #pragma unroll
  for (int k2=0;k2<20;k2++){ e[k2] = __expf(row[k2]-mx); s += e[k2]; }
  float inv = __builtin_amdgcn_rcpf(s);
  float* mixo  = out;
  float* meano = out + 163840;
  float* scaleo= out + 491520;
  float* corro = out + 819200;
  float* vlogo = out + 983040;
  #pragma unroll
  for (int k2=0;k2<20;k2++) mixo[r*20+k2] = e[k2]*inv;
  #pragma unroll
  for (int j=0;j<40;j++) meano[r*40+j] = row[20+j];
  #pragma unroll
  for (int j=0;j<40;j++) scaleo[r*40+j] = __expf(row[60+j]);
  #pragma unroll
  for (int k2=0;k2<20;k2++) corro[r*20+k2] = ftanh(row[100+k2]);
  vlogo[r] = row[120];
}

extern "C" void kernel_launch(void* const* d_in, const int* in_sizes, int n_in,
                              void* d_out, int out_size, void* d_ws, size_t ws_size,
                              hipStream_t stream){
  const float* x       = (const float*)d_in[0];
  const float* x_canv  = (const float*)d_in[1];
  const float* start_  = (const float*)d_in[2];
  const float* conv1_w = (const float*)d_in[3];
  const float* conv1_b = (const float*)d_in[4];
  const float* conv2_w = (const float*)d_in[5];
  const float* conv2_b = (const float*)d_in[6];
  const float* conv3_w = (const float*)d_in[7];
  const float* conv3_b = (const float*)d_in[8];
  const float* init_w  = (const float*)d_in[9];
  const float* init_b  = (const float*)d_in[10];
  const float* Uw      = (const float*)d_in[11];
  const float* Ub      = (const float*)d_in[12];
  const float* Ww      = (const float*)d_in[13];
  const float* Wb      = (const float*)d_in[14];
  const float* vw      = (const float*)d_in[15];
  const float* vb      = (const float*)d_in[16];
  const float* beta_w  = (const float*)d_in[17];
  const float* beta_b  = (const float*)d_in[18];
  const float* xemb_w  = (const float*)d_in[19];
  const float* xemb_b  = (const float*)d_in[20];
  const float* semb_w  = (const float*)d_in[21];
  const float* semb_b  = (const float*)d_in[22];
  const float* Wih     = (const float*)d_in[23];
  const float* Whh     = (const float*)d_in[24];
  const float* bih     = (const float*)d_in[25];
  const float* bhh     = (const float*)d_in[26];
  const float* comb_w  = (const float*)d_in[27];
  const float* comb_b  = (const float*)d_in[28];
  const float* out_w   = (const float*)d_in[29];
  const float* out_b   = (const float*)d_in[30];
  (void)in_sizes; (void)n_in; (void)out_size; (void)ws_size;

  char* wsb = (char*)d_ws;
  size_t off = 0;
  auto alloc = [&](size_t bytes)->char*{
    char* p = wsb + off;
    off = (off + bytes + 255) & ~(size_t)255;
    return p;
  };
  unsigned short* c1bf   = (unsigned short*)alloc((size_t)TN*16*784*2);
  unsigned short* a2     = (unsigned short*)alloc((size_t)100352*160*2);  // a3 aliases a2
  unsigned short* a3     = a2;
  unsigned short* c2bf   = (unsigned short*)alloc((size_t)100352*32*2);
  unsigned short* afbf   = (unsigned short*)alloc((size_t)TN*64*196*2);
  unsigned short* abf    = (unsigned short*)alloc((size_t)TN*196*64*2);
  float*          amean  = (float*)alloc((size_t)TN*64*4);
  float*          xe     = (float*)alloc((size_t)TN*TT*16*4);
  float*          se     = (float*)alloc((size_t)TN*16*4);
  unsigned short* wabf   = (unsigned short*)alloc((size_t)TN*196*128*2);
  float*          cbuf   = (float*)alloc((size_t)TN*512*4);
  unsigned short* hbfA   = (unsigned short*)alloc((size_t)TN*512*2);
  unsigned short* hbfB   = (unsigned short*)alloc((size_t)TN*512*2);
  unsigned short* ubf_all= (unsigned short*)alloc((size_t)TT*TN*96*2);
  unsigned short* cbf    = (unsigned short*)alloc((size_t)TN*TT*608*2);
  unsigned short* ybf    = (unsigned short*)alloc((size_t)TN*TT*1024*2);
  float*          obuf   = (float*)alloc((size_t)TN*TT*128*4);
  unsigned short* wgf    = (unsigned short*)alloc((size_t)1245184*2);
  float*          gbias  = (float*)alloc((size_t)2048*4);
  float*          gpart  = (float*)alloc((size_t)4*128*512*4);
  unsigned short* cwbf   = (unsigned short*)alloc((size_t)1024*608*2);
  unsigned short* owbf   = (unsigned short*)alloc((size_t)128*1024*2);
  float*          obias  = (float*)alloc((size_t)128*4);
  unsigned short* uwbf   = (unsigned short*)alloc((size_t)128*512*2);
  unsigned short* betabf = (unsigned short*)alloc((size_t)64*512*2);
  unsigned short* wwbf   = (unsigned short*)alloc((size_t)128*64*2);
  unsigned short* w2b    = (unsigned short*)alloc((size_t)32*160*2);
  unsigned short* w3b    = (unsigned short*)alloc((size_t)64*320*2);

  hipLaunchKernelGGL(k_conv1, dim3(6272), dim3(256), 0, stream, x_canv, conv1_w, conv1_b, c1bf);
  hipLaunchKernelGGL(k_prep, dim3(1042), dim3(256), 0, stream,
                     Whh, Wih, bih, bhh, comb_w, out_w, out_b, Uw, beta_w, Ww, conv2_w, conv3_w,
                     wgf, gbias, cwbf, owbf, obias, uwbf, betabf, wwbf, w2b, w3b);
  hipLaunchKernelGGL(k_im2col2, dim3(7840), dim3(256), 0, stream, c1bf, a2);
  hipLaunchKernelGGL(k_gconv2, dim3(784), dim3(256), 0, stream, a2, w2b, conv2_b, c2bf);
  hipLaunchKernelGGL(k_im2col3, dim3(3920), dim3(256), 0, stream, c2bf, a3);
  hipLaunchKernelGGL(k_gconv3, dim3(196), dim3(256), 0, stream, a3, w3b, conv3_b, afbf, abf);
  hipLaunchKernelGGL(k_amean, dim3(128), dim3(64), 0, stream, afbf, amean);
  hipLaunchKernelGGL(k_embed, dim3(520), dim3(256), 0, stream, x, start_, xemb_w, xemb_b, semb_w, semb_b, xe, se);
  hipLaunchKernelGGL(k_init, dim3(512), dim3(256), 0, stream, amean, se, init_w, init_b, hbfA, cbuf);
  hipLaunchKernelGGL(k_wa, dim3(196), dim3(256), 0, stream, abf, wwbf, Wb, wabf);
  hipLaunchKernelGGL(k_cbf_xs, dim3(2048), dim3(256), 0, stream, xe, se, cbf, ubf_all);

  for (int t = 0; t < TT; ++t){
    unsigned short* hin  = (t & 1) ? hbfB : hbfA;
    unsigned short* hout = (t & 1) ? hbfA : hbfB;
    hipLaunchKernelGGL(k_stepA, dim3(160), dim3(512), 0, stream, t,
                       hin, uwbf, Ub, betabf, beta_b, vw, vb, wabf, afbf, ubf_all, cbf, wgf, gpart);
    hipLaunchKernelGGL(k_stepB, dim3(32), dim3(512), 0, stream, t,
                       hout, ubf_all, wgf, gbias, gpart, cbuf, cbf);
  }

  hipLaunchKernelGGL(k_comb, dim3(64, 8), dim3(256), 0, stream, cbf, cwbf, comb_b, ybf);
  hipLaunchKernelGGL(k_out, dim3(64), dim3(256), 0, stream, ybf, owbf, obias, obuf);
  hipLaunchKernelGGL(k_post, dim3(32), dim3(256), 0, stream, obuf, (float*)d_out);
}

// Round 13
// 1485.576 us; speedup vs baseline: 1.4765x; 1.0308x over previous
//
#include <hip/hip_runtime.h>

// LSTMConditioned: conv-encoder + attention-LSTM (T=64) + MDN head.
// N=128, T=64, HID=512, COMB=1024, ATT=128, K=20, D=2, FMAP=64, L=196, ODIM=121.
// Loop: 2 launches/step (launch-boundary sync is the only cheap sync on MI355X;
// in-kernel cross-block sync measured 44-183us/step; zero-sync is per-CU-L2-BW bound).
// stepA (160 blk x 512thr) = attention (blk 0-127) || gates Whh-GEMM (blk 128-159).
// stepB (32 blk x 512thr) = z-part GEMM + fused cell update.
// Head/mid/tail kernels merged to cut graph nodes (launch overhead ~7us/node).

#define TN 128
#define TT 64

typedef __attribute__((ext_vector_type(4))) float f32x4;
typedef __attribute__((ext_vector_type(8))) short bf16x8;

__device__ __forceinline__ float fsigm(float x){ return __builtin_amdgcn_rcpf(1.0f + __expf(-x)); }
__device__ __forceinline__ float ftanh(float x){ return 1.0f - 2.0f*__builtin_amdgcn_rcpf(1.0f + __expf(2.0f*x)); }
__device__ __forceinline__ unsigned short f2bf(float f){
  unsigned int u = __float_as_uint(f);
  u += 0x7fffu + ((u >> 16) & 1u);
  return (unsigned short)(u >> 16);
}
__device__ __forceinline__ float b2f(unsigned short u){ return __uint_as_float(((unsigned)u)<<16); }
__device__ __forceinline__ void cvt8(unsigned short* d, const float* s){
  __align__(16) unsigned short vals[8];
  #pragma unroll
  for (int j=0;j<8;j++) vals[j] = f2bf(s[j]);
  *(float4*)d = *(float4*)vals;
}

// ---------------- device bodies ----------------
__device__ __forceinline__ void dev_conv1(int idx, const float* __restrict__ xc,
    const float* __restrict__ w, const float* __restrict__ b, unsigned short* __restrict__ c1bf){
  if (idx >= TN*16*784) return;
  int p = idx % 784, oc = (idx/784) & 15, n = idx/(784*16);
  int py = p/28, px = p%28;
  const float* src = xc + n*784;
  float acc = b[oc];
  #pragma unroll
  for (int ky=0;ky<3;ky++){
    int iy = py+ky-1; if (iy<0||iy>=28) continue;
    #pragma unroll
    for (int kx=0;kx<3;kx++){
      int ix = px+kx-1; if (ix<0||ix>=28) continue;
      acc += (src[iy*28+ix]-0.0243f)*(1.0f/0.1383f) * w[oc*9+ky*3+kx];
    }
  }
  c1bf[idx] = f2bf(fmaxf(acc, 0.0f));
}

__device__ __forceinline__ void dev_prep(int u,
    const float* __restrict__ Whh, const float* __restrict__ Wih,
    const float* __restrict__ bih, const float* __restrict__ bhh,
    const float* __restrict__ comb_w, const float* __restrict__ out_w, const float* __restrict__ out_b,
    const float* __restrict__ Uw, const float* __restrict__ beta_w, const float* __restrict__ Ww,
    const float* __restrict__ conv2_w, const float* __restrict__ conv3_w,
    unsigned short* __restrict__ wgf, float* __restrict__ gbias,
    unsigned short* __restrict__ cwbf, unsigned short* __restrict__ owbf, float* __restrict__ obias,
    unsigned short* __restrict__ uwbf, unsigned short* __restrict__ betabf, unsigned short* __restrict__ wwbf,
    unsigned short* __restrict__ w2b, unsigned short* __restrict__ w3b){
  if (u < 155648){   // wgf fragment order (units of 8)
    int fragi = u >> 6, lane = u & 63;
    int g = fragi / 608, rem = fragi - g*608;
    int b = rem / 19, kt = rem - b*19;
    int row = g*512 + b*16 + (lane & 15);
    int col = kt*32 + (lane >> 4)*8;
    __align__(16) unsigned short vals[8];
    if (col < 512){
      const float* s = Whh + (size_t)row*512 + col;
      #pragma unroll
      for (int j=0;j<8;j++) vals[j] = f2bf(s[j]);
    } else if (col - 512 < 80){
      const float* s = Wih + (size_t)row*80 + (col-512);
      #pragma unroll
      for (int j=0;j<8;j++) vals[j] = f2bf(s[j]);
    } else {
      #pragma unroll
      for (int j=0;j<8;j++) vals[j] = 0;
    }
    *(float4*)(wgf + (size_t)u*8) = *(float4*)vals;
    return;
  }
  u -= 155648;
  if (u < 256){
    #pragma unroll
    for (int j=0;j<8;j++) gbias[u*8+j] = bih[u*8+j] + bhh[u*8+j];
    return;
  }
  u -= 256;
  if (u < 77824){ cvt8(cwbf + (size_t)u*8, comb_w + (size_t)u*8); return; }
  u -= 77824;
  if (u < 16384){
    int o = u >> 7, k2 = (u & 127)*8;
    __align__(16) unsigned short vals[8];
    if (o < 121){
      const float* s = out_w + (size_t)o*1024 + k2;
      #pragma unroll
      for (int j=0;j<8;j++) vals[j] = f2bf(s[j]);
    } else {
      #pragma unroll
      for (int j=0;j<8;j++) vals[j] = 0;
    }
    *(float4*)(owbf + (size_t)u*8) = *(float4*)vals;
    return;
  }
  u -= 16384;
  if (u < 16){
    #pragma unroll
    for (int j=0;j<8;j++){ int i = u*8+j; obias[i] = (i<121)? out_b[i] : 0.0f; }
    return;
  }
  u -= 16;
  if (u < 8192){ cvt8(uwbf + (size_t)u*8, Uw + (size_t)u*8); return; }
  u -= 8192;
  if (u < 4096){ cvt8(betabf + (size_t)u*8, beta_w + (size_t)u*8); return; }
  u -= 4096;
  if (u < 1024){ cvt8(wwbf + (size_t)u*8, Ww + (size_t)u*8); return; }
  u -= 1024;
  if (u < 640){
    int o = u/20, k2 = (u - o*20)*8;
    if (k2 < 144) cvt8(w2b + (size_t)u*8, conv2_w + (size_t)o*144 + k2);
    else { __align__(16) unsigned short z[8] = {0,0,0,0,0,0,0,0}; *(float4*)(w2b + (size_t)u*8) = *(float4*)z; }
    return;
  }
  u -= 640;
  if (u < 2560){
    int o = u/40, k2 = (u - o*40)*8;
    if (k2 < 288) cvt8(w3b + (size_t)u*8, conv3_w + (size_t)o*288 + k2);
    else { __align__(16) unsigned short z[8] = {0,0,0,0,0,0,0,0}; *(float4*)(w3b + (size_t)u*8) = *(float4*)z; }
    return;
  }
}

// ---------------- head: conv1 || weight prep ----------------
__global__ __launch_bounds__(256) void k_head(const float* __restrict__ xc,
    const float* __restrict__ conv1_w, const float* __restrict__ conv1_b, unsigned short* __restrict__ c1bf,
    const float* __restrict__ Whh, const float* __restrict__ Wih,
    const float* __restrict__ bih, const float* __restrict__ bhh,
    const float* __restrict__ comb_w, const float* __restrict__ out_w, const float* __restrict__ out_b,
    const float* __restrict__ Uw, const float* __restrict__ beta_w, const float* __restrict__ Ww,
    const float* __restrict__ conv2_w, const float* __restrict__ conv3_w,
    unsigned short* __restrict__ wgf, float* __restrict__ gbias,
    unsigned short* __restrict__ cwbf, unsigned short* __restrict__ owbf, float* __restrict__ obias,
    unsigned short* __restrict__ uwbf, unsigned short* __restrict__ betabf, unsigned short* __restrict__ wwbf,
    unsigned short* __restrict__ w2b, unsigned short* __restrict__ w3b){
  int bid = blockIdx.x;
  if (bid < 6272) dev_conv1(bid*256 + threadIdx.x, xc, conv1_w, conv1_b, c1bf);
  else dev_prep((bid-6272)*256 + threadIdx.x, Whh, Wih, bih, bhh, comb_w, out_w, out_b,
                Uw, beta_w, Ww, conv2_w, conv3_w,
                wgf, gbias, cwbf, owbf, obias, uwbf, betabf, wwbf, w2b, w3b);
}

// ---------------- im2col for conv2 ----------------
__global__ __launch_bounds__(256) void k_im2col2(const unsigned short* __restrict__ c1bf, unsigned short* __restrict__ a2){
  int u = blockIdx.x*256 + threadIdx.x;   // 100352*20 units, grid 7840
  if (u >= 100352*20) return;
  int r = u / 20, k8 = (u - r*20)*8;
  int p = r % 784, n = r / 784;
  int py = p/28, px = p%28;
  __align__(16) unsigned short vals[8];
  #pragma unroll
  for (int j=0;j<8;j++){
    int k = k8 + j;
    unsigned short v = 0;
    if (k < 144){
      int ic = k/9, rem = k - ic*9, ky = rem/3, kx = rem - ky*3;
      int iy = py+ky-1, ix = px+kx-1;
      if (iy>=0 && iy<28 && ix>=0 && ix<28) v = c1bf[(n*16+ic)*784 + iy*28+ix];
    }
    vals[j] = v;
  }
  *(float4*)(a2 + (size_t)r*160 + k8) = *(float4*)vals;
}

// ---------------- conv2 GEMM ----------------
__global__ __launch_bounds__(256) void k_gconv2(const unsigned short* __restrict__ a2,
    const unsigned short* __restrict__ w2b, const float* __restrict__ b2,
    unsigned short* __restrict__ c2bf){
  int mbase = blockIdx.x*128;           // 784 blocks
  int tid = threadIdx.x, w = tid>>6, l = tid&63;
  int lr = l&15, lk = (l>>4)*8;
  __shared__ unsigned short at[128*168];
  {
    int row = tid>>1, off = (tid&1)*80;
    const unsigned short* sp = a2 + (size_t)(mbase+row)*160 + off;
    #pragma unroll
    for (int j=0;j<10;j++) *(float4*)&at[row*168 + off + j*8] = *(const float4*)(sp + j*8);
  }
  __syncthreads();
  f32x4 acc[2][2];
  #pragma unroll
  for (int mi=0;mi<2;mi++){ acc[mi][0]=(f32x4){0,0,0,0}; acc[mi][1]=(f32x4){0,0,0,0}; }
  for (int kt=0; kt<5; ++kt){
    bf16x8 b0 = *(const bf16x8*)(w2b + (0*16+lr)*160 + kt*32 + lk);
    bf16x8 b1 = *(const bf16x8*)(w2b + (1*16+lr)*160 + kt*32 + lk);
    #pragma unroll
    for (int mi=0;mi<2;mi++){
      bf16x8 afrag = *(const bf16x8*)&at[((2*w+mi)*16+lr)*168 + kt*32 + lk];
      acc[mi][0] = __builtin_amdgcn_mfma_f32_16x16x32_bf16(afrag, b0, acc[mi][0], 0,0,0);
      acc[mi][1] = __builtin_amdgcn_mfma_f32_16x16x32_bf16(afrag, b1, acc[mi][1], 0,0,0);
    }
  }
  #pragma unroll
  for (int mi=0;mi<2;mi++){
    #pragma unroll
    for (int j=0;j<2;j++){
      int oc = j*16 + lr;
      float bb = b2[oc];
      #pragma unroll
      for (int i=0;i<4;i++){
        int r = mbase + (2*w+mi)*16 + (l>>4)*4 + i;
        c2bf[(size_t)r*32 + oc] = f2bf(fmaxf(acc[mi][j][i] + bb, 0.0f));
      }
    }
  }
}

// ---------------- im2col for conv3 (stride 2) ----------------
__global__ __launch_bounds__(256) void k_im2col3(const unsigned short* __restrict__ c2bf, unsigned short* __restrict__ a3){
  int u = blockIdx.x*256 + threadIdx.x;   // 25088*40 units, grid 3920
  if (u >= 25088*40) return;
  int r = u / 40, k8 = (u - r*40)*8;
  int p = r % 196, n = r / 196;
  int py = p/14, px = p%14;
  __align__(16) unsigned short vals[8];
  #pragma unroll
  for (int j=0;j<8;j++){
    int k = k8 + j;
    unsigned short v = 0;
    if (k < 288){
      int ic = k/9, rem = k - ic*9, ky = rem/3, kx = rem - ky*3;
      int iy = 2*py+ky-1, ix = 2*px+kx-1;
      if (iy>=0 && iy<28 && ix>=0 && ix<28) v = c2bf[(size_t)(n*784 + iy*28+ix)*32 + ic];
    }
    vals[j] = v;
  }
  *(float4*)(a3 + (size_t)r*320 + k8) = *(float4*)vals;
}

// ---------------- conv3 GEMM: afbf[n][f][l] + abf[r][f] ----------------
__global__ __launch_bounds__(256) void k_gconv3(const unsigned short* __restrict__ a3,
    const unsigned short* __restrict__ w3b, const float* __restrict__ b3,
    unsigned short* __restrict__ afbf, unsigned short* __restrict__ abf){
  int mbase = blockIdx.x*128;           // 196 blocks
  int tid = threadIdx.x, w = tid>>6, l = tid&63;
  int lr = l&15, lk = (l>>4)*8;
  __shared__ unsigned short at[128*168];
  f32x4 acc[2][4];
  #pragma unroll
  for (int mi=0;mi<2;mi++)
    #pragma unroll
    for (int j=0;j<4;j++) acc[mi][j]=(f32x4){0,0,0,0};
  for (int kt2=0; kt2<2; ++kt2){
    {
      int row = tid>>1, off = (tid&1)*80;
      const unsigned short* sp = a3 + (size_t)(mbase+row)*320 + kt2*160 + off;
      #pragma unroll
      for (int j=0;j<10;j++) *(float4*)&at[row*168 + off + j*8] = *(const float4*)(sp + j*8);
    }
    __syncthreads();
    for (int kt=0; kt<5; ++kt){
      #pragma unroll
      for (int mi=0;mi<2;mi++){
        bf16x8 afrag = *(const bf16x8*)&at[((2*w+mi)*16+lr)*168 + kt*32 + lk];
        #pragma unroll
        for (int j=0;j<4;j++){
          bf16x8 bf = *(const bf16x8*)(w3b + (size_t)(j*16+lr)*320 + kt2*160 + kt*32 + lk);
          acc[mi][j] = __builtin_amdgcn_mfma_f32_16x16x32_bf16(afrag, bf, acc[mi][j], 0,0,0);
        }
      }
    }
    __syncthreads();
  }
  #pragma unroll
  for (int mi=0;mi<2;mi++){
    #pragma unroll
    for (int j=0;j<4;j++){
      int oc = j*16 + lr;
      float bb = b3[oc];
      #pragma unroll
      for (int i=0;i<4;i++){
        int r = mbase + (2*w+mi)*16 + (l>>4)*4 + i;
        int n = r/196, p = r - n*196;
        float v = ftanh(acc[mi][j][i] + bb);
        unsigned short vb16 = f2bf(v);
        afbf[(size_t)(n*64+oc)*196 + p] = vb16;
        abf[(size_t)r*64 + oc] = vb16;
      }
    }
  }
}

// ---------------- mid: amean || se || wa || cbf_xs(inline embeddings) ----------------
__global__ __launch_bounds__(256) void k_mid(
    const unsigned short* __restrict__ afbf, float* __restrict__ amean,
    const float* __restrict__ start, const float* __restrict__ sw, const float* __restrict__ sb,
    float* __restrict__ se,
    const unsigned short* __restrict__ abf, const unsigned short* __restrict__ wwbf,
    const float* __restrict__ Wb, unsigned short* __restrict__ wabf,
    const float* __restrict__ x, const float* __restrict__ xw, const float* __restrict__ xb,
    unsigned short* __restrict__ cbf, unsigned short* __restrict__ ubf_all)
{
  const int bid = blockIdx.x, tid = threadIdx.x;
  __shared__ __align__(16) unsigned short at[128*40];
  __shared__ float qp[4][64];
  if (bid < 128){
    // amean: sample n = bid
    int f = tid & 63, q = tid >> 6;
    const unsigned short* row = afbf + (size_t)(bid*64+f)*196 + q*49;
    float s = 0;
    #pragma unroll 7
    for (int l=0;l<49;l++) s += b2f(row[l]);
    qp[q][f] = s;
    __syncthreads();
    if (tid < 64) amean[bid*64+tid] = (qp[0][tid]+qp[1][tid]+qp[2][tid]+qp[3][tid]) * (1.0f/196.0f);
    return;
  }
  if (bid == 128){
    for (int i = tid; i < TN*16; i += 256){
      int j = i & 15, n = i >> 4;
      se[i] = ftanh(sb[j] + start[n*2]*sw[j*2] + start[n*2+1]*sw[j*2+1]);
    }
    return;
  }
  if (bid < 325){
    // wa GEMM: W_a = a @ Ww.T + Wb, stored bf16 [n][l][att]
    int mbase = (bid-129)*128;
    int w = tid>>6, l = tid&63;
    int lr = l & 15, lk = (l>>4)*8;
    f32x4 acc[8][2];
    #pragma unroll
    for (int m=0;m<8;m++){ acc[m][0] = (f32x4){0,0,0,0}; acc[m][1] = (f32x4){0,0,0,0}; }
    for (int kt=0; kt<2; ++kt){
      int row = tid>>1, half = (tid&1)*16;
      const unsigned short* sp = abf + (mbase+row)*64 + kt*32 + half;
      *(float4*)&at[row*40 + half]     = *(const float4*)sp;
      *(float4*)&at[row*40 + half + 8] = *(const float4*)(sp + 8);
      __syncthreads();
      bf16x8 b0 = *(const bf16x8*)(wwbf + ((2*w+0)*16 + lr)*64 + kt*32 + lk);
      bf16x8 b1 = *(const bf16x8*)(wwbf + ((2*w+1)*16 + lr)*64 + kt*32 + lk);
      #pragma unroll
      for (int m=0;m<8;m++){
        bf16x8 afrag = *(const bf16x8*)&at[(m*16+lr)*40 + lk];
        acc[m][0] = __builtin_amdgcn_mfma_f32_16x16x32_bf16(afrag, b0, acc[m][0], 0,0,0);
        acc[m][1] = __builtin_amdgcn_mfma_f32_16x16x32_bf16(afrag, b1, acc[m][1], 0,0,0);
      }
      __syncthreads();
    }
    #pragma unroll
    for (int m=0;m<8;m++){
      #pragma unroll
      for (int j=0;j<2;j++){
        int att = (2*w+j)*16 + lr;
        float wb = Wb[att];
        #pragma unroll
        for (int i=0;i<4;i++){
          int arow = mbase + m*16 + (l>>4)*4 + i;
          int n = arow/196, l2 = arow - n*196;
          wabf[((size_t)n*196 + l2)*128 + att] = f2bf(acc[m][j][i] + wb);
        }
      }
    }
    return;
  }
  // cbf/ubf fill with inline embeddings
  {
    int idx = (bid-325)*256 + tid;
    if (idx >= TN*TT*64) return;
    int j = idx & 63, r = idx >> 6;
    int n = r >> 6, t = r & 63;
    if (j < 16){
      float acc = xb[j];
      if (t > 0){ const float* xp = x + (n*TT + t-1)*2; acc += xp[0]*xw[j*2] + xp[1]*xw[j*2+1]; }
      cbf[(size_t)r*608 + 576 + j] = f2bf(ftanh(acc));
    } else if (j < 32){
      int jj = j-16;
      cbf[(size_t)r*608 + 592 + jj] = f2bf(ftanh(sb[jj] + start[n*2]*sw[jj*2] + start[n*2+1]*sw[jj*2+1]));
    } else if (j < 48){
      int jj = j-32;
      float acc = xb[jj];
      if (t > 0){ const float* xp = x + (n*TT + t-1)*2; acc += xp[0]*xw[jj*2] + xp[1]*xw[jj*2+1]; }
      ubf_all[((size_t)t*TN + n)*96 + jj] = f2bf(ftanh(acc));
    } else {
      ubf_all[((size_t)t*TN + n)*96 + 80 + (j-48)] = 0;
    }
  }
}

// ---------------- init h/c ----------------
__global__ __launch_bounds__(256) void k_init(const float* __restrict__ amean, const float* __restrict__ se,
    const float* __restrict__ w, const float* __restrict__ b,
    unsigned short* __restrict__ hbfA, float* __restrict__ cbuf){
  int idx = blockIdx.x*256 + threadIdx.x;
  if (idx >= TN*1024) return;
  int o = idx & 1023, n = idx >> 10;
  const float* wr = w + o*80;
  float acc = b[o];
  for (int k2=0;k2<64;k2++) acc += amean[n*64+k2]*wr[k2];
  for (int k2=0;k2<16;k2++) acc += se[n*16+k2]*wr[64+k2];
  float v = ftanh(acc);
  if (o & 1) cbuf[n*512 + (o>>1)] = v;
  else       hbfA[n*512 + (o>>1)] = f2bf(v);
}

// ---------------- step A: attention (blocks 0-127) || gates-h GEMM (blocks 128-159) ----------------
__global__ __launch_bounds__(512) void k_stepA(int t,
    const unsigned short* __restrict__ hbf_in,
    const unsigned short* __restrict__ uwbf, const float* __restrict__ Ub,
    const unsigned short* __restrict__ betabf, const float* __restrict__ beta_b,
    const float* __restrict__ vw, const float* __restrict__ vb,
    const unsigned short* __restrict__ wabf, const unsigned short* __restrict__ afbf,
    unsigned short* __restrict__ ubf_all, unsigned short* __restrict__ cbf,
    const unsigned short* __restrict__ wgf, float* __restrict__ gpart)
{
  const int bid = blockIdx.x, tid = threadIdx.x;
  __shared__ __align__(16) float hs[512];
  __shared__ __align__(16) float Uh[128];
  __shared__ __align__(16) float vws[128];
  __shared__ float bsig[64];
  __shared__ float ew[196];
  __shared__ float red[8];
  __shared__ float up[4][128];
  __shared__ float qp8[8][64];
  __shared__ float ep2[256][2];
  __shared__ __align__(16) unsigned short at2[128*516];   // 132 KB: full h-tile (gates role)

  if (bid < TN){
    // =================== attention role: sample n = bid ===================
    const int n = bid;
    hs[tid] = b2f(hbf_in[n*512 + tid]);
    if (tid < 128) vws[tid] = vw[tid];
    const float vb0 = vb[0];
    __syncthreads();
    // Uh partials: (att, k-quarter)
    {
      int att = tid & 127, q = tid >> 7;
      const unsigned short* uw = uwbf + (size_t)att*512 + q*128;
      const float* hh = hs + q*128;
      float acc = 0.f;
      #pragma unroll 4
      for (int k=0;k<128;k+=8){
        bf16x8 v = *(const bf16x8*)(uw + k);
        acc += hh[k+0]*b2f(v[0]) + hh[k+1]*b2f(v[1]) + hh[k+2]*b2f(v[2]) + hh[k+3]*b2f(v[3])
             + hh[k+4]*b2f(v[4]) + hh[k+5]*b2f(v[5]) + hh[k+6]*b2f(v[6]) + hh[k+7]*b2f(v[7]);
      }
      up[q][att] = acc;
    }
    // beta partials: (f, k-eighth)
    {
      int f = tid & 63, q = tid >> 6;
      const unsigned short* bw = betabf + (size_t)f*512 + q*64;
      const float* hh = hs + q*64;
      float acc = 0.f;
      #pragma unroll 4
      for (int k=0;k<64;k+=8){
        bf16x8 v = *(const bf16x8*)(bw + k);
        acc += hh[k+0]*b2f(v[0]) + hh[k+1]*b2f(v[1]) + hh[k+2]*b2f(v[2]) + hh[k+3]*b2f(v[3])
             + hh[k+4]*b2f(v[4]) + hh[k+5]*b2f(v[5]) + hh[k+6]*b2f(v[6]) + hh[k+7]*b2f(v[7]);
      }
      qp8[q][f] = acc;
    }
    __syncthreads();
    if (tid < 128) Uh[tid] = Ub[tid] + up[0][tid]+up[1][tid]+up[2][tid]+up[3][tid];
    else if (tid < 192){
      int f = tid-128;
      bsig[f] = fsigm(beta_b[f] + qp8[0][f]+qp8[1][f]+qp8[2][f]+qp8[3][f]
                                + qp8[4][f]+qp8[5][f]+qp8[6][f]+qp8[7][f]);
    }
    __syncthreads();
    // e partials: (l, att-half)
    {
      int l = tid >> 1, half = tid & 1;
      float acc = 0.f;
      if (l < 196){
        const unsigned short* wr = wabf + ((size_t)n*196 + l)*128 + half*64;
        const float* uh = Uh + half*64;
        const float* vv = vws + half*64;
        #pragma unroll 2
        for (int k=0;k<64;k+=8){
          bf16x8 wv = *(const bf16x8*)(wr + k);
          acc += vv[k+0]*ftanh(b2f(wv[0]) + uh[k+0]) + vv[k+1]*ftanh(b2f(wv[1]) + uh[k+1])
               + vv[k+2]*ftanh(b2f(wv[2]) + uh[k+2]) + vv[k+3]*ftanh(b2f(wv[3]) + uh[k+3])
               + vv[k+4]*ftanh(b2f(wv[4]) + uh[k+4]) + vv[k+5]*ftanh(b2f(wv[5]) + uh[k+5])
               + vv[k+6]*ftanh(b2f(wv[6]) + uh[k+6]) + vv[k+7]*ftanh(b2f(wv[7]) + uh[k+7]);
        }
      }
      ep2[l][half] = acc;
    }
    __syncthreads();
    // softmax WITHOUT max-pass: |e| <= |vb| + sum|vw| ~ 6, exp is fp32-safe
    float ex = 0.f;
    if (tid < 196) ex = __expf(vb0 + ep2[tid][0] + ep2[tid][1]);
    float ss = ex;
    #pragma unroll
    for (int off=32; off>0; off>>=1) ss += __shfl_xor(ss, off);
    if ((tid&63)==0) red[tid>>6] = ss;
    if (tid<196) ew[tid] = ex;
    __syncthreads();
    float inv = __builtin_amdgcn_rcpf(red[0]+red[1]+red[2]+red[3]+red[4]+red[5]+red[6]+red[7]);
    // z partials: (f, l-chunk of 25)
    {
      int f = tid & 63, q = tid >> 6;
      int l0 = q*25, l1 = (l0+25 < 196) ? l0+25 : 196;
      const unsigned short* an = afbf + (size_t)n*12544 + (size_t)f*196;
      float acc = 0.f;
      for (int l2=l0; l2<l1; l2++) acc += ew[l2]*b2f(an[l2]);
      qp8[q][f] = acc;
    }
    __syncthreads();
    if (tid < 64){
      float z = bsig[tid]*(qp8[0][tid]+qp8[1][tid]+qp8[2][tid]+qp8[3][tid]
                          +qp8[4][tid]+qp8[5][tid]+qp8[6][tid]+qp8[7][tid])*inv;
      unsigned short zb = f2bf(z);
      ubf_all[((size_t)t*TN + tid>=0 ? (size_t)t*TN + n : 0)*96 + 16 + tid] = zb;
      cbf[((size_t)n*TT + t)*608 + 512 + tid] = zb;
    }
  } else {
    // =================== gates Whh-part role: col-slice b (full h-tile staged once) ===================
    const int b = bid - TN;                       // 0..31
    const int w = tid>>6, l = tid&63, lr = l&15, li = l>>4, lk = li*8;
    const int g = w & 3, mh = w >> 2;             // wave -> (gate, M-half)
    bf16x8 wreg[16];
    {
      const unsigned short* wp = wgf + ((size_t)(g*32 + b)*19)*512 + (size_t)l*8;
      #pragma unroll
      for (int i=0;i<16;i++) wreg[i] = *(const bf16x8*)(wp + (size_t)i*512);
    }
    for (int i = tid; i < 8192; i += 512){
      int row = i >> 6, seg = (i & 63)*8;
      *(float4*)&at2[row*516 + seg] = *(const float4*)(hbf_in + (size_t)row*512 + seg);
    }
    __syncthreads();
    f32x4 acc[4];
    #pragma unroll
    for (int m2=0;m2<4;m2++) acc[m2] = (f32x4){0,0,0,0};
    #pragma unroll 4
    for (int kt=0; kt<16; ++kt){
      #pragma unroll
      for (int m2=0;m2<4;m2++){
        bf16x8 a = *(const bf16x8*)&at2[((mh*4+m2)*16 + lr)*516 + kt*32 + lk];
        acc[m2] = __builtin_amdgcn_mfma_f32_16x16x32_bf16(a, wreg[kt], acc[m2], 0,0,0);
      }
    }
    #pragma unroll
    for (int m2=0;m2<4;m2++){
      #pragma unroll
      for (int i=0;i<4;i++){
        int n2 = (mh*4+m2)*16 + li*4 + i;
        gpart[(((size_t)g*128 + n2)<<9) + b*16 + lr] = acc[m2][i];
      }
    }
  }
}

// ---------------- step B: z-part GEMM (direct u-frags) + cell update (32 blocks x 512 thr) ----------------
__global__ __launch_bounds__(512) void k_stepB(int t,
    unsigned short* __restrict__ hout,
    const unsigned short* __restrict__ ubf_all,
    const unsigned short* __restrict__ wgf, const float* __restrict__ gbias,
    const float* __restrict__ gpart,
    float* __restrict__ cbuf, unsigned short* __restrict__ cbf)
{
  const int b = blockIdx.x, tid = threadIdx.x;
  const int w = tid>>6, l = tid&63, lr = l&15, li = l>>4, lk = li*8;
  const int g = w & 3, mh = w >> 2;
  __shared__ float gsh[4][128][16];              // 32 KB: gate accumulators
  const unsigned short* ub = ubf_all + (size_t)t*TN*96;
  bf16x8 wz[3];
  {
    const unsigned short* wp = wgf + (((size_t)(g*32 + b)*19) + 16)*512 + (size_t)l*8;
    #pragma unroll
    for (int i=0;i<3;i++) wz[i] = *(const bf16x8*)(wp + (size_t)i*512);
  }
  for (int i = tid; i < 2048; i += 512){
    int gg = i>>9, r = i&511, n2 = r>>2, j4 = r&3;
    *(float4*)&gsh[gg][n2][j4*4] = *(const float4*)&gpart[(((size_t)gg*128 + n2)<<9) + b*16 + j4*4];
  }
  f32x4 acc[4];
  #pragma unroll
  for (int m2=0;m2<4;m2++) acc[m2] = (f32x4){0,0,0,0};
  #pragma unroll
  for (int kt=0; kt<3; ++kt){
    #pragma unroll
    for (int m2=0;m2<4;m2++){
      bf16x8 a = *(const bf16x8*)(ub + (size_t)((mh*4+m2)*16 + lr)*96 + kt*32 + lk);
      acc[m2] = __builtin_amdgcn_mfma_f32_16x16x32_bf16(a, wz[kt], acc[m2], 0,0,0);
    }
  }
  __syncthreads();   // gsh fully loaded
  #pragma unroll
  for (int m2=0;m2<4;m2++)
    #pragma unroll
    for (int i=0;i<4;i++)
      gsh[g][(mh*4+m2)*16 + li*4 + i][lr] += acc[m2][i];
  __syncthreads();
  #pragma unroll
  for (int e=0;e<4;++e){
    int c = tid*4 + e;
    int nn = c>>4, j = c&15;
    int hidx = b*16 + j;
    float gi = gsh[0][nn][j] + gbias[         hidx];
    float gf = gsh[1][nn][j] + gbias[1*512 + hidx];
    float gg = gsh[2][nn][j] + gbias[2*512 + hidx];
    float go = gsh[3][nn][j] + gbias[3*512 + hidx];
    float cc = cbuf[nn*512 + hidx];
    float cs = fsigm(gf)*cc + fsigm(gi)*ftanh(gg);
    float h  = fsigm(go)*ftanh(cs);
    cbuf[nn*512 + hidx] = cs;
    unsigned short hb = f2bf(h);
    hout[nn*512 + hidx] = hb;
    cbf[((size_t)nn*TT + t)*608 + hidx] = hb;
  }
}

// ---------------- comb GEMM ----------------
__global__ __launch_bounds__(256) void k_comb(const unsigned short* __restrict__ cbf,
    const unsigned short* __restrict__ cwbf, const float* __restrict__ comb_b,
    unsigned short* __restrict__ ybf){
  int mbase = blockIdx.x*128, obase = blockIdx.y*128;
  int tid = threadIdx.x, w = tid>>6, l = tid&63;
  int lr = l&15, lk = (l>>4)*8;
  __shared__ unsigned short at[128*40];
  f32x4 acc[8][2];
  #pragma unroll
  for (int m=0;m<8;m++){ acc[m][0] = (f32x4){0,0,0,0}; acc[m][1] = (f32x4){0,0,0,0}; }
  for (int kt=0; kt<19; ++kt){
    int row = tid>>1, half = (tid&1)*16;
    const unsigned short* sp = cbf + (size_t)(mbase+row)*608 + kt*32 + half;
    *(float4*)&at[row*40 + half]     = *(const float4*)sp;
    *(float4*)&at[row*40 + half + 8] = *(const float4*)(sp + 8);
    __syncthreads();
    bf16x8 b0 = *(const bf16x8*)(cwbf + (size_t)(obase + (2*w+0)*16 + lr)*608 + kt*32 + lk);
    bf16x8 b1 = *(const bf16x8*)(cwbf + (size_t)(obase + (2*w+1)*16 + lr)*608 + kt*32 + lk);
    #pragma unroll
    for (int m=0;m<8;m++){
      bf16x8 afrag = *(const bf16x8*)&at[(m*16+lr)*40 + lk];
      acc[m][0] = __builtin_amdgcn_mfma_f32_16x16x32_bf16(afrag, b0, acc[m][0], 0,0,0);
      acc[m][1] = __builtin_amdgcn_mfma_f32_16x16x32_bf16(afrag, b1, acc[m][1], 0,0,0);
    }
    __syncthreads();
  }
  #pragma unroll
  for (int m=0;m<8;m++){
    #pragma unroll
    for (int j=0;j<2;j++){
      int o = obase + (2*w+j)*16 + lr;
      float cb = comb_b[o];
      #pragma unroll
      for (int i=0;i<4;i++){
        int r = mbase + m*16 + (l>>4)*4 + i;
        ybf[(size_t)r*1024 + o] = f2bf(ftanh(acc[m][j][i] + cb));
      }
    }
  }
}

// ---------------- out GEMM + fused postprocess ----------------
__global__ __launch_bounds__(256) void k_out(const unsigned short* __restrict__ ybf,
    const unsigned short* __restrict__ owbf, const float* __restrict__ obias,
    float* __restrict__ out){
  int mbase = blockIdx.x*128;
  int tid = threadIdx.x, w = tid>>6, l = tid&63;
  int lr = l&15, lk = (l>>4)*8;
  __shared__ unsigned short at[128*40];
  __shared__ float osh[128][129];
  f32x4 acc[8][2];
  #pragma unroll
  for (int m=0;m<8;m++){ acc[m][0] = (f32x4){0,0,0,0}; acc[m][1] = (f32x4){0,0,0,0}; }
  for (int kt=0; kt<32; ++kt){
    int row = tid>>1, half = (tid&1)*16;
    const unsigned short* sp = ybf + (size_t)(mbase+row)*1024 + kt*32 + half;
    *(float4*)&at[row*40 + half]     = *(const float4*)sp;
    *(float4*)&at[row*40 + half + 8] = *(const float4*)(sp + 8);
    __syncthreads();
    bf16x8 b0 = *(const bf16x8*)(owbf + ((2*w+0)*16 + lr)*1024 + kt*32 + lk);
    bf16x8 b1 = *(const bf16x8*)(owbf + ((2*w+1)*16 + lr)*1024 + kt*32 + lk);
    #pragma unroll
    for (int m=0;m<8;m++){
      bf16x8 afrag = *(const bf16x8*)&at[(m*16+lr)*40 + lk];
      acc[m][0] = __builtin_amdgcn_mfma_f32_16x16x32_bf16(afrag, b0, acc[m][0], 0,0,0);
      acc[m][1] = __builtin_amdgcn_mfma_f32_16x16x32_bf16(afrag, b1, acc[m][1], 0,0,0);
    }
    __syncthreads();
  }
  #pragma unroll
  for (int m=0;m<8;m++){
    #pragma unroll
    for (int j=0;j<2;j++){
      int o = (2*w+j)*16 + lr;
      float ob = obias[o];
      #pragma unroll
      for (int i=0;i<4;i++){
        int r = m*16 + (l>>4)*4 + i;
        osh[r][o] = acc[m][j][i] + ob;
      }
    }
  }
  __syncthreads();
  if (tid < 128){
    const float* row = osh[tid];
    int r = mbase + tid;
    float mx = -1e30f;
    #pragma unroll
    for (int k2=0;k2<20;k2++) mx = fmaxf(mx, row[k2]);
    float e[20]; float s = 0;
    #pragma unroll
    for (int k2=0;k2<20;k2++){ e[k2] = __expf(row[k2]-mx); s += e[k2]; }
    float inv = __builtin_amdgcn_rcpf(s);
    float* mixo  = out;
    float* meano = out + 163840;
    float* scaleo= out + 491520;
    float* corro = out + 819200;
    float* vlogo = out + 983040;
    #pragma unroll
    for (int k2=0;k2<20;k2++) mixo[r*20+k2] = e[k2]*inv;
    #pragma unroll
    for (int j=0;j<40;j++) meano[r*40+j] = row[20+j];
    #pragma unroll
    for (int j=0;j<40;j++) scaleo[r*40+j] = __expf(row[60+j]);
    #pragma unroll
    for (int k2=0;k2<20;k2++) corro[r*20+k2] = ftanh(row[100+k2]);
    vlogo[r] = row[120];
  }
}

extern "C" void kernel_launch(void* const* d_in, const int* in_sizes, int n_in,
                              void* d_out, int out_size, void* d_ws, size_t ws_size,
                              hipStream_t stream){
  const float* x       = (const float*)d_in[0];
  const float* x_canv  = (const float*)d_in[1];
  const float* start_  = (const float*)d_in[2];
  const float* conv1_w = (const float*)d_in[3];
  const float* conv1_b = (const float*)d_in[4];
  const float* conv2_w = (const float*)d_in[5];
  const float* conv2_b = (const float*)d_in[6];
  const float* conv3_w = (const float*)d_in[7];
  const float* conv3_b = (const float*)d_in[8];
  const float* init_w  = (const float*)d_in[9];
  const float* init_b  = (const float*)d_in[10];
  const float* Uw      = (const float*)d_in[11];
  const float* Ub      = (const float*)d_in[12];
  const float* Ww      = (const float*)d_in[13];
  const float* Wb      = (const float*)d_in[14];
  const float* vw      = (const float*)d_in[15];
  const float* vb      = (const float*)d_in[16];
  const float* beta_w  = (const float*)d_in[17];
  const float* beta_b  = (const float*)d_in[18];
  const float* xemb_w  = (const float*)d_in[19];
  const float* xemb_b  = (const float*)d_in[20];
  const float* semb_w  = (const float*)d_in[21];
  const float* semb_b  = (const float*)d_in[22];
  const float* Wih     = (const float*)d_in[23];
  const float* Whh     = (const float*)d_in[24];
  const float* bih     = (const float*)d_in[25];
  const float* bhh     = (const float*)d_in[26];
  const float* comb_w  = (const float*)d_in[27];
  const float* comb_b  = (const float*)d_in[28];
  const float* out_w   = (const float*)d_in[29];
  const float* out_b   = (const float*)d_in[30];
  (void)in_sizes; (void)n_in; (void)out_size; (void)ws_size;

  char* wsb = (char*)d_ws;
  size_t off = 0;
  auto alloc = [&](size_t bytes)->char*{
    char* p = wsb + off;
    off = (off + bytes + 255) & ~(size_t)255;
    return p;
  };
  unsigned short* c1bf   = (unsigned short*)alloc((size_t)TN*16*784*2);
  unsigned short* a2     = (unsigned short*)alloc((size_t)100352*160*2);  // a3 aliases a2
  unsigned short* a3     = a2;
  unsigned short* c2bf   = (unsigned short*)alloc((size_t)100352*32*2);
  unsigned short* afbf   = (unsigned short*)alloc((size_t)TN*64*196*2);
  unsigned short* abf    = (unsigned short*)alloc((size_t)TN*196*64*2);
  float*          amean  = (float*)alloc((size_t)TN*64*4);
  float*          se     = (float*)alloc((size_t)TN*16*4);
  unsigned short* wabf   = (unsigned short*)alloc((size_t)TN*196*128*2);
  float*          cbuf   = (float*)alloc((size_t)TN*512*4);
  unsigned short* hbfA   = (unsigned short*)alloc((size_t)TN*512*2);
  unsigned short* hbfB   = (unsigned short*)alloc((size_t)TN*512*2);
  unsigned short* ubf_all= (unsigned short*)alloc((size_t)TT*TN*96*2);
  unsigned short* cbf    = (unsigned short*)alloc((size_t)TN*TT*608*2);
  unsigned short* ybf    = (unsigned short*)alloc((size_t)TN*TT*1024*2);
  unsigned short* wgf    = (unsigned short*)alloc((size_t)1245184*2);
  float*          gbias  = (float*)alloc((size_t)2048*4);
  float*          gpart  = (float*)alloc((size_t)4*128*512*4);
  unsigned short* cwbf   = (unsigned short*)alloc((size_t)1024*608*2);
  unsigned short* owbf   = (unsigned short*)alloc((size_t)128*1024*2);
  float*          obias  = (float*)alloc((size_t)128*4);
  unsigned short* uwbf   = (unsigned short*)alloc((size_t)128*512*2);
  unsigned short* betabf = (unsigned short*)alloc((size_t)64*512*2);
  unsigned short* wwbf   = (unsigned short*)alloc((size_t)128*64*2);
  unsigned short* w2b    = (unsigned short*)alloc((size_t)32*160*2);
  unsigned short* w3b    = (unsigned short*)alloc((size_t)64*320*2);

  hipLaunchKernelGGL(k_head, dim3(7314), dim3(256), 0, stream,
                     x_canv, conv1_w, conv1_b, c1bf,
                     Whh, Wih, bih, bhh, comb_w, out_w, out_b, Uw, beta_w, Ww, conv2_w, conv3_w,
                     wgf, gbias, cwbf, owbf, obias, uwbf, betabf, wwbf, w2b, w3b);
  hipLaunchKernelGGL(k_im2col2, dim3(7840), dim3(256), 0, stream, c1bf, a2);
  hipLaunchKernelGGL(k_gconv2, dim3(784), dim3(256), 0, stream, a2, w2b, conv2_b, c2bf);
  hipLaunchKernelGGL(k_im2col3, dim3(3920), dim3(256), 0, stream, c2bf, a3);
  hipLaunchKernelGGL(k_gconv3, dim3(196), dim3(256), 0, stream, a3, w3b, conv3_b, afbf, abf);
  hipLaunchKernelGGL(k_mid, dim3(2373), dim3(256), 0, stream,
                     afbf, amean, start_, semb_w, semb_b, se,
                     abf, wwbf, Wb, wabf,
                     x, xemb_w, xemb_b, cbf, ubf_all);
  hipLaunchKernelGGL(k_init, dim3(512), dim3(256), 0, stream, amean, se, init_w, init_b, hbfA, cbuf);

  for (int t = 0; t < TT; ++t){
    unsigned short* hin  = (t & 1) ? hbfB : hbfA;
    unsigned short* hout = (t & 1) ? hbfA : hbfB;
    hipLaunchKernelGGL(k_stepA, dim3(160), dim3(512), 0, stream, t,
                       hin, uwbf, Ub, betabf, beta_b, vw, vb, wabf, afbf, ubf_all, cbf, wgf, gpart);
    hipLaunchKernelGGL(k_stepB, dim3(32), dim3(512), 0, stream, t,
                       hout, ubf_all, wgf, gbias, gpart, cbuf, cbf);
  }

  hipLaunchKernelGGL(k_comb, dim3(64, 8), dim3(256), 0, stream, cbf, cwbf, comb_b, ybf);
  hipLaunchKernelGGL(k_out, dim3(64), dim3(256), 0, stream, ybf, owbf, obias, (float*)d_out);
}

// Round 14
// 1435.258 us; speedup vs baseline: 1.5283x; 1.0351x over previous
//
#include <hip/hip_runtime.h>

// LSTMConditioned: conv-encoder + attention-LSTM (T=64) + MDN head.
// N=128, T=64, HID=512, COMB=1024, ATT=128, K=20, D=2, FMAP=64, L=196, ODIM=121.
// Loop: 2 launches/step (launch-boundary sync is the only cheap sync on MI355X;
// in-kernel cross-block sync measured 44-183us/step; zero-sync is per-CU-L2-BW bound).
// stepA (160 blk x 512thr) = attention (blk 0-127) || gates Whh-GEMM (blk 128-159).
// stepB (32 blk x 512thr) = z-part GEMM + fused cell update (gpart in [g][b][n][16]
// layout so stepB reads are fully contiguous).

#define TN 128
#define TT 64

typedef __attribute__((ext_vector_type(4))) float f32x4;
typedef __attribute__((ext_vector_type(8))) short bf16x8;

__device__ __forceinline__ float fsigm(float x){ return __builtin_amdgcn_rcpf(1.0f + __expf(-x)); }
__device__ __forceinline__ float ftanh(float x){ return 1.0f - 2.0f*__builtin_amdgcn_rcpf(1.0f + __expf(2.0f*x)); }
__device__ __forceinline__ unsigned short f2bf(float f){
  unsigned int u = __float_as_uint(f);
  u += 0x7fffu + ((u >> 16) & 1u);
  return (unsigned short)(u >> 16);
}
__device__ __forceinline__ float b2f(unsigned short u){ return __uint_as_float(((unsigned)u)<<16); }
__device__ __forceinline__ void cvt8(unsigned short* d, const float* s){
  __align__(16) unsigned short vals[8];
  #pragma unroll
  for (int j=0;j<8;j++) vals[j] = f2bf(s[j]);
  *(float4*)d = *(float4*)vals;
}

// ---------------- device bodies ----------------
__device__ __forceinline__ void dev_conv1(int idx, const float* __restrict__ xc,
    const float* __restrict__ w, const float* __restrict__ b, unsigned short* __restrict__ c1bf){
  if (idx >= TN*16*784) return;
  int p = idx % 784, oc = (idx/784) & 15, n = idx/(784*16);
  int py = p/28, px = p%28;
  const float* src = xc + n*784;
  float acc = b[oc];
  #pragma unroll
  for (int ky=0;ky<3;ky++){
    int iy = py+ky-1; if (iy<0||iy>=28) continue;
    #pragma unroll
    for (int kx=0;kx<3;kx++){
      int ix = px+kx-1; if (ix<0||ix>=28) continue;
      acc += (src[iy*28+ix]-0.0243f)*(1.0f/0.1383f) * w[oc*9+ky*3+kx];
    }
  }
  c1bf[idx] = f2bf(fmaxf(acc, 0.0f));
}

__device__ __forceinline__ void dev_prep(int u,
    const float* __restrict__ Whh, const float* __restrict__ Wih,
    const float* __restrict__ bih, const float* __restrict__ bhh,
    const float* __restrict__ comb_w, const float* __restrict__ out_w, const float* __restrict__ out_b,
    const float* __restrict__ Uw, const float* __restrict__ beta_w, const float* __restrict__ Ww,
    const float* __restrict__ conv2_w, const float* __restrict__ conv3_w,
    unsigned short* __restrict__ wgf, float* __restrict__ gbias,
    unsigned short* __restrict__ cwbf, unsigned short* __restrict__ owbf, float* __restrict__ obias,
    unsigned short* __restrict__ uwbf, unsigned short* __restrict__ betabf, unsigned short* __restrict__ wwbf,
    unsigned short* __restrict__ w2b, unsigned short* __restrict__ w3b){
  if (u < 155648){   // wgf fragment order (units of 8)
    int fragi = u >> 6, lane = u & 63;
    int g = fragi / 608, rem = fragi - g*608;
    int b = rem / 19, kt = rem - b*19;
    int row = g*512 + b*16 + (lane & 15);
    int col = kt*32 + (lane >> 4)*8;
    __align__(16) unsigned short vals[8];
    if (col < 512){
      const float* s = Whh + (size_t)row*512 + col;
      #pragma unroll
      for (int j=0;j<8;j++) vals[j] = f2bf(s[j]);
    } else if (col - 512 < 80){
      const float* s = Wih + (size_t)row*80 + (col-512);
      #pragma unroll
      for (int j=0;j<8;j++) vals[j] = f2bf(s[j]);
    } else {
      #pragma unroll
      for (int j=0;j<8;j++) vals[j] = 0;
    }
    *(float4*)(wgf + (size_t)u*8) = *(float4*)vals;
    return;
  }
  u -= 155648;
  if (u < 256){
    #pragma unroll
    for (int j=0;j<8;j++) gbias[u*8+j] = bih[u*8+j] + bhh[u*8+j];
    return;
  }
  u -= 256;
  if (u < 77824){ cvt8(cwbf + (size_t)u*8, comb_w + (size_t)u*8); return; }
  u -= 77824;
  if (u < 16384){
    int o = u >> 7, k2 = (u & 127)*8;
    __align__(16) unsigned short vals[8];
    if (o < 121){
      const float* s = out_w + (size_t)o*1024 + k2;
      #pragma unroll
      for (int j=0;j<8;j++) vals[j] = f2bf(s[j]);
    } else {
      #pragma unroll
      for (int j=0;j<8;j++) vals[j] = 0;
    }
    *(float4*)(owbf + (size_t)u*8) = *(float4*)vals;
    return;
  }
  u -= 16384;
  if (u < 16){
    #pragma unroll
    for (int j=0;j<8;j++){ int i = u*8+j; obias[i] = (i<121)? out_b[i] : 0.0f; }
    return;
  }
  u -= 16;
  if (u < 8192){ cvt8(uwbf + (size_t)u*8, Uw + (size_t)u*8); return; }
  u -= 8192;
  if (u < 4096){ cvt8(betabf + (size_t)u*8, beta_w + (size_t)u*8); return; }
  u -= 4096;
  if (u < 1024){ cvt8(wwbf + (size_t)u*8, Ww + (size_t)u*8); return; }
  u -= 1024;
  if (u < 640){
    int o = u/20, k2 = (u - o*20)*8;
    if (k2 < 144) cvt8(w2b + (size_t)u*8, conv2_w + (size_t)o*144 + k2);
    else { __align__(16) unsigned short z[8] = {0,0,0,0,0,0,0,0}; *(float4*)(w2b + (size_t)u*8) = *(float4*)z; }
    return;
  }
  u -= 640;
  if (u < 2560){
    int o = u/40, k2 = (u - o*40)*8;
    if (k2 < 288) cvt8(w3b + (size_t)u*8, conv3_w + (size_t)o*288 + k2);
    else { __align__(16) unsigned short z[8] = {0,0,0,0,0,0,0,0}; *(float4*)(w3b + (size_t)u*8) = *(float4*)z; }
    return;
  }
}

// ---------------- head: conv1 || weight prep ----------------
__global__ __launch_bounds__(256) void k_head(const float* __restrict__ xc,
    const float* __restrict__ conv1_w, const float* __restrict__ conv1_b, unsigned short* __restrict__ c1bf,
    const float* __restrict__ Whh, const float* __restrict__ Wih,
    const float* __restrict__ bih, const float* __restrict__ bhh,
    const float* __restrict__ comb_w, const float* __restrict__ out_w, const float* __restrict__ out_b,
    const float* __restrict__ Uw, const float* __restrict__ beta_w, const float* __restrict__ Ww,
    const float* __restrict__ conv2_w, const float* __restrict__ conv3_w,
    unsigned short* __restrict__ wgf, float* __restrict__ gbias,
    unsigned short* __restrict__ cwbf, unsigned short* __restrict__ owbf, float* __restrict__ obias,
    unsigned short* __restrict__ uwbf, unsigned short* __restrict__ betabf, unsigned short* __restrict__ wwbf,
    unsigned short* __restrict__ w2b, unsigned short* __restrict__ w3b){
  int bid = blockIdx.x;
  if (bid < 6272) dev_conv1(bid*256 + threadIdx.x, xc, conv1_w, conv1_b, c1bf);
  else dev_prep((bid-6272)*256 + threadIdx.x, Whh, Wih, bih, bhh, comb_w, out_w, out_b,
                Uw, beta_w, Ww, conv2_w, conv3_w,
                wgf, gbias, cwbf, owbf, obias, uwbf, betabf, wwbf, w2b, w3b);
}

// ---------------- im2col for conv2 ----------------
__global__ __launch_bounds__(256) void k_im2col2(const unsigned short* __restrict__ c1bf, unsigned short* __restrict__ a2){
  int u = blockIdx.x*256 + threadIdx.x;   // 100352*20 units, grid 7840
  if (u >= 100352*20) return;
  int r = u / 20, k8 = (u - r*20)*8;
  int p = r % 784, n = r / 784;
  int py = p/28, px = p%28;
  __align__(16) unsigned short vals[8];
  #pragma unroll
  for (int j=0;j<8;j++){
    int k = k8 + j;
    unsigned short v = 0;
    if (k < 144){
      int ic = k/9, rem = k - ic*9, ky = rem/3, kx = rem - ky*3;
      int iy = py+ky-1, ix = px+kx-1;
      if (iy>=0 && iy<28 && ix>=0 && ix<28) v = c1bf[(n*16+ic)*784 + iy*28+ix];
    }
    vals[j] = v;
  }
  *(float4*)(a2 + (size_t)r*160 + k8) = *(float4*)vals;
}

// ---------------- conv2 GEMM ----------------
__global__ __launch_bounds__(256) void k_gconv2(const unsigned short* __restrict__ a2,
    const unsigned short* __restrict__ w2b, const float* __restrict__ b2,
    unsigned short* __restrict__ c2bf){
  int mbase = blockIdx.x*128;           // 784 blocks
  int tid = threadIdx.x, w = tid>>6, l = tid&63;
  int lr = l&15, lk = (l>>4)*8;
  __shared__ unsigned short at[128*168];
  {
    int row = tid>>1, off = (tid&1)*80;
    const unsigned short* sp = a2 + (size_t)(mbase+row)*160 + off;
    #pragma unroll
    for (int j=0;j<10;j++) *(float4*)&at[row*168 + off + j*8] = *(const float4*)(sp + j*8);
  }
  __syncthreads();
  f32x4 acc[2][2];
  #pragma unroll
  for (int mi=0;mi<2;mi++){ acc[mi][0]=(f32x4){0,0,0,0}; acc[mi][1]=(f32x4){0,0,0,0}; }
  for (int kt=0; kt<5; ++kt){
    bf16x8 b0 = *(const bf16x8*)(w2b + (0*16+lr)*160 + kt*32 + lk);
    bf16x8 b1 = *(const bf16x8*)(w2b + (1*16+lr)*160 + kt*32 + lk);
    #pragma unroll
    for (int mi=0;mi<2;mi++){
      bf16x8 afrag = *(const bf16x8*)&at[((2*w+mi)*16+lr)*168 + kt*32 + lk];
      acc[mi][0] = __builtin_amdgcn_mfma_f32_16x16x32_bf16(afrag, b0, acc[mi][0], 0,0,0);
      acc[mi][1] = __builtin_amdgcn_mfma_f32_16x16x32_bf16(afrag, b1, acc[mi][1], 0,0,0);
    }
  }
  #pragma unroll
  for (int mi=0;mi<2;mi++){
    #pragma unroll
    for (int j=0;j<2;j++){
      int oc = j*16 + lr;
      float bb = b2[oc];
      #pragma unroll
      for (int i=0;i<4;i++){
        int r = mbase + (2*w+mi)*16 + (l>>4)*4 + i;
        c2bf[(size_t)r*32 + oc] = f2bf(fmaxf(acc[mi][j][i] + bb, 0.0f));
      }
    }
  }
}

// ---------------- im2col for conv3 (stride 2) ----------------
__global__ __launch_bounds__(256) void k_im2col3(const unsigned short* __restrict__ c2bf, unsigned short* __restrict__ a3){
  int u = blockIdx.x*256 + threadIdx.x;   // 25088*40 units, grid 3920
  if (u >= 25088*40) return;
  int r = u / 40, k8 = (u - r*40)*8;
  int p = r % 196, n = r / 196;
  int py = p/14, px = p%14;
  __align__(16) unsigned short vals[8];
  #pragma unroll
  for (int j=0;j<8;j++){
    int k = k8 + j;
    unsigned short v = 0;
    if (k < 288){
      int ic = k/9, rem = k - ic*9, ky = rem/3, kx = rem - ky*3;
      int iy = 2*py+ky-1, ix = 2*px+kx-1;
      if (iy>=0 && iy<28 && ix>=0 && ix<28) v = c2bf[(size_t)(n*784 + iy*28+ix)*32 + ic];
    }
    vals[j] = v;
  }
  *(float4*)(a3 + (size_t)r*320 + k8) = *(float4*)vals;
}

// ---------------- conv3 GEMM: afbf[n][f][l] + abf[r][f] ----------------
__global__ __launch_bounds__(256) void k_gconv3(const unsigned short* __restrict__ a3,
    const unsigned short* __restrict__ w3b, const float* __restrict__ b3,
    unsigned short* __restrict__ afbf, unsigned short* __restrict__ abf){
  int mbase = blockIdx.x*128;           // 196 blocks
  int tid = threadIdx.x, w = tid>>6, l = tid&63;
  int lr = l&15, lk = (l>>4)*8;
  __shared__ unsigned short at[128*168];
  f32x4 acc[2][4];
  #pragma unroll
  for (int mi=0;mi<2;mi++)
    #pragma unroll
    for (int j=0;j<4;j++) acc[mi][j]=(f32x4){0,0,0,0};
  for (int kt2=0; kt2<2; ++kt2){
    {
      int row = tid>>1, off = (tid&1)*80;
      const unsigned short* sp = a3 + (size_t)(mbase+row)*320 + kt2*160 + off;
      #pragma unroll
      for (int j=0;j<10;j++) *(float4*)&at[row*168 + off + j*8] = *(const float4*)(sp + j*8);
    }
    __syncthreads();
    for (int kt=0; kt<5; ++kt){
      #pragma unroll
      for (int mi=0;mi<2;mi++){
        bf16x8 afrag = *(const bf16x8*)&at[((2*w+mi)*16+lr)*168 + kt*32 + lk];
        #pragma unroll
        for (int j=0;j<4;j++){
          bf16x8 bf = *(const bf16x8*)(w3b + (size_t)(j*16+lr)*320 + kt2*160 + kt*32 + lk);
          acc[mi][j] = __builtin_amdgcn_mfma_f32_16x16x32_bf16(afrag, bf, acc[mi][j], 0,0,0);
        }
      }
    }
    __syncthreads();
  }
  #pragma unroll
  for (int mi=0;mi<2;mi++){
    #pragma unroll
    for (int j=0;j<4;j++){
      int oc = j*16 + lr;
      float bb = b3[oc];
      #pragma unroll
      for (int i=0;i<4;i++){
        int r = mbase + (2*w+mi)*16 + (l>>4)*4 + i;
        int n = r/196, p = r - n*196;
        float v = ftanh(acc[mi][j][i] + bb);
        unsigned short vb16 = f2bf(v);
        afbf[(size_t)(n*64+oc)*196 + p] = vb16;
        abf[(size_t)r*64 + oc] = vb16;
      }
    }
  }
}

// ---------------- mid: wa || cbf/ubf fill || h/c init (self-contained amean/se) ----------------
__global__ __launch_bounds__(256) void k_mid(
    const unsigned short* __restrict__ afbf,
    const float* __restrict__ start, const float* __restrict__ sw, const float* __restrict__ sb,
    const unsigned short* __restrict__ abf, const unsigned short* __restrict__ wwbf,
    const float* __restrict__ Wb, unsigned short* __restrict__ wabf,
    const float* __restrict__ x, const float* __restrict__ xw, const float* __restrict__ xb,
    unsigned short* __restrict__ cbf, unsigned short* __restrict__ ubf_all,
    const float* __restrict__ init_w, const float* __restrict__ init_b,
    unsigned short* __restrict__ hbfA, float* __restrict__ cbuf)
{
  const int bid = blockIdx.x, tid = threadIdx.x;
  __shared__ __align__(16) unsigned short at[128*40];
  __shared__ float qp[4][64];
  __shared__ float am[64];
  __shared__ float sse[16];
  if (bid < 196){
    // wa GEMM: W_a = a @ Ww.T + Wb, stored bf16 [n][l][att]
    int mbase = bid*128;
    int w = tid>>6, l = tid&63;
    int lr = l & 15, lk = (l>>4)*8;
    f32x4 acc[8][2];
    #pragma unroll
    for (int m=0;m<8;m++){ acc[m][0] = (f32x4){0,0,0,0}; acc[m][1] = (f32x4){0,0,0,0}; }
    for (int kt=0; kt<2; ++kt){
      int row = tid>>1, half = (tid&1)*16;
      const unsigned short* sp = abf + (mbase+row)*64 + kt*32 + half;
      *(float4*)&at[row*40 + half]     = *(const float4*)sp;
      *(float4*)&at[row*40 + half + 8] = *(const float4*)(sp + 8);
      __syncthreads();
      bf16x8 b0 = *(const bf16x8*)(wwbf + ((2*w+0)*16 + lr)*64 + kt*32 + lk);
      bf16x8 b1 = *(const bf16x8*)(wwbf + ((2*w+1)*16 + lr)*64 + kt*32 + lk);
      #pragma unroll
      for (int m=0;m<8;m++){
        bf16x8 afrag = *(const bf16x8*)&at[(m*16+lr)*40 + lk];
        acc[m][0] = __builtin_amdgcn_mfma_f32_16x16x32_bf16(afrag, b0, acc[m][0], 0,0,0);
        acc[m][1] = __builtin_amdgcn_mfma_f32_16x16x32_bf16(afrag, b1, acc[m][1], 0,0,0);
      }
      __syncthreads();
    }
    #pragma unroll
    for (int m=0;m<8;m++){
      #pragma unroll
      for (int j=0;j<2;j++){
        int att = (2*w+j)*16 + lr;
        float wb = Wb[att];
        #pragma unroll
        for (int i=0;i<4;i++){
          int arow = mbase + m*16 + (l>>4)*4 + i;
          int n = arow/196, l2 = arow - n*196;
          wabf[((size_t)n*196 + l2)*128 + att] = f2bf(acc[m][j][i] + wb);
        }
      }
    }
    return;
  }
  if (bid < 2244){
    // cbf/ubf fill with inline embeddings
    int idx = (bid-196)*256 + tid;
    if (idx >= TN*TT*64) return;
    int j = idx & 63, r = idx >> 6;
    int n = r >> 6, t = r & 63;
    if (j < 16){
      float acc = xb[j];
      if (t > 0){ const float* xp = x + (n*TT + t-1)*2; acc += xp[0]*xw[j*2] + xp[1]*xw[j*2+1]; }
      cbf[(size_t)r*608 + 576 + j] = f2bf(ftanh(acc));
    } else if (j < 32){
      int jj = j-16;
      cbf[(size_t)r*608 + 592 + jj] = f2bf(ftanh(sb[jj] + start[n*2]*sw[jj*2] + start[n*2+1]*sw[jj*2+1]));
    } else if (j < 48){
      int jj = j-32;
      float acc = xb[jj];
      if (t > 0){ const float* xp = x + (n*TT + t-1)*2; acc += xp[0]*xw[jj*2] + xp[1]*xw[jj*2+1]; }
      ubf_all[((size_t)t*TN + n)*96 + jj] = f2bf(ftanh(acc));
    } else {
      ubf_all[((size_t)t*TN + n)*96 + 80 + (j-48)] = 0;
    }
    return;
  }
  // init role: sample n = bid-2244; recompute amean/se locally, then 1024 dot-80s
  {
    const int n = bid - 2244;
    int f = tid & 63, q = tid >> 6;
    const unsigned short* row = afbf + (size_t)(n*64+f)*196 + q*49;
    float s = 0;
    #pragma unroll 7
    for (int l=0;l<49;l++) s += b2f(row[l]);
    qp[q][f] = s;
    __syncthreads();
    if (tid < 64) am[tid] = (qp[0][tid]+qp[1][tid]+qp[2][tid]+qp[3][tid]) * (1.0f/196.0f);
    else if (tid < 80){
      int j = tid-64;
      sse[j] = ftanh(sb[j] + start[n*2]*sw[j*2] + start[n*2+1]*sw[j*2+1]);
    }
    __syncthreads();
    #pragma unroll
    for (int k=0;k<4;k++){
      int o = tid + k*256;
      const float* wr = init_w + (size_t)o*80;
      float acc = init_b[o];
      #pragma unroll 8
      for (int k2=0;k2<64;k2++) acc += am[k2]*wr[k2];
      #pragma unroll
      for (int k2=0;k2<16;k2++) acc += sse[k2]*wr[64+k2];
      float v = ftanh(acc);
      if (o & 1) cbuf[n*512 + (o>>1)] = v;
      else       hbfA[n*512 + (o>>1)] = f2bf(v);
    }
  }
}

// ---------------- step A: attention (blocks 0-127) || gates-h GEMM (blocks 128-159) ----------------
__global__ __launch_bounds__(512) void k_stepA(int t,
    const unsigned short* __restrict__ hbf_in,
    const unsigned short* __restrict__ uwbf, const float* __restrict__ Ub,
    const unsigned short* __restrict__ betabf, const float* __restrict__ beta_b,
    const float* __restrict__ vw, const float* __restrict__ vb,
    const unsigned short* __restrict__ wabf, const unsigned short* __restrict__ afbf,
    unsigned short* __restrict__ ubf_all, unsigned short* __restrict__ cbf,
    const unsigned short* __restrict__ wgf, float* __restrict__ gpart)
{
  const int bid = blockIdx.x, tid = threadIdx.x;
  __shared__ __align__(16) float hs[512];
  __shared__ __align__(16) float Uh[128];
  __shared__ __align__(16) float vws[128];
  __shared__ float bsig[64];
  __shared__ float ew[196];
  __shared__ float red[8];
  __shared__ float up[4][128];
  __shared__ float qp8[8][64];
  __shared__ float ep2[256][2];
  __shared__ __align__(16) unsigned short at2[128*516];   // 132 KB: full h-tile (gates role)

  if (bid < TN){
    // =================== attention role: sample n = bid ===================
    const int n = bid;
    hs[tid] = b2f(hbf_in[n*512 + tid]);
    if (tid < 128) vws[tid] = vw[tid];
    const float vb0 = vb[0];
    __syncthreads();
    // Uh partials: (att, k-quarter)
    {
      int att = tid & 127, q = tid >> 7;
      const unsigned short* uw = uwbf + (size_t)att*512 + q*128;
      const float* hh = hs + q*128;
      float acc = 0.f;
      #pragma unroll 4
      for (int k=0;k<128;k+=8){
        bf16x8 v = *(const bf16x8*)(uw + k);
        acc += hh[k+0]*b2f(v[0]) + hh[k+1]*b2f(v[1]) + hh[k+2]*b2f(v[2]) + hh[k+3]*b2f(v[3])
             + hh[k+4]*b2f(v[4]) + hh[k+5]*b2f(v[5]) + hh[k+6]*b2f(v[6]) + hh[k+7]*b2f(v[7]);
      }
      up[q][att] = acc;
    }
    // beta partials: (f, k-eighth)
    {
      int f = tid & 63, q = tid >> 6;
      const unsigned short* bw = betabf + (size_t)f*512 + q*64;
      const float* hh = hs + q*64;
      float acc = 0.f;
      #pragma unroll 4
      for (int k=0;k<64;k+=8){
        bf16x8 v = *(const bf16x8*)(bw + k);
        acc += hh[k+0]*b2f(v[0]) + hh[k+1]*b2f(v[1]) + hh[k+2]*b2f(v[2]) + hh[k+3]*b2f(v[3])
             + hh[k+4]*b2f(v[4]) + hh[k+5]*b2f(v[5]) + hh[k+6]*b2f(v[6]) + hh[k+7]*b2f(v[7]);
      }
      qp8[q][f] = acc;
    }
    __syncthreads();
    if (tid < 128) Uh[tid] = Ub[tid] + up[0][tid]+up[1][tid]+up[2][tid]+up[3][tid];
    else if (tid < 192){
      int f = tid-128;
      bsig[f] = fsigm(beta_b[f] + qp8[0][f]+qp8[1][f]+qp8[2][f]+qp8[3][f]
                                + qp8[4][f]+qp8[5][f]+qp8[6][f]+qp8[7][f]);
    }
    __syncthreads();
    // e partials: (l, att-half)
    {
      int l = tid >> 1, half = tid & 1;
      float acc = 0.f;
      if (l < 196){
        const unsigned short* wr = wabf + ((size_t)n*196 + l)*128 + half*64;
        const float* uh = Uh + half*64;
        const float* vv = vws + half*64;
        #pragma unroll 2
        for (int k=0;k<64;k+=8){
          bf16x8 wv = *(const bf16x8*)(wr + k);
          acc += vv[k+0]*ftanh(b2f(wv[0]) + uh[k+0]) + vv[k+1]*ftanh(b2f(wv[1]) + uh[k+1])
               + vv[k+2]*ftanh(b2f(wv[2]) + uh[k+2]) + vv[k+3]*ftanh(b2f(wv[3]) + uh[k+3])
               + vv[k+4]*ftanh(b2f(wv[4]) + uh[k+4]) + vv[k+5]*ftanh(b2f(wv[5]) + uh[k+5])
               + vv[k+6]*ftanh(b2f(wv[6]) + uh[k+6]) + vv[k+7]*ftanh(b2f(wv[7]) + uh[k+7]);
        }
      }
      ep2[l][half] = acc;
    }
    __syncthreads();
    // softmax WITHOUT max-pass: |e| <= |vb| + sum|vw| ~ 6, exp is fp32-safe
    float ex = 0.f;
    if (tid < 196) ex = __expf(vb0 + ep2[tid][0] + ep2[tid][1]);
    float ss = ex;
    #pragma unroll
    for (int off=32; off>0; off>>=1) ss += __shfl_xor(ss, off);
    if ((tid&63)==0) red[tid>>6] = ss;
    if (tid<196) ew[tid] = ex;
    __syncthreads();
    float inv = __builtin_amdgcn_rcpf(red[0]+red[1]+red[2]+red[3]+red[4]+red[5]+red[6]+red[7]);
    // z partials: (f, l-chunk of 25)
    {
      int f = tid & 63, q = tid >> 6;
      int l0 = q*25, l1 = (l0+25 < 196) ? l0+25 : 196;
      const unsigned short* an = afbf + (size_t)n*12544 + (size_t)f*196;
      float acc = 0.f;
      for (int l2=l0; l2<l1; l2++) acc += ew[l2]*b2f(an[l2]);
      qp8[q][f] = acc;
    }
    __syncthreads();
    if (tid < 64){
      float z = bsig[tid]*(qp8[0][tid]+qp8[1][tid]+qp8[2][tid]+qp8[3][tid]
                          +qp8[4][tid]+qp8[5][tid]+qp8[6][tid]+qp8[7][tid])*inv;
      unsigned short zb = f2bf(z);
      ubf_all[((size_t)t*TN + n)*96 + 16 + tid] = zb;
      cbf[((size_t)n*TT + t)*608 + 512 + tid] = zb;
    }
  } else {
    // =================== gates Whh-part role: col-slice b (full h-tile staged once) ===================
    const int b = bid - TN;                       // 0..31
    const int w = tid>>6, l = tid&63, lr = l&15, li = l>>4, lk = li*8;
    const int g = w & 3, mh = w >> 2;             // wave -> (gate, M-half)
    bf16x8 wreg[16];
    {
      const unsigned short* wp = wgf + ((size_t)(g*32 + b)*19)*512 + (size_t)l*8;
      #pragma unroll
      for (int i=0;i<16;i++) wreg[i] = *(const bf16x8*)(wp + (size_t)i*512);
    }
    for (int i = tid; i < 8192; i += 512){
      int row = i >> 6, seg = (i & 63)*8;
      *(float4*)&at2[row*516 + seg] = *(const float4*)(hbf_in + (size_t)row*512 + seg);
    }
    __syncthreads();
    f32x4 acc[4];
    #pragma unroll
    for (int m2=0;m2<4;m2++) acc[m2] = (f32x4){0,0,0,0};
    #pragma unroll 4
    for (int kt=0; kt<16; ++kt){
      #pragma unroll
      for (int m2=0;m2<4;m2++){
        bf16x8 a = *(const bf16x8*)&at2[((mh*4+m2)*16 + lr)*516 + kt*32 + lk];
        acc[m2] = __builtin_amdgcn_mfma_f32_16x16x32_bf16(a, wreg[kt], acc[m2], 0,0,0);
      }
    }
    // gpart layout [g][b][n][16] -> stepB reads are contiguous
    #pragma unroll
    for (int m2=0;m2<4;m2++){
      #pragma unroll
      for (int i=0;i<4;i++){
        int n2 = (mh*4+m2)*16 + li*4 + i;
        gpart[(((size_t)(g*32 + b)*128 + n2)<<4) + lr] = acc[m2][i];
      }
    }
  }
}

// ---------------- step B: z-part GEMM (direct u-frags) + cell update (32 blocks x 512 thr) ----------------
__global__ __launch_bounds__(512) void k_stepB(int t,
    unsigned short* __restrict__ hout,
    const unsigned short* __restrict__ ubf_all,
    const unsigned short* __restrict__ wgf, const float* __restrict__ gbias,
    const float* __restrict__ gpart,
    float* __restrict__ cbuf, unsigned short* __restrict__ cbf)
{
  const int b = blockIdx.x, tid = threadIdx.x;
  const int w = tid>>6, l = tid&63, lr = l&15, li = l>>4, lk = li*8;
  const int g = w & 3, mh = w >> 2;
  __shared__ float gsh[4][128][16];              // 32 KB: gate accumulators
  const unsigned short* ub = ubf_all + (size_t)t*TN*96;
  bf16x8 wz[3];
  {
    const unsigned short* wp = wgf + (((size_t)(g*32 + b)*19) + 16)*512 + (size_t)l*8;
    #pragma unroll
    for (int i=0;i<3;i++) wz[i] = *(const bf16x8*)(wp + (size_t)i*512);
  }
  // load gpart -> gsh: [g][b][n][16] layout, fully contiguous 8KB per g
  for (int i = tid; i < 2048; i += 512){
    int gg = i>>9, r = i&511;   // r = n*4 + j4
    *(float4*)&gsh[gg][r>>2][(r&3)*4] = *(const float4*)&gpart[(((size_t)(gg*32 + b)*128)<<4) + r*4];
  }
  f32x4 acc[4];
  #pragma unroll
  for (int m2=0;m2<4;m2++) acc[m2] = (f32x4){0,0,0,0};
  #pragma unroll
  for (int kt=0; kt<3; ++kt){
    #pragma unroll
    for (int m2=0;m2<4;m2++){
      bf16x8 a = *(const bf16x8*)(ub + (size_t)((mh*4+m2)*16 + lr)*96 + kt*32 + lk);
      acc[m2] = __builtin_amdgcn_mfma_f32_16x16x32_bf16(a, wz[kt], acc[m2], 0,0,0);
    }
  }
  __syncthreads();   // gsh fully loaded
  #pragma unroll
  for (int m2=0;m2<4;m2++)
    #pragma unroll
    for (int i=0;i<4;i++)
      gsh[g][(mh*4+m2)*16 + li*4 + i][lr] += acc[m2][i];
  __syncthreads();
  #pragma unroll
  for (int e=0;e<4;++e){
    int c = tid*4 + e;
    int nn = c>>4, j = c&15;
    int hidx = b*16 + j;
    float gi = gsh[0][nn][j] + gbias[         hidx];
    float gf = gsh[1][nn][j] + gbias[1*512 + hidx];
    float gg = gsh[2][nn][j] + gbias[2*512 + hidx];
    float go = gsh[3][nn][j] + gbias[3*512 + hidx];
    float cc = cbuf[nn*512 + hidx];
    float cs = fsigm(gf)*cc + fsigm(gi)*ftanh(gg);
    float h  = fsigm(go)*ftanh(cs);
    cbuf[nn*512 + hidx] = cs;
    unsigned short hb = f2bf(h);
    hout[nn*512 + hidx] = hb;
    cbf[((size_t)nn*TT + t)*608 + hidx] = hb;
  }
}

// ---------------- comb GEMM ----------------
__global__ __launch_bounds__(256) void k_comb(const unsigned short* __restrict__ cbf,
    const unsigned short* __restrict__ cwbf, const float* __restrict__ comb_b,
    unsigned short* __restrict__ ybf){
  int mbase = blockIdx.x*128, obase = blockIdx.y*128;
  int tid = threadIdx.x, w = tid>>6, l = tid&63;
  int lr = l&15, lk = (l>>4)*8;
  __shared__ unsigned short at[128*40];
  f32x4 acc[8][2];
  #pragma unroll
  for (int m=0;m<8;m++){ acc[m][0] = (f32x4){0,0,0,0}; acc[m][1] = (f32x4){0,0,0,0}; }
  for (int kt=0; kt<19; ++kt){
    int row = tid>>1, half = (tid&1)*16;
    const unsigned short* sp = cbf + (size_t)(mbase+row)*608 + kt*32 + half;
    *(float4*)&at[row*40 + half]     = *(const float4*)sp;
    *(float4*)&at[row*40 + half + 8] = *(const float4*)(sp + 8);
    __syncthreads();
    bf16x8 b0 = *(const bf16x8*)(cwbf + (size_t)(obase + (2*w+0)*16 + lr)*608 + kt*32 + lk);
    bf16x8 b1 = *(const bf16x8*)(cwbf + (size_t)(obase + (2*w+1)*16 + lr)*608 + kt*32 + lk);
    #pragma unroll
    for (int m=0;m<8;m++){
      bf16x8 afrag = *(const bf16x8*)&at[(m*16+lr)*40 + lk];
      acc[m][0] = __builtin_amdgcn_mfma_f32_16x16x32_bf16(afrag, b0, acc[m][0], 0,0,0);
      acc[m][1] = __builtin_amdgcn_mfma_f32_16x16x32_bf16(afrag, b1, acc[m][1], 0,0,0);
    }
    __syncthreads();
  }
  #pragma unroll
  for (int m=0;m<8;m++){
    #pragma unroll
    for (int j=0;j<2;j++){
      int o = obase + (2*w+j)*16 + lr;
      float cb = comb_b[o];
      #pragma unroll
      for (int i=0;i<4;i++){
        int r = mbase + m*16 + (l>>4)*4 + i;
        ybf[(size_t)r*1024 + o] = f2bf(ftanh(acc[m][j][i] + cb));
      }
    }
  }
}

// ---------------- out GEMM + fused postprocess ----------------
__global__ __launch_bounds__(256) void k_out(const unsigned short* __restrict__ ybf,
    const unsigned short* __restrict__ owbf, const float* __restrict__ obias,
    float* __restrict__ out){
  int mbase = blockIdx.x*128;
  int tid = threadIdx.x, w = tid>>6, l = tid&63;
  int lr = l&15, lk = (l>>4)*8;
  __shared__ unsigned short at[128*40];
  __shared__ float osh[128][129];
  f32x4 acc[8][2];
  #pragma unroll
  for (int m=0;m<8;m++){ acc[m][0] = (f32x4){0,0,0,0}; acc[m][1] = (f32x4){0,0,0,0}; }
  for (int kt=0; kt<32; ++kt){
    int row = tid>>1, half = (tid&1)*16;
    const unsigned short* sp = ybf + (size_t)(mbase+row)*1024 + kt*32 + half;
    *(float4*)&at[row*40 + half]     = *(const float4*)sp;
    *(float4*)&at[row*40 + half + 8] = *(const float4*)(sp + 8);
    __syncthreads();
    bf16x8 b0 = *(const bf16x8*)(owbf + ((2*w+0)*16 + lr)*1024 + kt*32 + lk);
    bf16x8 b1 = *(const bf16x8*)(owbf + ((2*w+1)*16 + lr)*1024 + kt*32 + lk);
    #pragma unroll
    for (int m=0;m<8;m++){
      bf16x8 afrag = *(const bf16x8*)&at[(m*16+lr)*40 + lk];
      acc[m][0] = __builtin_amdgcn_mfma_f32_16x16x32_bf16(afrag, b0, acc[m][0], 0,0,0);
      acc[m][1] = __builtin_amdgcn_mfma_f32_16x16x32_bf16(afrag, b1, acc[m][1], 0,0,0);
    }
    __syncthreads();
  }
  #pragma unroll
  for (int m=0;m<8;m++){
    #pragma unroll
    for (int j=0;j<2;j++){
      int o = (2*w+j)*16 + lr;
      float ob = obias[o];
      #pragma unroll
      for (int i=0;i<4;i++){
        int r = m*16 + (l>>4)*4 + i;
        osh[r][o] = acc[m][j][i] + ob;
      }
    }
  }
  __syncthreads();
  if (tid < 128){
    const float* row = osh[tid];
    int r = mbase + tid;
    float mx = -1e30f;
    #pragma unroll
    for (int k2=0;k2<20;k2++) mx = fmaxf(mx, row[k2]);
    float e[20]; float s = 0;
    #pragma unroll
    for (int k2=0;k2<20;k2++){ e[k2] = __expf(row[k2]-mx); s += e[k2]; }
    float inv = __builtin_amdgcn_rcpf(s);
    float* mixo  = out;
    float* meano = out + 163840;
    float* scaleo= out + 491520;
    float* corro = out + 819200;
    float* vlogo = out + 983040;
    #pragma unroll
    for (int k2=0;k2<20;k2++) mixo[r*20+k2] = e[k2]*inv;
    #pragma unroll
    for (int j=0;j<40;j++) meano[r*40+j] = row[20+j];
    #pragma unroll
    for (int j=0;j<40;j++) scaleo[r*40+j] = __expf(row[60+j]);
    #pragma unroll
    for (int k2=0;k2<20;k2++) corro[r*20+k2] = ftanh(row[100+k2]);
    vlogo[r] = row[120];
  }
}

extern "C" void kernel_launch(void* const* d_in, const int* in_sizes, int n_in,
                              void* d_out, int out_size, void* d_ws, size_t ws_size,
                              hipStream_t stream){
  const float* x       = (const float*)d_in[0];
  const float* x_canv  = (const float*)d_in[1];
  const float* start_  = (const float*)d_in[2];
  const float* conv1_w = (const float*)d_in[3];
  const float* conv1_b = (const float*)d_in[4];
  const float* conv2_w = (const float*)d_in[5];
  const float* conv2_b = (const float*)d_in[6];
  const float* conv3_w = (const float*)d_in[7];
  const float* conv3_b = (const float*)d_in[8];
  const float* init_w  = (const float*)d_in[9];
  const float* init_b  = (const float*)d_in[10];
  const float* Uw      = (const float*)d_in[11];
  const float* Ub      = (const float*)d_in[12];
  const float* Ww      = (const float*)d_in[13];
  const float* Wb      = (const float*)d_in[14];
  const float* vw      = (const float*)d_in[15];
  const float* vb      = (const float*)d_in[16];
  const float* beta_w  = (const float*)d_in[17];
  const float* beta_b  = (const float*)d_in[18];
  const float* xemb_w  = (const float*)d_in[19];
  const float* xemb_b  = (const float*)d_in[20];
  const float* semb_w  = (const float*)d_in[21];
  const float* semb_b  = (const float*)d_in[22];
  const float* Wih     = (const float*)d_in[23];
  const float* Whh     = (const float*)d_in[24];
  const float* bih     = (const float*)d_in[25];
  const float* bhh     = (const float*)d_in[26];
  const float* comb_w  = (const float*)d_in[27];
  const float* comb_b  = (const float*)d_in[28];
  const float* out_w   = (const float*)d_in[29];
  const float* out_b   = (const float*)d_in[30];
  (void)in_sizes; (void)n_in; (void)out_size; (void)ws_size;

  char* wsb = (char*)d_ws;
  size_t off = 0;
  auto alloc = [&](size_t bytes)->char*{
    char* p = wsb + off;
    off = (off + bytes + 255) & ~(size_t)255;
    return p;
  };
  unsigned short* c1bf   = (unsigned short*)alloc((size_t)TN*16*784*2);
  unsigned short* a2     = (unsigned short*)alloc((size_t)100352*160*2);  // a3 aliases a2
  unsigned short* a3     = a2;
  unsigned short* c2bf   = (unsigned short*)alloc((size_t)100352*32*2);
  unsigned short* afbf   = (unsigned short*)alloc((size_t)TN*64*196*2);
  unsigned short* abf    = (unsigned short*)alloc((size_t)TN*196*64*2);
  unsigned short* wabf   = (unsigned short*)alloc((size_t)TN*196*128*2);
  float*          cbuf   = (float*)alloc((size_t)TN*512*4);
  unsigned short* hbfA   = (unsigned short*)alloc((size_t)TN*512*2);
  unsigned short* hbfB   = (unsigned short*)alloc((size_t)TN*512*2);
  unsigned short* ubf_all= (unsigned short*)alloc((size_t)TT*TN*96*2);
  unsigned short* cbf    = (unsigned short*)alloc((size_t)TN*TT*608*2);
  unsigned short* ybf    = (unsigned short*)alloc((size_t)TN*TT*1024*2);
  unsigned short* wgf    = (unsigned short*)alloc((size_t)1245184*2);
  float*          gbias  = (float*)alloc((size_t)2048*4);
  float*          gpart  = (float*)alloc((size_t)4*128*512*4);
  unsigned short* cwbf   = (unsigned short*)alloc((size_t)1024*608*2);
  unsigned short* owbf   = (unsigned short*)alloc((size_t)128*1024*2);
  float*          obias  = (float*)alloc((size_t)128*4);
  unsigned short* uwbf   = (unsigned short*)alloc((size_t)128*512*2);
  unsigned short* betabf = (unsigned short*)alloc((size_t)64*512*2);
  unsigned short* wwbf   = (unsigned short*)alloc((size_t)128*64*2);
  unsigned short* w2b    = (unsigned short*)alloc((size_t)32*160*2);
  unsigned short* w3b    = (unsigned short*)alloc((size_t)64*320*2);

  hipLaunchKernelGGL(k_head, dim3(7314), dim3(256), 0, stream,
                     x_canv, conv1_w, conv1_b, c1bf,
                     Whh, Wih, bih, bhh, comb_w, out_w, out_b, Uw, beta_w, Ww, conv2_w, conv3_w,
                     wgf, gbias, cwbf, owbf, obias, uwbf, betabf, wwbf, w2b, w3b);
  hipLaunchKernelGGL(k_im2col2, dim3(7840), dim3(256), 0, stream, c1bf, a2);
  hipLaunchKernelGGL(k_gconv2, dim3(784), dim3(256), 0, stream, a2, w2b, conv2_b, c2bf);
  hipLaunchKernelGGL(k_im2col3, dim3(3920), dim3(256), 0, stream, c2bf, a3);
  hipLaunchKernelGGL(k_gconv3, dim3(196), dim3(256), 0, stream, a3, w3b, conv3_b, afbf, abf);
  hipLaunchKernelGGL(k_mid, dim3(2372), dim3(256), 0, stream,
                     afbf, start_, semb_w, semb_b,
                     abf, wwbf, Wb, wabf,
                     x, xemb_w, xemb_b, cbf, ubf_all,
                     init_w, init_b, hbfA, cbuf);

  for (int t = 0; t < TT; ++t){
    unsigned short* hin  = (t & 1) ? hbfB : hbfA;
    unsigned short* hout = (t & 1) ? hbfA : hbfB;
    hipLaunchKernelGGL(k_stepA, dim3(160), dim3(512), 0, stream, t,
                       hin, uwbf, Ub, betabf, beta_b, vw, vb, wabf, afbf, ubf_all, cbf, wgf, gpart);
    hipLaunchKernelGGL(k_stepB, dim3(32), dim3(512), 0, stream, t,
                       hout, ubf_all, wgf, gbias, gpart, cbuf, cbf);
  }

  hipLaunchKernelGGL(k_comb, dim3(64, 8), dim3(256), 0, stream, cbf, cwbf, comb_b, ybf);
  hipLaunchKernelGGL(k_out, dim3(64), dim3(256), 0, stream, ybf, owbf, obias, (float*)d_out);
}